// Round 7
// baseline (425.227 us; speedup 1.0000x reference)
//
#include <hip/hip_runtime.h>
#include <cstdint>
#include <cstddef>

typedef unsigned short ushort_t;
#define DEVI __device__ __forceinline__

constexpr int Bc = 4, Tc = 2048, Cc = 1024, Hc = 16;
constexpr int BT = Bc * Tc;           // 8192
constexpr int NCHUNK = Tc / 64;       // 32

using f32x4  = __attribute__((ext_vector_type(4))) float;
using bf16x8 = __attribute__((ext_vector_type(8))) __bf16;

DEVI ushort_t f2bf(float f) {
  union { float f; unsigned u; } v; v.f = f;
  unsigned r = v.u + 0x7fffu + ((v.u >> 16) & 1u);
  return (ushort_t)(r >> 16);
}
DEVI float bf2f(ushort_t u) {
  union { unsigned u; float f; } v; v.u = ((unsigned)u) << 16; return v.f;
}
DEVI float clip30(float x) { return fminf(fmaxf(x, -30.f), 30.f); }
DEVI float clip20(float x) { return fminf(fmaxf(x, -20.f), 20.f); }

DEVI float4 bf4up(uint2 r) {
  float4 v;
  v.x = bf2f((ushort_t)(r.x & 0xffff)); v.y = bf2f((ushort_t)(r.x >> 16));
  v.z = bf2f((ushort_t)(r.y & 0xffff)); v.w = bf2f((ushort_t)(r.y >> 16));
  return v;
}
DEVI uint2 f4pk(float4 v) {
  uint2 r;
  r.x = (unsigned)f2bf(v.x) | ((unsigned)f2bf(v.y) << 16);
  r.y = (unsigned)f2bf(v.z) | ((unsigned)f2bf(v.w) << 16);
  return r;
}

DEVI void gload_lds16(const ushort_t* g, ushort_t* l) {
  __builtin_amdgcn_global_load_lds(
      (const __attribute__((address_space(1))) void*)g,
      (__attribute__((address_space(3))) void*)l, 16, 0, 0);
}

#define GETEL(V4, E) ((E) == 0 ? (V4).x : (E) == 1 ? (V4).y : (E) == 2 ? (V4).z : (V4).w)
#define SETEL(V4, E, VAL) do { if ((E) == 0) (V4).x = (VAL); else if ((E) == 1) (V4).y = (VAL); \
                               else if ((E) == 2) (V4).z = (VAL); else (V4).w = (VAL); } while (0)

// one launch: 5 weight matrices f32 -> bf16 (z selects), float4 -> ushort4 vectorized
__global__ void k_f2bf5(const float* __restrict__ i0, const float* __restrict__ i1,
                        const float* __restrict__ i2, const float* __restrict__ i3,
                        const float* __restrict__ i4,
                        ushort_t* __restrict__ o0, ushort_t* __restrict__ o1,
                        ushort_t* __restrict__ o2, ushort_t* __restrict__ o3,
                        ushort_t* __restrict__ o4) {
  int z = blockIdx.z;
  const float* in = (z == 0) ? i0 : (z == 1) ? i1 : (z == 2) ? i2 : (z == 3) ? i3 : i4;
  ushort_t* out   = (z == 0) ? o0 : (z == 1) ? o1 : (z == 2) ? o2 : (z == 3) ? o3 : o4;
  int i = blockIdx.x * 256 + threadIdx.x;
  if (i < Cc * Cc / 4) {
    float4 v = *(const float4*)(in + (size_t)i * 4);
    ushort4 o;
    o.x = f2bf(v.x); o.y = f2bf(v.y); o.z = f2bf(v.z); o.w = f2bf(v.w);
    *(ushort4*)(out + (size_t)i * 4) = o;
  }
}

// merged prep: w2t (160K) | w1t (160K) | dw1t (64K) | xlast (4K) — one launch replaces 4
__global__ void k_prep(const float* __restrict__ w2, const float* __restrict__ w1,
                       const float* __restrict__ dw1, const float* __restrict__ x,
                       ushort_t* __restrict__ w2t, ushort_t* __restrict__ w1t,
                       ushort_t* __restrict__ dw1t, float* __restrict__ xlast) {
  int i = blockIdx.x * 256 + threadIdx.x;
  if (i < 163840) {                       // w2t[c][fd] = bf16(w2[fd][c])
    int c = i / 160, fd = i % 160;
    w2t[i] = f2bf(w2[(size_t)fd * 1024 + c]);
  } else if (i < 327680) {                // w1t[n][r] = bf16(w1[r][n]), w1 is 1024x160
    int j = i - 163840; int n = j >> 10, r = j & 1023;
    w1t[j] = f2bf(w1[(size_t)r * 160 + n]);
  } else if (i < 393216) {                // dw1t[n][r] = bf16(dw1[r][n]), dw1 is 1024x64
    int j = i - 327680; int n = j >> 10, r = j & 1023;
    dw1t[j] = f2bf(dw1[(size_t)r * 64 + n]);
  } else if (i < 397312) {                // xlast
    int j = i - 393216; int b = j >> 10, c = j & 1023;
    xlast[j] = x[((size_t)b * Tc + Tc - 1) * Cc + c];
  }
}

// ---------------- fused token-shift + skinny MFMA GEMM + tanh (NCOLS=160, bf16 out) ----------------
__global__ __launch_bounds__(256) void k_shift_tanh(
    const float* __restrict__ x, const float* __restrict__ sst,
    const float* __restrict__ tmx, const ushort_t* __restrict__ Wt,
    ushort_t* __restrict__ outv) {
  constexpr int NCOLS = 160, NF = NCOLS / 16;
  int tid = threadIdx.x;
  int wave = tid >> 6, lane = tid & 63;
  int row0 = (blockIdx.x * 4 + wave) * 16;
  int lr = lane & 15, lk = (lane >> 4) * 8;
  int rg = row0 + lr;
  int tt = rg & (Tc - 1);
  const float* xrow = x + (size_t)rg * Cc;
  const float* prow = (tt == 0) ? (sst + (size_t)(rg >> 11) * Cc) : (xrow - Cc);
  f32x4 acc[NF];
  #pragma unroll
  for (int n = 0; n < NF; ++n) acc[n] = (f32x4){0.f, 0.f, 0.f, 0.f};
  for (int k0 = 0; k0 < 1024; k0 += 32) {
    int c0 = k0 + lk;
    float4 xa = *(const float4*)(xrow + c0), xb = *(const float4*)(xrow + c0 + 4);
    float4 pa = *(const float4*)(prow + c0), pb = *(const float4*)(prow + c0 + 4);
    float4 ta = *(const float4*)(tmx + c0), tb = *(const float4*)(tmx + c0 + 4);
    union { bf16x8 v; uint2 u[2]; } cv;
    cv.u[0] = f4pk(make_float4(xa.x + (pa.x - xa.x) * ta.x, xa.y + (pa.y - xa.y) * ta.y,
                               xa.z + (pa.z - xa.z) * ta.z, xa.w + (pa.w - xa.w) * ta.w));
    cv.u[1] = f4pk(make_float4(xb.x + (pb.x - xb.x) * tb.x, xb.y + (pb.y - xb.y) * tb.y,
                               xb.z + (pb.z - xb.z) * tb.z, xb.w + (pb.w - xb.w) * tb.w));
    #pragma unroll
    for (int n = 0; n < NF; ++n) {
      bf16x8 b = *(const bf16x8*)&Wt[(size_t)(n * 16 + lr) * 1024 + k0 + lk];
      acc[n] = __builtin_amdgcn_mfma_f32_16x16x32_bf16(cv.v, b, acc[n], 0, 0, 0);
    }
  }
  #pragma unroll
  for (int n = 0; n < NF; ++n) {
    #pragma unroll
    for (int q = 0; q < 4; ++q) {
      int row = row0 + (lane >> 4) * 4 + q;
      size_t oi = (size_t)row * NCOLS + n * 16 + lr;
      outv[oi] = f2bf(tanhf(acc[n][q]));
    }
  }
}

// ---------------- skinny MFMA GEMM + tanh ----------------
template<int NCOLS, int OBF>
__global__ __launch_bounds__(256) void k_tanh_mfma(const ushort_t* __restrict__ A,
                                                   const ushort_t* __restrict__ Wt,
                                                   void* __restrict__ outv) {
  constexpr int NF = NCOLS / 16;
  int tid = threadIdx.x;
  int wave = tid >> 6, lane = tid & 63;
  int row0 = (blockIdx.x * 4 + wave) * 16;
  int lr = lane & 15, lk = (lane >> 4) * 8;
  f32x4 acc[NF];
  #pragma unroll
  for (int n = 0; n < NF; ++n) acc[n] = (f32x4){0.f, 0.f, 0.f, 0.f};
  for (int k0 = 0; k0 < 1024; k0 += 32) {
    bf16x8 a = *(const bf16x8*)&A[(size_t)(row0 + lr) * 1024 + k0 + lk];
    #pragma unroll
    for (int n = 0; n < NF; ++n) {
      bf16x8 b = *(const bf16x8*)&Wt[(size_t)(n * 16 + lr) * 1024 + k0 + lk];
      acc[n] = __builtin_amdgcn_mfma_f32_16x16x32_bf16(a, b, acc[n], 0, 0, 0);
    }
  }
  #pragma unroll
  for (int n = 0; n < NF; ++n) {
    #pragma unroll
    for (int q = 0; q < 4; ++q) {
      int row = row0 + (lane >> 4) * 4 + q;
      size_t oi = (size_t)row * NCOLS + n * 16 + lr;
      float v = tanhf(acc[n][q]);
      if (OBF == 1) ((ushort_t*)outv)[oi] = f2bf(v);
      else          ((float*)outv)[oi] = v;
    }
  }
}

// ---------------- mixer via MFMA (dx recomputed on the fly; all outs bf16) ----------------
__global__ __launch_bounds__(256) void k_mix5m(
    const float* __restrict__ x, const float* __restrict__ sst,
    const ushort_t* __restrict__ t160b, const ushort_t* __restrict__ w2t,
    const float* __restrict__ maaw, const float* __restrict__ maak,
    const float* __restrict__ maav, const float* __restrict__ maar,
    const float* __restrict__ maag,
    ushort_t* __restrict__ xw, ushort_t* __restrict__ xk, ushort_t* __restrict__ xv,
    ushort_t* __restrict__ xr, ushort_t* __restrict__ xg) {
  __shared__ __align__(16) ushort_t As[64 * 168];
  __shared__ __align__(16) ushort_t Bs[64 * 168];
  int tid = threadIdx.x;
  int lane = tid & 63;
  int bRow = blockIdx.x * 64, bCol = blockIdx.y * 64;
  #pragma unroll
  for (int i = 0; i < 5; ++i) {
    int e = tid + i * 256;
    int r = e / 20, cc = (e % 20) * 8;
    *(int4*)&As[r * 168 + cc] = *(const int4*)&t160b[(size_t)(bRow + r) * 160 + cc];
    *(int4*)&Bs[r * 168 + cc] = *(const int4*)&w2t[(size_t)(bCol + r) * 160 + cc];
  }
  __syncthreads();
  int wm = tid >> 7, wn = (tid >> 6) & 1;
  f32x4 acc[5][2][2];
  #pragma unroll
  for (int f = 0; f < 5; ++f)
    #pragma unroll
    for (int m = 0; m < 2; ++m)
      #pragma unroll
      for (int n = 0; n < 2; ++n) acc[f][m][n] = (f32x4){0.f, 0.f, 0.f, 0.f};
  #pragma unroll
  for (int f = 0; f < 5; ++f) {
    bf16x8 af[2], bfv[2];
    #pragma unroll
    for (int m = 0; m < 2; ++m)
      af[m] = *(const bf16x8*)&As[(wm * 32 + m * 16 + (lane & 15)) * 168 + f * 32 + (lane >> 4) * 8];
    #pragma unroll
    for (int n = 0; n < 2; ++n)
      bfv[n] = *(const bf16x8*)&Bs[(wn * 32 + n * 16 + (lane & 15)) * 168 + f * 32 + (lane >> 4) * 8];
    #pragma unroll
    for (int m = 0; m < 2; ++m)
      #pragma unroll
      for (int n = 0; n < 2; ++n)
        acc[f][m][n] = __builtin_amdgcn_mfma_f32_16x16x32_bf16(af[m], bfv[n], acc[f][m][n], 0, 0, 0);
  }
  #pragma unroll
  for (int n = 0; n < 2; ++n) {
    int col = bCol + wn * 32 + n * 16 + (lane & 15);
    float mw_c = maaw[col], mk_c = maak[col], mv_c = maav[col];
    float mr_c = maar[col], mg_c = maag[col];
    #pragma unroll
    for (int m = 0; m < 2; ++m) {
      int row0 = bRow + wm * 32 + m * 16 + (lane >> 4) * 4;
      #pragma unroll
      for (int q = 0; q < 4; ++q) {
        int rg = row0 + q;
        int tt = rg & (Tc - 1);
        size_t g = (size_t)rg * Cc + col;
        float xv0 = x[g];
        float xprev = (tt == 0) ? sst[(size_t)(rg >> 11) * Cc + col] : x[g - Cc];
        float dv = xprev - xv0;
        xw[g] = f2bf(xv0 + dv * (mw_c + acc[0][m][n][q]));
        xk[g] = f2bf(xv0 + dv * (mk_c + acc[1][m][n][q]));
        xv[g] = f2bf(xv0 + dv * (mv_c + acc[2][m][n][q]));
        xr[g] = f2bf(xv0 + dv * (mr_c + acc[3][m][n][q]));
        xg[g] = f2bf(xv0 + dv * (mg_c + acc[4][m][n][q]));
      }
    }
  }
}

// ---------------- 256x256 / BK=64 / 8-wave / 8-phase counted-vmcnt GEMM — retry of R1 with
// the PROVEN sub-tile LDS format. The 256x64 K-tile is 4 panels (row-half x k-half), each
// 8 sub-tiles of 16x32 stored EXACTLY like the measured-0-conflict 128² kernel:
//   store: gload_lds16, lane l -> row l>>2, src chunk (l&3)^((l>>3)&3), dest lane*16B
//   read:  row lane&15, phys chunk (lane>>4)^((lane>>1)&3)
// Every LDS instruction's address pattern is identical to the proven kernel.
// Schedule/vmcnt/liveness copied from R1 (correctness-proven there, absmax 0.125).
// Per-element K order unchanged -> bit-identical output.
template<int EPI>
DEVI void gemm256_body(const ushort_t* __restrict__ A, const ushort_t* __restrict__ Wt,
                       ushort_t* __restrict__ out,
                       ushort_t* As0, ushort_t* As1, ushort_t* Bs0, ushort_t* Bs1) {
  int tid = threadIdx.x;
  int wid = tid >> 6, lane = tid & 63;
  int wm = wid >> 2, wn = wid & 3;
  int lr = lane & 15;
  int bRow = blockIdx.x * 256, bCol = blockIdx.y * 256;
  int lkb = ((lane & 3) ^ ((lane >> 3) & 3)) * 8;   // proven source chunk swizzle
  int pch = ((lane >> 4) ^ ((lane >> 1) & 3)) * 8;  // proven read chunk swizzle

  f32x4 acc[8][4];
  #pragma unroll
  for (int m = 0; m < 8; ++m)
    #pragma unroll
    for (int n = 0; n < 4; ++n) acc[m][n] = (f32x4){0.f, 0.f, 0.f, 0.f};
  bf16x8 a[4][2], b[2][2][2];

// stage half-tile h (rows/cols [h*128,h*128+128)) of tile t: wave stages sub-tile st=wid
// in both k-half panels. panel index = h*2+kh, panel size 4096 ushorts, sub-tile 512.
#define STG_A(LB, t, h) do { \
    _Pragma("unroll") \
    for (int kh = 0; kh < 2; ++kh) \
      gload_lds16(A + (size_t)(bRow + (h) * 128 + wid * 16 + (lane >> 2)) * 1024 \
                    + (t) * 64 + kh * 32 + lkb, \
                  (LB) + ((h) * 2 + kh) * 4096 + wid * 512 + lane * 8); \
  } while (0)
#define STG_B(LB, t, h) do { \
    _Pragma("unroll") \
    for (int kh = 0; kh < 2; ++kh) \
      gload_lds16(Wt + (size_t)(bCol + (h) * 128 + wid * 16 + (lane >> 2)) * 1024 \
                     + (t) * 64 + kh * 32 + lkb, \
                  (LB) + ((h) * 2 + kh) * 4096 + wid * 512 + lane * 8); \
  } while (0)
// A rows: wm*128 + mh*64 + m*16 + lr  -> panel rh=wm, sub-tile st=mh*4+m
#define LDAF(LB, mh) do { \
    _Pragma("unroll") \
    for (int m = 0; m < 4; ++m) { \
      _Pragma("unroll") \
      for (int kh = 0; kh < 2; ++kh) \
        a[m][kh] = *(const bf16x8*)((LB) + (wm * 2 + kh) * 4096 \
                                    + ((mh) * 4 + m) * 512 + lr * 32 + pch); \
    } } while (0)
// B cols: wn*64 + nh*32 + n*16 + lr -> panel ch=wn>>1, sub-tile st=(wn&1)*4+nh*2+n
#define LDBF(LB, nh) do { \
    _Pragma("unroll") \
    for (int n = 0; n < 2; ++n) { \
      _Pragma("unroll") \
      for (int kh = 0; kh < 2; ++kh) \
        b[nh][n][kh] = *(const bf16x8*)((LB) + ((wn >> 1) * 2 + kh) * 4096 \
                                        + (((wn & 1) * 4 + (nh) * 2 + n)) * 512 + lr * 32 + pch); \
    } } while (0)
#define MQ(mh, nh) do { \
    _Pragma("unroll") \
    for (int kk = 0; kk < 2; ++kk) \
      _Pragma("unroll") \
      for (int m = 0; m < 4; ++m) \
        _Pragma("unroll") \
        for (int n = 0; n < 2; ++n) \
          acc[(mh) * 4 + m][(nh) * 2 + n] = __builtin_amdgcn_mfma_f32_16x16x32_bf16( \
              a[m][kk], b[nh][n][kk], acc[(mh) * 4 + m][(nh) * 2 + n], 0, 0, 0); \
  } while (0)
#define SB0() __builtin_amdgcn_sched_barrier(0)
#define MID(mh, nh) do { \
    __builtin_amdgcn_s_barrier(); \
    asm volatile("s_waitcnt lgkmcnt(0)" ::: "memory"); \
    SB0(); \
    __builtin_amdgcn_s_setprio(1); \
    MQ(mh, nh); \
    SB0(); \
    __builtin_amdgcn_s_setprio(0); \
  } while (0)
#define ENDP() do { __builtin_amdgcn_s_barrier(); SB0(); } while (0)
#define VMW(N) asm volatile("s_waitcnt vmcnt(" #N ")" ::: "memory")

  // prologue: tile0 A+B -> buf0, tile1 B -> buf1 (12 loads/wave); wait first 8 (tile0)
  STG_A(As0, 0, 0); STG_A(As0, 0, 1);
  STG_B(Bs0, 0, 0); STG_B(Bs0, 0, 1);
  STG_B(Bs1, 1, 0); STG_B(Bs1, 1, 1);
  VMW(4);
  __builtin_amdgcn_s_barrier();
  SB0();

  #pragma unroll 1
  for (int it = 0; it < 7; ++it) {
    int t1 = it * 2 + 1, t2 = it * 2 + 2, t3 = it * 2 + 3;
    // P1
    LDAF(As0, 0); LDBF(Bs0, 0); SB0();
    STG_A(As1, t1, 0);
    MID(0, 0); ENDP();
    // P2
    LDBF(Bs0, 1); SB0();
    STG_A(As1, t1, 1);
    MID(0, 1); ENDP();
    // P3
    LDAF(As0, 1); SB0();
    STG_B(Bs0, t2, 0);
    MID(1, 0); ENDP();
    // P4
    STG_B(Bs0, t2, 1);
    MID(1, 1); VMW(4); ENDP();
    // P5
    LDAF(As1, 0); LDBF(Bs1, 0); SB0();
    STG_A(As0, t2, 0);
    MID(0, 0); ENDP();
    // P6
    LDBF(Bs1, 1); SB0();
    STG_A(As0, t2, 1);
    MID(0, 1); ENDP();
    // P7
    LDAF(As1, 1); SB0();
    STG_B(Bs1, t3, 0);
    MID(1, 0); ENDP();
    // P8
    STG_B(Bs1, t3, 1);
    MID(1, 1); VMW(4); ENDP();
  }
  // epilogue: tiles 14 (buf0), 15 (buf1); stage only A(t15)
  LDAF(As0, 0); LDBF(Bs0, 0); SB0();
  STG_A(As1, 15, 0);
  MID(0, 0); ENDP();
  LDBF(Bs0, 1); SB0();
  STG_A(As1, 15, 1);
  MID(0, 1); ENDP();
  LDAF(As0, 1); SB0();
  MID(1, 0); ENDP();
  MID(1, 1); VMW(0); ENDP();
  LDAF(As1, 0); LDBF(Bs1, 0); SB0();
  MID(0, 0); ENDP();
  LDBF(Bs1, 1); SB0();
  MID(0, 1); ENDP();
  LDAF(As1, 1); SB0();
  MID(1, 0); ENDP();
  MID(1, 1);

#undef STG_A
#undef STG_B
#undef LDAF
#undef LDBF
#undef MQ
#undef SB0
#undef MID
#undef ENDP
#undef VMW

  // C write (bf16)
  #pragma unroll
  for (int m = 0; m < 8; ++m) {
    int row = bRow + wm * 128 + m * 16 + (lane >> 4) * 4;
    #pragma unroll
    for (int n = 0; n < 4; ++n) {
      int col = bCol + wn * 64 + n * 16 + lr;
      #pragma unroll
      for (int q = 0; q < 4; ++q) {
        float v = acc[m][n][q];
        if (EPI == 1) v = v / (1.f + __expf(-v));
        out[(size_t)(row + q) * 1024 + col] = f2bf(v);
      }
    }
  }
}

// fused 4-projection GEMM, 256^2 tiles: z selects r/k/v/g (g gets silu); all bf16 out
__global__ __launch_bounds__(512, 2) void k_gemm4x(
    const ushort_t* __restrict__ A0, const ushort_t* __restrict__ A1,
    const ushort_t* __restrict__ A2, const ushort_t* __restrict__ A3,
    const ushort_t* __restrict__ W0, const ushort_t* __restrict__ W1,
    const ushort_t* __restrict__ W2, const ushort_t* __restrict__ W3,
    ushort_t* __restrict__ O0, ushort_t* __restrict__ O1,
    ushort_t* __restrict__ O2, ushort_t* __restrict__ O3) {
  __shared__ __align__(16) ushort_t As[2][16384];
  __shared__ __align__(16) ushort_t Bs[2][16384];
  int z = blockIdx.z;
  const ushort_t* A  = (z == 0) ? A0 : (z == 1) ? A1 : (z == 2) ? A2 : A3;
  const ushort_t* Wt = (z == 0) ? W0 : (z == 1) ? W1 : (z == 2) ? W2 : W3;
  ushort_t* out      = (z == 0) ? O0 : (z == 1) ? O1 : (z == 2) ? O2 : O3;
  if (z == 3) gemm256_body<1>(A, Wt, out, As[0], As[1], Bs[0], Bs[1]);
  else        gemm256_body<0>(A, Wt, out, As[0], As[1], Bs[0], Bs[1]);
}

// ---------------- Wo GEMM, 64x128 tiles: 1024 blocks -> 4 blocks/CU residency ----------------
__global__ __launch_bounds__(256) void k_gemm_bm64(const ushort_t* __restrict__ A,
                                                   const ushort_t* __restrict__ Wt,
                                                   float* __restrict__ out) {
  __shared__ __align__(16) ushort_t As[2 * 64 * 32];
  __shared__ __align__(16) ushort_t Bs[2 * 128 * 32];
  int tid = threadIdx.x;
  int wave = tid >> 6, lane = tid & 63;
  int lr = lane >> 2;
  int lkb = (((lane & 3) ^ ((lane >> 3) & 3))) * 8;
  int pch = ((lane >> 4) ^ ((lane >> 1) & 3)) * 8;
  int bRow = blockIdx.x * 64, bCol = blockIdx.y * 128;
  f32x4 acc[4][2];
  #pragma unroll
  for (int m = 0; m < 4; ++m)
    #pragma unroll
    for (int n = 0; n < 2; ++n) acc[m][n] = (f32x4){0.f, 0.f, 0.f, 0.f};

#define STAGEK64(OA, OB, K0) do { \
    { int row = wave * 16 + lr; \
      gload_lds16(A + (size_t)(bRow + row) * 1024 + (K0) + lkb, &As[(OA) + wave * 512]); } \
    _Pragma("unroll") \
    for (int i = 0; i < 2; ++i) { \
      int row = (wave + 4 * i) * 16 + lr; \
      gload_lds16(Wt + (size_t)(bCol + row) * 1024 + (K0) + lkb, &Bs[(OB) + (wave + 4 * i) * 512]); \
    } } while (0)
#define CMP64(OA, OB) do { \
    bf16x8 af[4], bfv[2]; \
    _Pragma("unroll") \
    for (int m = 0; m < 4; ++m) \
      af[m] = *(const bf16x8*)&As[(OA) + (m * 16 + (lane & 15)) * 32 + pch]; \
    _Pragma("unroll") \
    for (int n = 0; n < 2; ++n) \
      bfv[n] = *(const bf16x8*)&Bs[(OB) + (wave * 32 + n * 16 + (lane & 15)) * 32 + pch]; \
    _Pragma("unroll") \
    for (int m = 0; m < 4; ++m) \
      _Pragma("unroll") \
      for (int n = 0; n < 2; ++n) \
        acc[m][n] = __builtin_amdgcn_mfma_f32_16x16x32_bf16(af[m], bfv[n], acc[m][n], 0, 0, 0); \
  } while (0)

  for (int k0 = 0; k0 < 1024; k0 += 64) {
    STAGEK64(0, 0, k0);
    STAGEK64(2048, 4096, k0 + 32);
    __syncthreads();
    CMP64(0, 0);
    CMP64(2048, 4096);
    __syncthreads();
  }
#undef STAGEK64
#undef CMP64

  #pragma unroll
  for (int m = 0; m < 4; ++m) {
    int row = bRow + m * 16 + (lane >> 4) * 4;
    #pragma unroll
    for (int n = 0; n < 2; ++n) {
      int col = bCol + wave * 32 + n * 16 + (lane & 15);
      #pragma unroll
      for (int q = 0; q < 4; ++q)
        out[(size_t)(row + q) * 1024 + col] = acc[m][n][q];
    }
  }
}

// ---------------- preA: wlog via MFMA, cumsum/esum, RW, A(MFMA), knorm, KV(MFMA) ----------------
__global__ __launch_bounds__(256) void k_preA(
    const ushort_t* __restrict__ rbuf, const ushort_t* __restrict__ kbuf,
    const ushort_t* __restrict__ vbf,
    const ushort_t* __restrict__ t64bf, const float* __restrict__ dw2,
    const float* __restrict__ tdec, const float* __restrict__ faaaa,
    ushort_t* __restrict__ rwbf, ushort_t* __restrict__ kvbf, ushort_t* __restrict__ knbuf,
    ushort_t* __restrict__ Abf, float* __restrict__ esum) {
  __shared__ __align__(16) char ubuf[16640 + 9216 + 9216];
  float* wc = (float*)ubuf;
  ushort_t* sA = (ushort_t*)(ubuf + 16640);
  ushort_t* sB = (ushort_t*)(ubuf + 16640 + 9216);
  __shared__ float sred[4 * 64];
  __shared__ float sdiag[64];
  __shared__ float snrm[64];
  int bx = blockIdx.x;
  int ci = bx & 31, bh = bx >> 5;
  int b = bh >> 4, h = bh & 15;
  int tid = threadIdx.x;
  int w = tid >> 6, lane = tid & 63;
  int c = lane;
  int row0g = b * Tc + ci * 64;
  size_t base = (size_t)row0g * Cc + (size_t)h * 64;

  #pragma unroll
  for (int j = 0; j < 2; ++j) {
    int e = tid + j * 256; int r = e >> 3, cc = (e & 7) * 8;
    *(int4*)&sA[r * 72 + cc] = *(const int4*)&t64bf[(size_t)(row0g + r) * 64 + cc];
  }
  for (int i = 0; i < 16; ++i) {
    int e = tid + i * 256; int r = e >> 6, cc = e & 63;
    sB[cc * 72 + r] = f2bf(dw2[(size_t)r * Cc + h * 64 + cc]);
  }
  float rv[16], kv[16];
  #pragma unroll
  for (int i = 0; i < 16; ++i) {
    size_t g = base + (size_t)(w * 16 + i) * Cc + c;
    rv[i] = bf2f(rbuf[g]); kv[i] = bf2f(kbuf[g]);
  }
  __syncthreads();
  {
    int rbase = w * 16;
    bf16x8 a0 = *(const bf16x8*)&sA[(rbase + (lane & 15)) * 72 + (lane >> 4) * 8];
    bf16x8 a1 = *(const bf16x8*)&sA[(rbase + (lane & 15)) * 72 + 32 + (lane >> 4) * 8];
    #pragma unroll
    for (int ct = 0; ct < 4; ++ct) {
      bf16x8 b0 = *(const bf16x8*)&sB[(ct * 16 + (lane & 15)) * 72 + (lane >> 4) * 8];
      bf16x8 b1 = *(const bf16x8*)&sB[(ct * 16 + (lane & 15)) * 72 + 32 + (lane >> 4) * 8];
      f32x4 acc = {0.f, 0.f, 0.f, 0.f};
      acc = __builtin_amdgcn_mfma_f32_16x16x32_bf16(a0, b0, acc, 0, 0, 0);
      acc = __builtin_amdgcn_mfma_f32_16x16x32_bf16(a1, b1, acc, 0, 0, 0);
      int s = ct * 16 + (lane & 15);
      #pragma unroll
      for (int q = 0; q < 4; ++q) {
        int t = rbase + (lane >> 4) * 4 + q;
        wc[t * 65 + s] = acc[q];
      }
    }
  }
  __syncthreads();
  float wv[16];
  {
    float td = tdec[h * 64 + c];
    #pragma unroll
    for (int i = 0; i < 16; ++i)
      wv[i] = -__expf(td + wc[(w * 16 + i) * 65 + c]);
  }
  {
    float s = 0.f;
    #pragma unroll
    for (int i = 0; i < 16; ++i) s += wv[i];
    sred[w * 64 + c] = s;
  }
  __syncthreads();
  {
    float run = 0.f;
    for (int ww = 0; ww < w; ++ww) run += sred[ww * 64 + c];
    #pragma unroll
    for (int i = 0; i < 16; ++i) {
      run += wv[i]; wv[i] = run;
      wc[(w * 16 + i) * 65 + c] = run;
    }
    if (w == 3) esum[((size_t)bh * 32 + ci) * 64 + c] = __expf(run);
  }
  {
    float u_c = faaaa[h * 64 + c];
    #pragma unroll
    for (int i = 0; i < 16; ++i) {
      float p = rv[i] * kv[i] * u_c;
      float n2 = kv[i] * kv[i];
      #pragma unroll
      for (int o = 32; o; o >>= 1) { p += __shfl_xor(p, o, 64); n2 += __shfl_xor(n2, o, 64); }
      if (lane == 0) {
        sdiag[w * 16 + i] = p;
        snrm[w * 16 + i] = 1.f / fmaxf(sqrtf(n2), 1e-12f);
      }
    }
  }
  __syncthreads();
  float off32 = wc[31 * 65 + c];
  float wc63 = wc[63 * 65 + c];
  #pragma unroll
  for (int i = 0; i < 16; ++i) {
    int t = w * 16 + i;
    size_t g = base + (size_t)t * Cc + c;
    float wsh = (i == 0) ? ((w == 0) ? 0.f : wc[(t - 1) * 65 + c]) : wv[i - 1];
    rwbf[g] = f2bf(rv[i] * __expf(clip30(wsh)));
    sA[t * 72 + c] = f2bf(rv[i] * __expf(clip30(wsh - off32)));
    sB[t * 72 + c] = f2bf(kv[i] * __expf(clip30(off32 - wv[i])));
    knbuf[g] = f2bf(kv[i] * snrm[t]);
  }
  __syncthreads();
  {
    int rbase = w * 16;
    bf16x8 a0 = *(const bf16x8*)&sA[(rbase + (lane & 15)) * 72 + (lane >> 4) * 8];
    bf16x8 a1 = *(const bf16x8*)&sA[(rbase + (lane & 15)) * 72 + 32 + (lane >> 4) * 8];
    #pragma unroll
    for (int ct = 0; ct < 4; ++ct) {
      bf16x8 b0 = *(const bf16x8*)&sB[(ct * 16 + (lane & 15)) * 72 + (lane >> 4) * 8];
      bf16x8 b1 = *(const bf16x8*)&sB[(ct * 16 + (lane & 15)) * 72 + 32 + (lane >> 4) * 8];
      f32x4 acc = {0.f, 0.f, 0.f, 0.f};
      acc = __builtin_amdgcn_mfma_f32_16x16x32_bf16(a0, b0, acc, 0, 0, 0);
      acc = __builtin_amdgcn_mfma_f32_16x16x32_bf16(a1, b1, acc, 0, 0, 0);
      int s = ct * 16 + (lane & 15);
      #pragma unroll
      for (int q = 0; q < 4; ++q) {
        int t = rbase + (lane >> 4) * 4 + q;
        float val = (t > s) ? acc[q] : ((t == s) ? sdiag[t] : 0.f);
        Abf[(size_t)bx * 4096 + t * 64 + s] = f2bf(val);
      }
    }
  }
  __syncthreads();
  #pragma unroll
  for (int i = 0; i < 16; ++i) {
    int t = w * 16 + i;
    size_t g = base + (size_t)t * Cc + c;
    sA[c * 72 + t] = f2bf(kv[i] * __expf(clip30(wc63 - wv[i])));
    sB[c * 72 + t] = vbf[g];
  }
  __syncthreads();
  {
    int rbase = w * 16;
    bf16x8 a0 = *(const bf16x8*)&sA[(rbase + (lane & 15)) * 72 + (lane >> 4) * 8];
    bf16x8 a1 = *(const bf16x8*)&sA[(rbase + (lane & 15)) * 72 + 32 + (lane >> 4) * 8];
    #pragma unroll
    for (int ct = 0; ct < 4; ++ct) {
      bf16x8 b0 = *(const bf16x8*)&sB[(ct * 16 + (lane & 15)) * 72 + (lane >> 4) * 8];
      bf16x8 b1 = *(const bf16x8*)&sB[(ct * 16 + (lane & 15)) * 72 + 32 + (lane >> 4) * 8];
      f32x4 acc = {0.f, 0.f, 0.f, 0.f};
      acc = __builtin_amdgcn_mfma_f32_16x16x32_bf16(a0, b0, acc, 0, 0, 0);
      acc = __builtin_amdgcn_mfma_f32_16x16x32_bf16(a1, b1, acc, 0, 0, 0);
      int j = ct * 16 + (lane & 15);
      #pragma unroll
      for (int q = 0; q < 4; ++q) {
        int ii = rbase + (lane >> 4) * 4 + q;
        kvbf[base + (size_t)ii * Cc + j] = f2bf(acc[q]);
      }
    }
  }
}

// ---------------- preB: P(MFMA), static-register GJ solve, y = A@X + RW@state, fused GroupNorm*g ----------------
__global__ __launch_bounds__(256) void k_preB(
    const ushort_t* __restrict__ knbuf, const ushort_t* __restrict__ vbf,
    const ushort_t* __restrict__ Abf, const ushort_t* __restrict__ rwbf,
    const ushort_t* __restrict__ statebuf, const float* __restrict__ ltemp,
    const ushort_t* __restrict__ gbuf, const float* __restrict__ gamma,
    const float* __restrict__ beta, ushort_t* __restrict__ ong) {
  __shared__ __align__(16) ushort_t sKX[64 * 72];
  __shared__ __align__(16) ushort_t sAb[64 * 72];
  __shared__ __align__(16) char ubuf[64 * 72 * 2 * 2];
  __shared__ __align__(16) float pivbuf[2][192];
  __shared__ float colbuf[2][64];
  __shared__ float diagbuf[64];
  float* sP = (float*)ubuf;
  ushort_t* sRW = (ushort_t*)ubuf;
  ushort_t* sSTt = (ushort_t*)(ubuf + 64 * 72 * 2);

  int bx = blockIdx.x;
  int ci = bx & 31, bh = bx >> 5;
  int b = bh >> 4, h = bh & 15;
  int tid = threadIdx.x;
  int w = tid >> 6, lane = tid & 63;
  int rg = tid >> 4, cg = tid & 15;
  size_t base = ((size_t)(b * Tc + ci * 64)) * Cc + (size_t)h * 64;

  #pragma unroll
  for (int j = 0; j < 2; ++j) {
    int e = tid + j * 256;
    int r = e >> 3, cc = (e & 7) * 8;
    *(int4*)&sKX[r * 72 + cc] = *(const int4*)&knbuf[base + (size_t)r * Cc + cc];
    *(int4*)&sAb[r * 72 + cc] = *(const int4*)&Abf[(size_t)bx * 4096 + (size_t)r * 64 + cc];
  }
  float4 A0, A1, A2, A3, B0, B1, B2, B3;
  if (cg >= 8) {
#define LDV(R, AR, BR) do { \
      int4 raw = *(const int4*)(vbf + base + (size_t)(4 * rg + (R)) * Cc + (cg - 8) * 8); \
      (AR).x = bf2f((ushort_t)(raw.x & 0xffff)); (AR).y = bf2f((ushort_t)((unsigned)raw.x >> 16)); \
      (AR).z = bf2f((ushort_t)(raw.y & 0xffff)); (AR).w = bf2f((ushort_t)((unsigned)raw.y >> 16)); \
      (BR).x = bf2f((ushort_t)(raw.z & 0xffff)); (BR).y = bf2f((ushort_t)((unsigned)raw.z >> 16)); \
      (BR).z = bf2f((ushort_t)(raw.w & 0xffff)); (BR).w = bf2f((ushort_t)((unsigned)raw.w >> 16)); \
    } while (0)
    LDV(0, A0, B0); LDV(1, A1, B1); LDV(2, A2, B2); LDV(3, A3, B3);
#undef LDV
  }
  __syncthreads();
  float temp = log1pf(__expf(ltemp[h]));
  {
    int rbase = w * 16;
    bf16x8 a0 = *(const bf16x8*)&sKX[(rbase + (lane & 15)) * 72 + (lane >> 4) * 8];
    bf16x8 a1 = *(const bf16x8*)&sKX[(rbase + (lane & 15)) * 72 + 32 + (lane >> 4) * 8];
    #pragma unroll
    for (int ct = 0; ct < 4; ++ct) {
      bf16x8 b0 = *(const bf16x8*)&sKX[(ct * 16 + (lane & 15)) * 72 + (lane >> 4) * 8];
      bf16x8 b1 = *(const bf16x8*)&sKX[(ct * 16 + (lane & 15)) * 72 + 32 + (lane >> 4) * 8];
      f32x4 acc = {0.f, 0.f, 0.f, 0.f};
      acc = __builtin_amdgcn_mfma_f32_16x16x32_bf16(a0, b0, acc, 0, 0, 0);
      acc = __builtin_amdgcn_mfma_f32_16x16x32_bf16(a1, b1, acc, 0, 0, 0);
      int s = ct * 16 + (lane & 15);
      #pragma unroll
      for (int q = 0; q < 4; ++q) {
        int t = rbase + (lane >> 4) * 4 + q;
        sP[t * 68 + s] = ((t == s) ? 1.f : 0.f) + __expf(clip20(temp * acc[q]));
      }
    }
  }
  __syncthreads();
  if (cg < 8) {
    A0 = *(float4*)&sP[(4 * rg + 0) * 68 + cg * 8]; B0 = *(float4*)&sP[(4 * rg + 0) * 68 + cg * 8 + 4];
    A1 = *(float4*)&sP[(4 * rg + 1) * 68 + cg * 8]; B1 = *(float4*)&sP[(4 * rg + 1) * 68 + cg * 8 + 4];
    A2 = *(float4*)&sP[(4 * rg + 2) * 68 + cg * 8]; B2 = *(float4*)&sP[(4 * rg + 2) * 68 + cg * 8 + 4];
    A3 = *(float4*)&sP[(4 * rg + 3) * 68 + cg * 8]; B3 = *(float4*)&sP[(4 * rg + 3) * 68 + cg * 8 + 4];
  }
  __syncthreads();
  #pragma unroll
  for (int j = 0; j < 2; ++j) {
    int e = tid + j * 256;
    int r = e >> 3, cc = (e & 7) * 8;
    *(int4*)&sRW[r * 72 + cc] = *(const int4*)&rwbf[base + (size_t)r * Cc + cc];
  }
  {
    const ushort_t* sb = statebuf + ((size_t)bh * 32 + ci) * 4096;
    #pragma unroll
    for (int i = 0; i < 16; ++i) {
      int e = tid + i * 256;
      int r = e >> 6, c = e & 63;
      sSTt[c * 72 + r] = sb[e];
    }
  }
#define UPD(MA, MB, F) do { \
    (MA).x -= (F) * p0_.x; (MA).y -= (F) * p0_.y; (MA).z -= (F) * p0_.z; (MA).w -= (F) * p0_.w; \
    (MB).x -= (F) * p1_.x; (MB).y -= (F) * p1_.y; (MB).z -= (F) * p1_.z; (MB).w -= (F) * p1_.w; \
  } while (0)
#define GJSTEP(JL, PRA, PRB, H0, H1, H2, H3) do { \
    int j_ = jh * 8 + (JL); \
    if (rg == (j_ >> 2)) { \
      *(float4*)&pivbuf[(JL) & 1][cg * 12]     = (PRA); \
      *(float4*)&pivbuf[(JL) & 1][cg * 12 + 4] = (PRB); \
    } \
    if (cg == jh) { \
      float4 cv_; \
      cv_.x = GETEL(H0, (JL) & 3); \
      cv_.y = GETEL(H1, (JL) & 3); \
      cv_.z = GETEL(H2, (JL) & 3); \
      cv_.w = GETEL(H3, (JL) & 3); \
      *(float4*)&colbuf[(JL) & 1][rg * 4] = cv_; \
    } \
    __syncthreads(); \
    float pd_ = pivbuf[(JL) & 1][(j_ >> 3) * 12 + (j_ & 7)]; \
    float4 fv_ = *(float4*)&colbuf[(JL) & 1][rg * 4]; \
    float4 p0_ = *(float4*)&pivbuf[(JL) & 1][cg * 12]; \
    float4 p1_ = *(float4*)&pivbuf[(JL) & 1][cg * 12 + 4]; \
    if (rg == (j_ >> 2)) SETEL(fv_, (JL) & 3, 0.f); \
    float inv_ = 1.f / pd_; \
    float f0_ = fv_.x * inv_, f1_ = fv_.y * inv_, f2_ = fv_.z * inv_, f3_ = fv_.w * inv_; \
    UPD(A0, B0, f0_); UPD(A1, B1, f1_); UPD(A2, B2, f2_); UPD(A3, B3, f3_); \
  } while (0)
  for (int jh = 0; jh < 8; ++jh) {
    GJSTEP(0, A0, B0, A0, A1, A2, A3);
    GJSTEP(1, A1, B1, A0, A1, A2, A3);
    GJSTEP(2, A2, B2, A0, A1, A2, A3);
    GJSTEP(3, A3, B3, A0, A1, A2, A3);
    GJSTEP(4, A0, B0, B0, B1, B2, B3);
    GJSTEP(5, A1, B1, B0, B1, B2, B3);
    GJSTEP(6, A2, B2, B0, B1, B2, B3);
    GJSTEP(7, A3, B3, B0, B1, B2, B3);
  }
#undef GJSTEP
#undef UPD
  if (cg == (rg >> 1)) {
    float4 h0 = (rg & 1) ? B0 : A0;
    float4 h1 = (rg & 1) ? B1 : A1;
    float4 h2 = (rg & 1) ? B2 : A2;
    float4 h3 = (rg & 1) ? B3 : A3;
    *(float4*)&diagbuf[rg * 4] = make_float4(h0.x, h1.y, h2.z, h3.w);
  }
  __syncthreads();
  if (cg >= 8) {
    float4 dg = *(float4*)&diagbuf[rg * 4];
#define WRX(R, AR, BR, IR) do { \
      int cb_ = (cg - 8) * 8; \
      sKX[(cb_ + 0) * 72 + 4 * rg + (R)] = f2bf((AR).x * (IR)); \
      sKX[(cb_ + 1) * 72 + 4 * rg + (R)] = f2bf((AR).y * (IR)); \
      sKX[(cb_ + 2) * 72 + 4 * rg + (R)] = f2bf((AR).z * (IR)); \
      sKX[(cb_ + 3) * 72 + 4 * rg + (R)] = f2bf((AR).w * (IR)); \
      sKX[(cb_ + 4) * 72 + 4 * rg + (R)] = f2bf((BR).x * (IR)); \
      sKX[(cb_ + 5) * 72 + 4 * rg + (R)] = f2bf((BR).y * (IR)); \
      sKX[(cb_ + 6) * 72 + 4 * rg + (R)] = f2bf((BR).z * (IR)); \
      sKX[(cb_ + 7) * 72 + 4 * rg + (R)] = f2bf((BR).w * (IR)); \
    } while (0)
    WRX(0, A0, B0, 1.f / dg.x);
    WRX(1, A1, B1, 1.f / dg.y);
    WRX(2, A2, B2, 1.f / dg.z);
    WRX(3, A3, B3, 1.f / dg.w);
#undef WRX
  }
  __syncthreads();
  {
    int rbase = w * 16;
    bf16x8 aA0 = *(const bf16x8*)&sAb[(rbase + (lane & 15)) * 72 + (lane >> 4) * 8];
    bf16x8 aA1 = *(const bf16x8*)&sAb[(rbase + (lane & 15)) * 72 + 32 + (lane >> 4) * 8];
    bf16x8 aR0 = *(const bf16x8*)&sRW[(rbase + (lane & 15)) * 72 + (lane >> 4) * 8];
    bf16x8 aR1 = *(const bf16x8*)&sRW[(rbase + (lane & 15)) * 72 + 32 + (lane >> 4) * 8];
    f32x4 yv[4];
    #pragma unroll
    for (int ct = 0; ct < 4; ++ct) {
      bf16x8 bX0 = *(const bf16x8*)&sKX[(ct * 16 + (lane & 15)) * 72 + (lane >> 4) * 8];
      bf16x8 bX1 = *(const bf16x8*)&sKX[(ct * 16 + (lane & 15)) * 72 + 32 + (lane >> 4) * 8];
      bf16x8 bS0 = *(const bf16x8*)&sSTt[(ct * 16 + (lane & 15)) * 72 + (lane >> 4) * 8];
      bf16x8 bS1 = *(const bf16x8*)&sSTt[(ct * 16 + (lane & 15)) * 72 + 32 + (lane >> 4) * 8];
      f32x4 acc = {0.f, 0.f, 0.f, 0.f};
      acc = __builtin_amdgcn_mfma_f32_16x16x32_bf16(aA0, bX0, acc, 0, 0, 0);
      acc = __builtin_amdgcn_mfma_f32_16x16x32_bf16(aA1, bX1, acc, 0, 0, 0);
      acc = __builtin_amdgcn_mfma_f32_16x16x32_bf16(aR0, bS0, acc, 0, 0, 0);
      acc = __builtin_amdgcn_mfma_f32_16x16x32_bf16(aR1, bS1, acc, 0, 0, 0);
      yv[ct] = acc;
    }
    #pragma unroll
    for (int q = 0; q < 4; ++q) {
      float s1 = yv[0][q] + yv[1][q] + yv[2][q] + yv[3][q];
      float s2 = yv[0][q] * yv[0][q] + yv[1][q] * yv[1][q] +
                 yv[2][q] * yv[2][q] + yv[3][q] * yv[3][q];
      #pragma unroll
      for (int o = 1; o < 16; o <<= 1) {
        s1 += __shfl_xor(s1, o, 64);
        s2 += __shfl_xor(s2, o, 64);
      }
      float mu = s1 * (1.f / 64.f);
      float var = s2 * (1.f / 64.f) - mu * mu;
      float rs = rsqrtf(var + 6.4e-4f);
      int t = rbase + (lane >> 4) * 4 + q;
      #pragma unroll
      for (int ct = 0; ct < 4; ++ct) {
        int cc = ct * 16 + (lane & 15);
        size_t g = base + (size_t)t * Cc + cc;
        float yn = (yv[ct][q] - mu) * rs;
        float o = (yn * gamma[h * 64 + cc] + beta[h * 64 + cc]) * bf2f(gbuf[g]);
        ong[g] = f2bf(o);
      }
    }
  }
}

// ---------------- state recurrence only (bf16 kv/statebuf, f32 registers) ----------------
__global__ __launch_bounds__(128) void k_scanstate(
    const float* __restrict__ wkv0, const ushort_t* __restrict__ kvbf,
    const float* __restrict__ esum, ushort_t* __restrict__ statebuf,
    float* __restrict__ stout) {
  int bh = blockIdx.x >> 3;
  int rg = blockIdx.x & 7;
  int b = bh >> 4, h = bh & 15;
  int tid = threadIdx.x;
  int r = rg * 8 + (tid >> 4);
  int c0 = (tid & 15) * 4;
  float4 st = *(const float4*)(wkv0 + ((size_t)bh * 64 + r) * 64 + c0);
  size_t kvb = (size_t)(b * Tc) * Cc + (size_t)h * 64 + (size_t)r * Cc + c0;
  constexpr int PF = 4;
  uint2 kvn[PF];
  float4 evn[PF];
  #pragma unroll
  for (int j = 0; j < PF; ++j) {
    kvn[j] = *(const uint2*)(kvbf + kvb + (size_t)j * 64 * Cc);
    evn[j] = *(const float4*)(esum + ((size_t)bh * 32 + j) * 64 + c0);
  }
  #pragma unroll
  for (int ci = 0; ci < NCHUNK; ++ci) {
    *(uint2*)(statebuf + ((size_t)bh * 32 + ci) * 4096 + (size_t)r * 64 + c0) = f4pk(st);
    float4 kv = bf4up(kvn[ci & 3]);
    float4 ev = evn[ci & 3];
    if (ci + PF < NCHUNK) {
      kvn[ci & 3] = *(const uint2*)(kvbf + kvb + (size_t)(ci + PF) * 64 * Cc);
      evn[ci & 3] = *(const float4*)(esum + ((size_t)bh * 32 + ci + PF) * 64 + c0);
    }
    st.x = st.x * ev.x + kv.x;
    st.y = st.y * ev.y + kv.y;
    st.z = st.z * ev.z + kv.z;
    st.w = st.w * ev.w + kv.w;
  }
  *(float4*)(stout + ((size_t)bh * 64 + r) * 64 + c0) = st;
}

// ---------------- launcher ----------------
extern "C" void kernel_launch(void* const* d_in, const int* in_sizes, int n_in,
                              void* d_out, int out_size, void* d_ws, size_t ws_size,
                              hipStream_t stream) {
  (void)in_sizes; (void)n_in; (void)out_size;
  const float* x     = (const float*)d_in[0];
  const float* sst   = (const float*)d_in[1];
  const float* wkv0  = (const float*)d_in[2];
  const float* tmx   = (const float*)d_in[3];
  const float* tmw   = (const float*)d_in[4];
  const float* tmk   = (const float*)d_in[5];
  const float* tmv   = (const float*)d_in[6];
  const float* tmr   = (const float*)d_in[7];
  const float* tmg   = (const float*)d_in[8];
  const float* w1    = (const float*)d_in[9];
  const float* w2    = (const float*)d_in[10];
  const float* tdec  = (const float*)d_in[11];
  const float* dw1   = (const float*)d_in[12];
  const float* dw2   = (const float*)d_in[13];
  const float* faaaa = (const float*)d_in[14];
  const float* ltemp = (const float*)d_in[15];
  const float* Wr    = (const float*)d_in[16];
  const float* Wk    = (const float*)d_in[17];
  const float* Wv    = (const float*)d_in[18];
  const float* Wg    = (const float*)d_in[19];
  const float* Wo    = (const float*)d_in[20];
  const float* lng   = (const float*)d_in[21];
  const float* lnb   = (const float*)d_in[22];
  float* out = (float*)d_out;

  const size_t MB = 1ull << 20;
  const size_t NEED = 242 * MB;
  if (ws_size < NEED) return;

  char* p = (char*)d_ws;
  ushort_t* kbb  = (ushort_t*)(p + 0 * MB);    // bf16 k (GEMM out)
  ushort_t* xwb  = (ushort_t*)(p + 16 * MB);   // xw bf16 -> rbb
  ushort_t* rbb  = (ushort_t*)(p + 16 * MB);   // bf16 r (GEMM out), overlays xwb
  ushort_t* kvbf = (ushort_t*)(p + 32 * MB);   // KV bf16 (16 MiB)
  ushort_t* statebuf = (ushort_t*)(p + 96 * MB); // bf16 (16 MiB)
  ushort_t* vbuf = (ushort_t*)(p + 128 * MB);  // v (bf16)
  ushort_t* gbuf = (ushort_t*)(p + 144 * MB);  // silu(g) (bf16)
  ushort_t* xkb  = (ushort_t*)(p + 160 * MB);  // -> Abf
  ushort_t* Abf  = (ushort_t*)(p + 160 * MB);
  ushort_t* xvb  = (ushort_t*)(p + 176 * MB);  // -> rwbf
  ushort_t* rwbf = (ushort_t*)(p + 176 * MB);
  ushort_t* xrb  = (ushort_t*)(p + 192 * MB);
  ushort_t* xgb  = (ushort_t*)(p + 208 * MB);  // xg -> knorm -> ong
  ushort_t* t160b = (ushort_t*)(p + 224 * MB);
  float*    esum = (float*)(p + 224 * MB);     // overlays t160b (dead by then)
  ushort_t* w2t  = (ushort_t*)(p + 227 * MB);  // 0.32 MiB
  ushort_t* w1t  = (ushort_t*)(p + 228 * MB);  // 0.32 MiB
  ushort_t* dw1t = (ushort_t*)(p + 229 * MB);  // 0.13 MiB
  ushort_t* t64bf = (ushort_t*)(p + 230 * MB); // bf16 tanh(xw@dw1), 1 MiB
  ushort_t* Wrb  = (ushort_t*)(p + 232 * MB);
  ushort_t* Wkb  = (ushort_t*)(p + 234 * MB);
  ushort_t* Wvb  = (ushort_t*)(p + 236 * MB);
  ushort_t* Wgb  = (ushort_t*)(p + 238 * MB);
  ushort_t* Wob  = (ushort_t*)(p + 240 * MB);

  const int thr = 256;
  k_f2bf5<<<dim3((Cc * Cc / 4 + 255) / 256, 1, 5), thr, 0, stream>>>(
      Wr, Wk, Wv, Wg, Wo, Wrb, Wkb, Wvb, Wgb, Wob);
  k_prep<<<(397312 + 255) / 256, thr, 0, stream>>>(w2, w1, dw1, x,
                                                   w2t, w1t, dw1t, out + (size_t)BT * Cc);

  k_shift_tanh<<<BT / 64, thr, 0, stream>>>(x, sst, tmx, w1t, t160b);
  k_mix5m<<<dim3(BT / 64, Cc / 64), thr, 0, stream>>>(x, sst, t160b, w2t,
                                                      tmw, tmk, tmv, tmr, tmg,
                                                      xwb, xkb, xvb, xrb, xgb);
  k_tanh_mfma<64, 1><<<BT / 64, thr, 0, stream>>>(xwb, dw1t, t64bf);

  k_gemm4x<<<dim3(BT / 256, Cc / 256, 4), 512, 0, stream>>>(
      xrb, xkb, xvb, xgb, Wrb, Wkb, Wvb, Wgb, rbb, kbb, vbuf, gbuf);

  k_preA<<<2048, thr, 0, stream>>>(rbb, kbb, vbuf, t64bf, dw2, tdec, faaaa,
                                   rwbf, kvbf, xgb /*knorm*/, Abf, esum);
  k_scanstate<<<512, 128, 0, stream>>>(wkv0, kvbf, esum, statebuf,
                                       out + (size_t)BT * Cc + (size_t)Bc * Cc);
  k_preB<<<2048, thr, 0, stream>>>(xgb /*knorm*/, vbuf, Abf, rwbf, statebuf, ltemp,
                                   gbuf, lng, lnb, xgb /*ong*/);

  k_gemm_bm64<<<dim3(BT / 64, Cc / 128), thr, 0, stream>>>(xgb, Wob, out);
}

// Round 8
// 398.172 us; speedup vs baseline: 1.0679x; 1.0679x over previous
//
#include <hip/hip_runtime.h>
#include <cstdint>
#include <cstddef>

typedef unsigned short ushort_t;
#define DEVI __device__ __forceinline__

constexpr int Bc = 4, Tc = 2048, Cc = 1024, Hc = 16;
constexpr int BT = Bc * Tc;           // 8192
constexpr int NCHUNK = Tc / 64;       // 32

using f32x4  = __attribute__((ext_vector_type(4))) float;
using bf16x8 = __attribute__((ext_vector_type(8))) __bf16;

DEVI ushort_t f2bf(float f) {
  union { float f; unsigned u; } v; v.f = f;
  unsigned r = v.u + 0x7fffu + ((v.u >> 16) & 1u);
  return (ushort_t)(r >> 16);
}
DEVI float bf2f(ushort_t u) {
  union { unsigned u; float f; } v; v.u = ((unsigned)u) << 16; return v.f;
}
DEVI float clip30(float x) { return fminf(fmaxf(x, -30.f), 30.f); }
DEVI float clip20(float x) { return fminf(fmaxf(x, -20.f), 20.f); }

DEVI float4 bf4up(uint2 r) {
  float4 v;
  v.x = bf2f((ushort_t)(r.x & 0xffff)); v.y = bf2f((ushort_t)(r.x >> 16));
  v.z = bf2f((ushort_t)(r.y & 0xffff)); v.w = bf2f((ushort_t)(r.y >> 16));
  return v;
}
DEVI uint2 f4pk(float4 v) {
  uint2 r;
  r.x = (unsigned)f2bf(v.x) | ((unsigned)f2bf(v.y) << 16);
  r.y = (unsigned)f2bf(v.z) | ((unsigned)f2bf(v.w) << 16);
  return r;
}

DEVI void gload_lds16(const ushort_t* g, ushort_t* l) {
  __builtin_amdgcn_global_load_lds(
      (const __attribute__((address_space(1))) void*)g,
      (__attribute__((address_space(3))) void*)l, 16, 0, 0);
}

#define GETEL(V4, E) ((E) == 0 ? (V4).x : (E) == 1 ? (V4).y : (E) == 2 ? (V4).z : (V4).w)
#define SETEL(V4, E, VAL) do { if ((E) == 0) (V4).x = (VAL); else if ((E) == 1) (V4).y = (VAL); \
                               else if ((E) == 2) (V4).z = (VAL); else (V4).w = (VAL); } while (0)

// one launch: 5 weight matrices f32 -> bf16 (z selects), float4 -> ushort4 vectorized
__global__ void k_f2bf5(const float* __restrict__ i0, const float* __restrict__ i1,
                        const float* __restrict__ i2, const float* __restrict__ i3,
                        const float* __restrict__ i4,
                        ushort_t* __restrict__ o0, ushort_t* __restrict__ o1,
                        ushort_t* __restrict__ o2, ushort_t* __restrict__ o3,
                        ushort_t* __restrict__ o4) {
  int z = blockIdx.z;
  const float* in = (z == 0) ? i0 : (z == 1) ? i1 : (z == 2) ? i2 : (z == 3) ? i3 : i4;
  ushort_t* out   = (z == 0) ? o0 : (z == 1) ? o1 : (z == 2) ? o2 : (z == 3) ? o3 : o4;
  int i = blockIdx.x * 256 + threadIdx.x;
  if (i < Cc * Cc / 4) {
    float4 v = *(const float4*)(in + (size_t)i * 4);
    ushort4 o;
    o.x = f2bf(v.x); o.y = f2bf(v.y); o.z = f2bf(v.z); o.w = f2bf(v.w);
    *(ushort4*)(out + (size_t)i * 4) = o;
  }
}

// merged prep: w2t (160K) | w1t (160K) | dw1t (64K) | xlast (4K) — one launch replaces 4
__global__ void k_prep(const float* __restrict__ w2, const float* __restrict__ w1,
                       const float* __restrict__ dw1, const float* __restrict__ x,
                       ushort_t* __restrict__ w2t, ushort_t* __restrict__ w1t,
                       ushort_t* __restrict__ dw1t, float* __restrict__ xlast) {
  int i = blockIdx.x * 256 + threadIdx.x;
  if (i < 163840) {                       // w2t[c][fd] = bf16(w2[fd][c])
    int c = i / 160, fd = i % 160;
    w2t[i] = f2bf(w2[(size_t)fd * 1024 + c]);
  } else if (i < 327680) {                // w1t[n][r] = bf16(w1[r][n]), w1 is 1024x160
    int j = i - 163840; int n = j >> 10, r = j & 1023;
    w1t[j] = f2bf(w1[(size_t)r * 160 + n]);
  } else if (i < 393216) {                // dw1t[n][r] = bf16(dw1[r][n]), dw1 is 1024x64
    int j = i - 327680; int n = j >> 10, r = j & 1023;
    dw1t[j] = f2bf(dw1[(size_t)r * 64 + n]);
  } else if (i < 397312) {                // xlast
    int j = i - 393216; int b = j >> 10, c = j & 1023;
    xlast[j] = x[((size_t)b * Tc + Tc - 1) * Cc + c];
  }
}

// ---------------- fused token-shift + skinny MFMA GEMM + tanh (NCOLS=160, bf16 out) ----------------
__global__ __launch_bounds__(256) void k_shift_tanh(
    const float* __restrict__ x, const float* __restrict__ sst,
    const float* __restrict__ tmx, const ushort_t* __restrict__ Wt,
    ushort_t* __restrict__ outv) {
  constexpr int NCOLS = 160, NF = NCOLS / 16;
  int tid = threadIdx.x;
  int wave = tid >> 6, lane = tid & 63;
  int row0 = (blockIdx.x * 4 + wave) * 16;
  int lr = lane & 15, lk = (lane >> 4) * 8;
  int rg = row0 + lr;
  int tt = rg & (Tc - 1);
  const float* xrow = x + (size_t)rg * Cc;
  const float* prow = (tt == 0) ? (sst + (size_t)(rg >> 11) * Cc) : (xrow - Cc);
  f32x4 acc[NF];
  #pragma unroll
  for (int n = 0; n < NF; ++n) acc[n] = (f32x4){0.f, 0.f, 0.f, 0.f};
  for (int k0 = 0; k0 < 1024; k0 += 32) {
    int c0 = k0 + lk;
    float4 xa = *(const float4*)(xrow + c0), xb = *(const float4*)(xrow + c0 + 4);
    float4 pa = *(const float4*)(prow + c0), pb = *(const float4*)(prow + c0 + 4);
    float4 ta = *(const float4*)(tmx + c0), tb = *(const float4*)(tmx + c0 + 4);
    union { bf16x8 v; uint2 u[2]; } cv;
    cv.u[0] = f4pk(make_float4(xa.x + (pa.x - xa.x) * ta.x, xa.y + (pa.y - xa.y) * ta.y,
                               xa.z + (pa.z - xa.z) * ta.z, xa.w + (pa.w - xa.w) * ta.w));
    cv.u[1] = f4pk(make_float4(xb.x + (pb.x - xb.x) * tb.x, xb.y + (pb.y - xb.y) * tb.y,
                               xb.z + (pb.z - xb.z) * tb.z, xb.w + (pb.w - xb.w) * tb.w));
    #pragma unroll
    for (int n = 0; n < NF; ++n) {
      bf16x8 b = *(const bf16x8*)&Wt[(size_t)(n * 16 + lr) * 1024 + k0 + lk];
      acc[n] = __builtin_amdgcn_mfma_f32_16x16x32_bf16(cv.v, b, acc[n], 0, 0, 0);
    }
  }
  #pragma unroll
  for (int n = 0; n < NF; ++n) {
    #pragma unroll
    for (int q = 0; q < 4; ++q) {
      int row = row0 + (lane >> 4) * 4 + q;
      size_t oi = (size_t)row * NCOLS + n * 16 + lr;
      outv[oi] = f2bf(tanhf(acc[n][q]));
    }
  }
}

// ---------------- skinny MFMA GEMM + tanh ----------------
template<int NCOLS, int OBF>
__global__ __launch_bounds__(256) void k_tanh_mfma(const ushort_t* __restrict__ A,
                                                   const ushort_t* __restrict__ Wt,
                                                   void* __restrict__ outv) {
  constexpr int NF = NCOLS / 16;
  int tid = threadIdx.x;
  int wave = tid >> 6, lane = tid & 63;
  int row0 = (blockIdx.x * 4 + wave) * 16;
  int lr = lane & 15, lk = (lane >> 4) * 8;
  f32x4 acc[NF];
  #pragma unroll
  for (int n = 0; n < NF; ++n) acc[n] = (f32x4){0.f, 0.f, 0.f, 0.f};
  for (int k0 = 0; k0 < 1024; k0 += 32) {
    bf16x8 a = *(const bf16x8*)&A[(size_t)(row0 + lr) * 1024 + k0 + lk];
    #pragma unroll
    for (int n = 0; n < NF; ++n) {
      bf16x8 b = *(const bf16x8*)&Wt[(size_t)(n * 16 + lr) * 1024 + k0 + lk];
      acc[n] = __builtin_amdgcn_mfma_f32_16x16x32_bf16(a, b, acc[n], 0, 0, 0);
    }
  }
  #pragma unroll
  for (int n = 0; n < NF; ++n) {
    #pragma unroll
    for (int q = 0; q < 4; ++q) {
      int row = row0 + (lane >> 4) * 4 + q;
      size_t oi = (size_t)row * NCOLS + n * 16 + lr;
      float v = tanhf(acc[n][q]);
      if (OBF == 1) ((ushort_t*)outv)[oi] = f2bf(v);
      else          ((float*)outv)[oi] = v;
    }
  }
}

// ---------------- mixer via MFMA; epilogue routed through LDS for coalesced int4 stores ----------------
// (old direct stores were 32B-segment scalar bf16; LDS tiles stride 72 -> <=2-way aliasing
//  on writes (free per m136), 16B-aligned rows for int4 flush; identical f2bf values.)
__global__ __launch_bounds__(256) void k_mix5m(
    const float* __restrict__ x, const float* __restrict__ sst,
    const ushort_t* __restrict__ t160b, const ushort_t* __restrict__ w2t,
    const float* __restrict__ maaw, const float* __restrict__ maak,
    const float* __restrict__ maav, const float* __restrict__ maar,
    const float* __restrict__ maag,
    ushort_t* __restrict__ xw, ushort_t* __restrict__ xk, ushort_t* __restrict__ xv,
    ushort_t* __restrict__ xr, ushort_t* __restrict__ xg) {
  __shared__ __align__(16) ushort_t smem[23040];   // 46080 B: As/Bs (21504 us) | 5x64x72 tiles
  ushort_t* As = smem;
  ushort_t* Bs = smem + 64 * 168;
  ushort_t* sT = smem;                              // reused after MFMA phase
  int tid = threadIdx.x;
  int lane = tid & 63;
  int bRow = blockIdx.x * 64, bCol = blockIdx.y * 64;
  #pragma unroll
  for (int i = 0; i < 5; ++i) {
    int e = tid + i * 256;
    int r = e / 20, cc = (e % 20) * 8;
    *(int4*)&As[r * 168 + cc] = *(const int4*)&t160b[(size_t)(bRow + r) * 160 + cc];
    *(int4*)&Bs[r * 168 + cc] = *(const int4*)&w2t[(size_t)(bCol + r) * 160 + cc];
  }
  __syncthreads();
  int wm = tid >> 7, wn = (tid >> 6) & 1;
  f32x4 acc[5][2][2];
  #pragma unroll
  for (int f = 0; f < 5; ++f)
    #pragma unroll
    for (int m = 0; m < 2; ++m)
      #pragma unroll
      for (int n = 0; n < 2; ++n) acc[f][m][n] = (f32x4){0.f, 0.f, 0.f, 0.f};
  #pragma unroll
  for (int f = 0; f < 5; ++f) {
    bf16x8 af[2], bfv[2];
    #pragma unroll
    for (int m = 0; m < 2; ++m)
      af[m] = *(const bf16x8*)&As[(wm * 32 + m * 16 + (lane & 15)) * 168 + f * 32 + (lane >> 4) * 8];
    #pragma unroll
    for (int n = 0; n < 2; ++n)
      bfv[n] = *(const bf16x8*)&Bs[(wn * 32 + n * 16 + (lane & 15)) * 168 + f * 32 + (lane >> 4) * 8];
    #pragma unroll
    for (int m = 0; m < 2; ++m)
      #pragma unroll
      for (int n = 0; n < 2; ++n)
        acc[f][m][n] = __builtin_amdgcn_mfma_f32_16x16x32_bf16(af[m], bfv[n], acc[f][m][n], 0, 0, 0);
  }
  __syncthreads();   // As/Bs dead -> sT reuse safe
  #pragma unroll
  for (int n = 0; n < 2; ++n) {
    int colL = wn * 32 + n * 16 + (lane & 15);
    int col = bCol + colL;
    float mw_c = maaw[col], mk_c = maak[col], mv_c = maav[col];
    float mr_c = maar[col], mg_c = maag[col];
    #pragma unroll
    for (int m = 0; m < 2; ++m) {
      int rowL0 = wm * 32 + m * 16 + (lane >> 4) * 4;
      #pragma unroll
      for (int q = 0; q < 4; ++q) {
        int rL = rowL0 + q;
        int rg = bRow + rL;
        int tt = rg & (Tc - 1);
        size_t g = (size_t)rg * Cc + col;
        float xv0 = x[g];
        float xprev = (tt == 0) ? sst[(size_t)(rg >> 11) * Cc + col] : x[g - Cc];
        float dv = xprev - xv0;
        sT[0 * 4608 + rL * 72 + colL] = f2bf(xv0 + dv * (mw_c + acc[0][m][n][q]));
        sT[1 * 4608 + rL * 72 + colL] = f2bf(xv0 + dv * (mk_c + acc[1][m][n][q]));
        sT[2 * 4608 + rL * 72 + colL] = f2bf(xv0 + dv * (mv_c + acc[2][m][n][q]));
        sT[3 * 4608 + rL * 72 + colL] = f2bf(xv0 + dv * (mr_c + acc[3][m][n][q]));
        sT[4 * 4608 + rL * 72 + colL] = f2bf(xv0 + dv * (mg_c + acc[4][m][n][q]));
      }
    }
  }
  __syncthreads();
  // coalesced flush: per field 512 int4 chunks (64 rows x 8), 2 per thread
  #pragma unroll
  for (int f = 0; f < 5; ++f) {
    ushort_t* dst = (f == 0) ? xw : (f == 1) ? xk : (f == 2) ? xv : (f == 3) ? xr : xg;
    #pragma unroll
    for (int j = 0; j < 2; ++j) {
      int e = tid + j * 256;
      int r = e >> 3, ch = (e & 7) * 8;
      *(int4*)&dst[(size_t)(bRow + r) * 1024 + bCol + ch] =
          *(const int4*)&sT[f * 4608 + r * 72 + ch];
    }
  }
}

// ---------------- big bf16 MFMA GEMM body: BK=64 (2 stacked 128x32 sub-tiles), swizzled LDS,
// global_load_lds, ONE stage/drain/compute/sync pair per 64-K.
// [R4: 32x32x16 variant = 8.4M bank conflicts; R7: 256² 8-phase = 0 conflicts but 124µs at
//  1 blk/CU — this 16x16x32 / 128² / 2-barrier form at ~109µs, 0 conflicts is the keeper.]
template<int EPI, int OBF>
DEVI void gemm_body(const ushort_t* __restrict__ A, const ushort_t* __restrict__ Wt,
                    void* __restrict__ outv, ushort_t* As, ushort_t* Bs,
                    int bRow, int bCol) {
  int tid = threadIdx.x;
  int wave = tid >> 6, lane = tid & 63;
  int wm = wave >> 1, wn = wave & 1;
  int lr = lane >> 2;
  int lkb = (((lane & 3) ^ ((lane >> 3) & 3))) * 8;   // swizzled source chunk
  int pch = ((lane >> 4) ^ ((lane >> 1) & 3)) * 8;    // physical chunk for fragment reads
  f32x4 zero4 = {0.f, 0.f, 0.f, 0.f};
  f32x4 acc[4][4];
  #pragma unroll
  for (int m = 0; m < 4; ++m)
    #pragma unroll
    for (int n = 0; n < 4; ++n) acc[m][n] = zero4;

#define STAGEK(OFS, K0) do { \
    _Pragma("unroll") \
    for (int i = 0; i < 2; ++i) { \
      int row = (wave + 4 * i) * 16 + lr; \
      gload_lds16(A + (size_t)(bRow + row) * 1024 + (K0) + lkb, &As[(OFS) + (wave + 4 * i) * 512]); \
      gload_lds16(Wt + (size_t)(bCol + row) * 1024 + (K0) + lkb, &Bs[(OFS) + (wave + 4 * i) * 512]); \
    } } while (0)
#define CMP(OFS) do { \
    bf16x8 af[4], bfv[4]; \
    _Pragma("unroll") \
    for (int m = 0; m < 4; ++m) \
      af[m] = *(const bf16x8*)&As[(OFS) + (wm * 64 + m * 16 + (lane & 15)) * 32 + pch]; \
    _Pragma("unroll") \
    for (int n = 0; n < 4; ++n) \
      bfv[n] = *(const bf16x8*)&Bs[(OFS) + (wn * 64 + n * 16 + (lane & 15)) * 32 + pch]; \
    _Pragma("unroll") \
    for (int m = 0; m < 4; ++m) \
      _Pragma("unroll") \
      for (int n = 0; n < 4; ++n) \
        acc[m][n] = __builtin_amdgcn_mfma_f32_16x16x32_bf16(af[m], bfv[n], acc[m][n], 0, 0, 0); \
  } while (0)

  for (int k0 = 0; k0 < 1024; k0 += 64) {
    STAGEK(0, k0);
    STAGEK(4096, k0 + 32);
    __syncthreads();          // single drain (vmcnt(0)) per 64-K
    CMP(0);
    CMP(4096);
    __syncthreads();
  }
#undef STAGEK
#undef CMP

  #pragma unroll
  for (int m = 0; m < 4; ++m) {
    int row = bRow + wm * 64 + m * 16 + (lane >> 4) * 4;
    #pragma unroll
    for (int n = 0; n < 4; ++n) {
      int col = bCol + wn * 64 + n * 16 + (lane & 15);
      #pragma unroll
      for (int q = 0; q < 4; ++q) {
        float v = acc[m][n][q];
        if (EPI == 1) v = v / (1.f + __expf(-v));
        size_t oi = (size_t)(row + q) * 1024 + col;
        if (OBF == 1) ((ushort_t*)outv)[oi] = f2bf(v);
        else          ((float*)outv)[oi] = v;
      }
    }
  }
}

// fused 4-projection GEMM: z selects r/k/v/g (g gets silu); all bf16 out
__global__ __launch_bounds__(256) void k_gemm4(
    const ushort_t* __restrict__ A0, const ushort_t* __restrict__ A1,
    const ushort_t* __restrict__ A2, const ushort_t* __restrict__ A3,
    const ushort_t* __restrict__ W0, const ushort_t* __restrict__ W1,
    const ushort_t* __restrict__ W2, const ushort_t* __restrict__ W3,
    ushort_t* __restrict__ O0, ushort_t* __restrict__ O1,
    ushort_t* __restrict__ O2, ushort_t* __restrict__ O3) {
  __shared__ __align__(16) ushort_t As[2 * 128 * 32];
  __shared__ __align__(16) ushort_t Bs[2 * 128 * 32];
  int z = blockIdx.z;
  const ushort_t* A  = (z == 0) ? A0 : (z == 1) ? A1 : (z == 2) ? A2 : A3;
  const ushort_t* Wt = (z == 0) ? W0 : (z == 1) ? W1 : (z == 2) ? W2 : W3;
  ushort_t* out      = (z == 0) ? O0 : (z == 1) ? O1 : (z == 2) ? O2 : O3;
  if (z == 3) gemm_body<1, 1>(A, Wt, out, As, Bs, blockIdx.x * 128, blockIdx.y * 128);
  else        gemm_body<0, 1>(A, Wt, out, As, Bs, blockIdx.x * 128, blockIdx.y * 128);
}

// ---------------- Wo GEMM, 64x128 tiles: 1024 blocks -> 4 blocks/CU residency ----------------
__global__ __launch_bounds__(256) void k_gemm_bm64(const ushort_t* __restrict__ A,
                                                   const ushort_t* __restrict__ Wt,
                                                   float* __restrict__ out) {
  __shared__ __align__(16) ushort_t As[2 * 64 * 32];
  __shared__ __align__(16) ushort_t Bs[2 * 128 * 32];
  int tid = threadIdx.x;
  int wave = tid >> 6, lane = tid & 63;
  int lr = lane >> 2;
  int lkb = (((lane & 3) ^ ((lane >> 3) & 3))) * 8;
  int pch = ((lane >> 4) ^ ((lane >> 1) & 3)) * 8;
  int bRow = blockIdx.x * 64, bCol = blockIdx.y * 128;
  f32x4 acc[4][2];
  #pragma unroll
  for (int m = 0; m < 4; ++m)
    #pragma unroll
    for (int n = 0; n < 2; ++n) acc[m][n] = (f32x4){0.f, 0.f, 0.f, 0.f};

#define STAGEK64(OA, OB, K0) do { \
    { int row = wave * 16 + lr; \
      gload_lds16(A + (size_t)(bRow + row) * 1024 + (K0) + lkb, &As[(OA) + wave * 512]); } \
    _Pragma("unroll") \
    for (int i = 0; i < 2; ++i) { \
      int row = (wave + 4 * i) * 16 + lr; \
      gload_lds16(Wt + (size_t)(bCol + row) * 1024 + (K0) + lkb, &Bs[(OB) + (wave + 4 * i) * 512]); \
    } } while (0)
#define CMP64(OA, OB) do { \
    bf16x8 af[4], bfv[2]; \
    _Pragma("unroll") \
    for (int m = 0; m < 4; ++m) \
      af[m] = *(const bf16x8*)&As[(OA) + (m * 16 + (lane & 15)) * 32 + pch]; \
    _Pragma("unroll") \
    for (int n = 0; n < 2; ++n) \
      bfv[n] = *(const bf16x8*)&Bs[(OB) + (wave * 32 + n * 16 + (lane & 15)) * 32 + pch]; \
    _Pragma("unroll") \
    for (int m = 0; m < 4; ++m) \
      _Pragma("unroll") \
      for (int n = 0; n < 2; ++n) \
        acc[m][n] = __builtin_amdgcn_mfma_f32_16x16x32_bf16(af[m], bfv[n], acc[m][n], 0, 0, 0); \
  } while (0)

  for (int k0 = 0; k0 < 1024; k0 += 64) {
    STAGEK64(0, 0, k0);
    STAGEK64(2048, 4096, k0 + 32);
    __syncthreads();
    CMP64(0, 0);
    CMP64(2048, 4096);
    __syncthreads();
  }
#undef STAGEK64
#undef CMP64

  #pragma unroll
  for (int m = 0; m < 4; ++m) {
    int row = bRow + m * 16 + (lane >> 4) * 4;
    #pragma unroll
    for (int n = 0; n < 2; ++n) {
      int col = bCol + wave * 32 + n * 16 + (lane & 15);
      #pragma unroll
      for (int q = 0; q < 4; ++q)
        out[(size_t)(row + q) * 1024 + col] = acc[m][n][q];
    }
  }
}

// ---------------- preA: wlog via MFMA, cumsum/esum, RW, A(MFMA), knorm, KV(MFMA) ----------------
__global__ __launch_bounds__(256) void k_preA(
    const ushort_t* __restrict__ rbuf, const ushort_t* __restrict__ kbuf,
    const ushort_t* __restrict__ vbf,
    const ushort_t* __restrict__ t64bf, const float* __restrict__ dw2,
    const float* __restrict__ tdec, const float* __restrict__ faaaa,
    ushort_t* __restrict__ rwbf, ushort_t* __restrict__ kvbf, ushort_t* __restrict__ knbuf,
    ushort_t* __restrict__ Abf, float* __restrict__ esum) {
  __shared__ __align__(16) char ubuf[16640 + 9216 + 9216];
  float* wc = (float*)ubuf;
  ushort_t* sA = (ushort_t*)(ubuf + 16640);
  ushort_t* sB = (ushort_t*)(ubuf + 16640 + 9216);
  __shared__ float sred[4 * 64];
  __shared__ float sdiag[64];
  __shared__ float snrm[64];
  int bx = blockIdx.x;
  int ci = bx & 31, bh = bx >> 5;
  int b = bh >> 4, h = bh & 15;
  int tid = threadIdx.x;
  int w = tid >> 6, lane = tid & 63;
  int c = lane;
  int row0g = b * Tc + ci * 64;
  size_t base = (size_t)row0g * Cc + (size_t)h * 64;

  #pragma unroll
  for (int j = 0; j < 2; ++j) {
    int e = tid + j * 256; int r = e >> 3, cc = (e & 7) * 8;
    *(int4*)&sA[r * 72 + cc] = *(const int4*)&t64bf[(size_t)(row0g + r) * 64 + cc];
  }
  for (int i = 0; i < 16; ++i) {
    int e = tid + i * 256; int r = e >> 6, cc = e & 63;
    sB[cc * 72 + r] = f2bf(dw2[(size_t)r * Cc + h * 64 + cc]);
  }
  float rv[16], kv[16];
  #pragma unroll
  for (int i = 0; i < 16; ++i) {
    size_t g = base + (size_t)(w * 16 + i) * Cc + c;
    rv[i] = bf2f(rbuf[g]); kv[i] = bf2f(kbuf[g]);
  }
  __syncthreads();
  {
    int rbase = w * 16;
    bf16x8 a0 = *(const bf16x8*)&sA[(rbase + (lane & 15)) * 72 + (lane >> 4) * 8];
    bf16x8 a1 = *(const bf16x8*)&sA[(rbase + (lane & 15)) * 72 + 32 + (lane >> 4) * 8];
    #pragma unroll
    for (int ct = 0; ct < 4; ++ct) {
      bf16x8 b0 = *(const bf16x8*)&sB[(ct * 16 + (lane & 15)) * 72 + (lane >> 4) * 8];
      bf16x8 b1 = *(const bf16x8*)&sB[(ct * 16 + (lane & 15)) * 72 + 32 + (lane >> 4) * 8];
      f32x4 acc = {0.f, 0.f, 0.f, 0.f};
      acc = __builtin_amdgcn_mfma_f32_16x16x32_bf16(a0, b0, acc, 0, 0, 0);
      acc = __builtin_amdgcn_mfma_f32_16x16x32_bf16(a1, b1, acc, 0, 0, 0);
      int s = ct * 16 + (lane & 15);
      #pragma unroll
      for (int q = 0; q < 4; ++q) {
        int t = rbase + (lane >> 4) * 4 + q;
        wc[t * 65 + s] = acc[q];
      }
    }
  }
  __syncthreads();
  float wv[16];
  {
    float td = tdec[h * 64 + c];
    #pragma unroll
    for (int i = 0; i < 16; ++i)
      wv[i] = -__expf(td + wc[(w * 16 + i) * 65 + c]);
  }
  {
    float s = 0.f;
    #pragma unroll
    for (int i = 0; i < 16; ++i) s += wv[i];
    sred[w * 64 + c] = s;
  }
  __syncthreads();
  {
    float run = 0.f;
    for (int ww = 0; ww < w; ++ww) run += sred[ww * 64 + c];
    #pragma unroll
    for (int i = 0; i < 16; ++i) {
      run += wv[i]; wv[i] = run;
      wc[(w * 16 + i) * 65 + c] = run;
    }
    if (w == 3) esum[((size_t)bh * 32 + ci) * 64 + c] = __expf(run);
  }
  {
    float u_c = faaaa[h * 64 + c];
    #pragma unroll
    for (int i = 0; i < 16; ++i) {
      float p = rv[i] * kv[i] * u_c;
      float n2 = kv[i] * kv[i];
      #pragma unroll
      for (int o = 32; o; o >>= 1) { p += __shfl_xor(p, o, 64); n2 += __shfl_xor(n2, o, 64); }
      if (lane == 0) {
        sdiag[w * 16 + i] = p;
        snrm[w * 16 + i] = 1.f / fmaxf(sqrtf(n2), 1e-12f);
      }
    }
  }
  __syncthreads();
  float off32 = wc[31 * 65 + c];
  float wc63 = wc[63 * 65 + c];
  #pragma unroll
  for (int i = 0; i < 16; ++i) {
    int t = w * 16 + i;
    size_t g = base + (size_t)t * Cc + c;
    float wsh = (i == 0) ? ((w == 0) ? 0.f : wc[(t - 1) * 65 + c]) : wv[i - 1];
    rwbf[g] = f2bf(rv[i] * __expf(clip30(wsh)));
    sA[t * 72 + c] = f2bf(rv[i] * __expf(clip30(wsh - off32)));
    sB[t * 72 + c] = f2bf(kv[i] * __expf(clip30(off32 - wv[i])));
    knbuf[g] = f2bf(kv[i] * snrm[t]);
  }
  __syncthreads();
  {
    int rbase = w * 16;
    bf16x8 a0 = *(const bf16x8*)&sA[(rbase + (lane & 15)) * 72 + (lane >> 4) * 8];
    bf16x8 a1 = *(const bf16x8*)&sA[(rbase + (lane & 15)) * 72 + 32 + (lane >> 4) * 8];
    #pragma unroll
    for (int ct = 0; ct < 4; ++ct) {
      bf16x8 b0 = *(const bf16x8*)&sB[(ct * 16 + (lane & 15)) * 72 + (lane >> 4) * 8];
      bf16x8 b1 = *(const bf16x8*)&sB[(ct * 16 + (lane & 15)) * 72 + 32 + (lane >> 4) * 8];
      f32x4 acc = {0.f, 0.f, 0.f, 0.f};
      acc = __builtin_amdgcn_mfma_f32_16x16x32_bf16(a0, b0, acc, 0, 0, 0);
      acc = __builtin_amdgcn_mfma_f32_16x16x32_bf16(a1, b1, acc, 0, 0, 0);
      int s = ct * 16 + (lane & 15);
      #pragma unroll
      for (int q = 0; q < 4; ++q) {
        int t = rbase + (lane >> 4) * 4 + q;
        float val = (t > s) ? acc[q] : ((t == s) ? sdiag[t] : 0.f);
        Abf[(size_t)bx * 4096 + t * 64 + s] = f2bf(val);
      }
    }
  }
  __syncthreads();
  #pragma unroll
  for (int i = 0; i < 16; ++i) {
    int t = w * 16 + i;
    size_t g = base + (size_t)t * Cc + c;
    sA[c * 72 + t] = f2bf(kv[i] * __expf(clip30(wc63 - wv[i])));
    sB[c * 72 + t] = vbf[g];
  }
  __syncthreads();
  {
    int rbase = w * 16;
    bf16x8 a0 = *(const bf16x8*)&sA[(rbase + (lane & 15)) * 72 + (lane >> 4) * 8];
    bf16x8 a1 = *(const bf16x8*)&sA[(rbase + (lane & 15)) * 72 + 32 + (lane >> 4) * 8];
    #pragma unroll
    for (int ct = 0; ct < 4; ++ct) {
      bf16x8 b0 = *(const bf16x8*)&sB[(ct * 16 + (lane & 15)) * 72 + (lane >> 4) * 8];
      bf16x8 b1 = *(const bf16x8*)&sB[(ct * 16 + (lane & 15)) * 72 + 32 + (lane >> 4) * 8];
      f32x4 acc = {0.f, 0.f, 0.f, 0.f};
      acc = __builtin_amdgcn_mfma_f32_16x16x32_bf16(a0, b0, acc, 0, 0, 0);
      acc = __builtin_amdgcn_mfma_f32_16x16x32_bf16(a1, b1, acc, 0, 0, 0);
      int j = ct * 16 + (lane & 15);
      #pragma unroll
      for (int q = 0; q < 4; ++q) {
        int ii = rbase + (lane >> 4) * 4 + q;
        kvbf[base + (size_t)ii * Cc + j] = f2bf(acc[q]);
      }
    }
  }
}

// ---------------- preB: P(MFMA), static-register GJ solve, y = A@X + RW@state, fused GroupNorm*g ----------------
__global__ __launch_bounds__(256) void k_preB(
    const ushort_t* __restrict__ knbuf, const ushort_t* __restrict__ vbf,
    const ushort_t* __restrict__ Abf, const ushort_t* __restrict__ rwbf,
    const ushort_t* __restrict__ statebuf, const float* __restrict__ ltemp,
    const ushort_t* __restrict__ gbuf, const float* __restrict__ gamma,
    const float* __restrict__ beta, ushort_t* __restrict__ ong) {
  __shared__ __align__(16) ushort_t sKX[64 * 72];
  __shared__ __align__(16) ushort_t sAb[64 * 72];
  __shared__ __align__(16) char ubuf[64 * 72 * 2 * 2];
  __shared__ __align__(16) float pivbuf[2][192];
  __shared__ float colbuf[2][64];
  __shared__ float diagbuf[64];
  float* sP = (float*)ubuf;
  ushort_t* sRW = (ushort_t*)ubuf;
  ushort_t* sSTt = (ushort_t*)(ubuf + 64 * 72 * 2);

  int bx = blockIdx.x;
  int ci = bx & 31, bh = bx >> 5;
  int b = bh >> 4, h = bh & 15;
  int tid = threadIdx.x;
  int w = tid >> 6, lane = tid & 63;
  int rg = tid >> 4, cg = tid & 15;
  size_t base = ((size_t)(b * Tc + ci * 64)) * Cc + (size_t)h * 64;

  #pragma unroll
  for (int j = 0; j < 2; ++j) {
    int e = tid + j * 256;
    int r = e >> 3, cc = (e & 7) * 8;
    *(int4*)&sKX[r * 72 + cc] = *(const int4*)&knbuf[base + (size_t)r * Cc + cc];
    *(int4*)&sAb[r * 72 + cc] = *(const int4*)&Abf[(size_t)bx * 4096 + (size_t)r * 64 + cc];
  }
  float4 A0, A1, A2, A3, B0, B1, B2, B3;
  if (cg >= 8) {
#define LDV(R, AR, BR) do { \
      int4 raw = *(const int4*)(vbf + base + (size_t)(4 * rg + (R)) * Cc + (cg - 8) * 8); \
      (AR).x = bf2f((ushort_t)(raw.x & 0xffff)); (AR).y = bf2f((ushort_t)((unsigned)raw.x >> 16)); \
      (AR).z = bf2f((ushort_t)(raw.y & 0xffff)); (AR).w = bf2f((ushort_t)((unsigned)raw.y >> 16)); \
      (BR).x = bf2f((ushort_t)(raw.z & 0xffff)); (BR).y = bf2f((ushort_t)((unsigned)raw.z >> 16)); \
      (BR).z = bf2f((ushort_t)(raw.w & 0xffff)); (BR).w = bf2f((ushort_t)((unsigned)raw.w >> 16)); \
    } while (0)
    LDV(0, A0, B0); LDV(1, A1, B1); LDV(2, A2, B2); LDV(3, A3, B3);
#undef LDV
  }
  __syncthreads();
  float temp = log1pf(__expf(ltemp[h]));
  {
    int rbase = w * 16;
    bf16x8 a0 = *(const bf16x8*)&sKX[(rbase + (lane & 15)) * 72 + (lane >> 4) * 8];
    bf16x8 a1 = *(const bf16x8*)&sKX[(rbase + (lane & 15)) * 72 + 32 + (lane >> 4) * 8];
    #pragma unroll
    for (int ct = 0; ct < 4; ++ct) {
      bf16x8 b0 = *(const bf16x8*)&sKX[(ct * 16 + (lane & 15)) * 72 + (lane >> 4) * 8];
      bf16x8 b1 = *(const bf16x8*)&sKX[(ct * 16 + (lane & 15)) * 72 + 32 + (lane >> 4) * 8];
      f32x4 acc = {0.f, 0.f, 0.f, 0.f};
      acc = __builtin_amdgcn_mfma_f32_16x16x32_bf16(a0, b0, acc, 0, 0, 0);
      acc = __builtin_amdgcn_mfma_f32_16x16x32_bf16(a1, b1, acc, 0, 0, 0);
      int s = ct * 16 + (lane & 15);
      #pragma unroll
      for (int q = 0; q < 4; ++q) {
        int t = rbase + (lane >> 4) * 4 + q;
        sP[t * 68 + s] = ((t == s) ? 1.f : 0.f) + __expf(clip20(temp * acc[q]));
      }
    }
  }
  __syncthreads();
  if (cg < 8) {
    A0 = *(float4*)&sP[(4 * rg + 0) * 68 + cg * 8]; B0 = *(float4*)&sP[(4 * rg + 0) * 68 + cg * 8 + 4];
    A1 = *(float4*)&sP[(4 * rg + 1) * 68 + cg * 8]; B1 = *(float4*)&sP[(4 * rg + 1) * 68 + cg * 8 + 4];
    A2 = *(float4*)&sP[(4 * rg + 2) * 68 + cg * 8]; B2 = *(float4*)&sP[(4 * rg + 2) * 68 + cg * 8 + 4];
    A3 = *(float4*)&sP[(4 * rg + 3) * 68 + cg * 8]; B3 = *(float4*)&sP[(4 * rg + 3) * 68 + cg * 8 + 4];
  }
  __syncthreads();
  #pragma unroll
  for (int j = 0; j < 2; ++j) {
    int e = tid + j * 256;
    int r = e >> 3, cc = (e & 7) * 8;
    *(int4*)&sRW[r * 72 + cc] = *(const int4*)&rwbf[base + (size_t)r * Cc + cc];
  }
  {
    const ushort_t* sb = statebuf + ((size_t)bh * 32 + ci) * 4096;
    #pragma unroll
    for (int i = 0; i < 16; ++i) {
      int e = tid + i * 256;
      int r = e >> 6, c = e & 63;
      sSTt[c * 72 + r] = sb[e];
    }
  }
#define UPD(MA, MB, F) do { \
    (MA).x -= (F) * p0_.x; (MA).y -= (F) * p0_.y; (MA).z -= (F) * p0_.z; (MA).w -= (F) * p0_.w; \
    (MB).x -= (F) * p1_.x; (MB).y -= (F) * p1_.y; (MB).z -= (F) * p1_.z; (MB).w -= (F) * p1_.w; \
  } while (0)
#define GJSTEP(JL, PRA, PRB, H0, H1, H2, H3) do { \
    int j_ = jh * 8 + (JL); \
    if (rg == (j_ >> 2)) { \
      *(float4*)&pivbuf[(JL) & 1][cg * 12]     = (PRA); \
      *(float4*)&pivbuf[(JL) & 1][cg * 12 + 4] = (PRB); \
    } \
    if (cg == jh) { \
      float4 cv_; \
      cv_.x = GETEL(H0, (JL) & 3); \
      cv_.y = GETEL(H1, (JL) & 3); \
      cv_.z = GETEL(H2, (JL) & 3); \
      cv_.w = GETEL(H3, (JL) & 3); \
      *(float4*)&colbuf[(JL) & 1][rg * 4] = cv_; \
    } \
    __syncthreads(); \
    float pd_ = pivbuf[(JL) & 1][(j_ >> 3) * 12 + (j_ & 7)]; \
    float4 fv_ = *(float4*)&colbuf[(JL) & 1][rg * 4]; \
    float4 p0_ = *(float4*)&pivbuf[(JL) & 1][cg * 12]; \
    float4 p1_ = *(float4*)&pivbuf[(JL) & 1][cg * 12 + 4]; \
    if (rg == (j_ >> 2)) SETEL(fv_, (JL) & 3, 0.f); \
    float inv_ = 1.f / pd_; \
    float f0_ = fv_.x * inv_, f1_ = fv_.y * inv_, f2_ = fv_.z * inv_, f3_ = fv_.w * inv_; \
    UPD(A0, B0, f0_); UPD(A1, B1, f1_); UPD(A2, B2, f2_); UPD(A3, B3, f3_); \
  } while (0)
  for (int jh = 0; jh < 8; ++jh) {
    GJSTEP(0, A0, B0, A0, A1, A2, A3);
    GJSTEP(1, A1, B1, A0, A1, A2, A3);
    GJSTEP(2, A2, B2, A0, A1, A2, A3);
    GJSTEP(3, A3, B3, A0, A1, A2, A3);
    GJSTEP(4, A0, B0, B0, B1, B2, B3);
    GJSTEP(5, A1, B1, B0, B1, B2, B3);
    GJSTEP(6, A2, B2, B0, B1, B2, B3);
    GJSTEP(7, A3, B3, B0, B1, B2, B3);
  }
#undef GJSTEP
#undef UPD
  if (cg == (rg >> 1)) {
    float4 h0 = (rg & 1) ? B0 : A0;
    float4 h1 = (rg & 1) ? B1 : A1;
    float4 h2 = (rg & 1) ? B2 : A2;
    float4 h3 = (rg & 1) ? B3 : A3;
    *(float4*)&diagbuf[rg * 4] = make_float4(h0.x, h1.y, h2.z, h3.w);
  }
  __syncthreads();
  if (cg >= 8) {
    float4 dg = *(float4*)&diagbuf[rg * 4];
#define WRX(R, AR, BR, IR) do { \
      int cb_ = (cg - 8) * 8; \
      sKX[(cb_ + 0) * 72 + 4 * rg + (R)] = f2bf((AR).x * (IR)); \
      sKX[(cb_ + 1) * 72 + 4 * rg + (R)] = f2bf((AR).y * (IR)); \
      sKX[(cb_ + 2) * 72 + 4 * rg + (R)] = f2bf((AR).z * (IR)); \
      sKX[(cb_ + 3) * 72 + 4 * rg + (R)] = f2bf((AR).w * (IR)); \
      sKX[(cb_ + 4) * 72 + 4 * rg + (R)] = f2bf((BR).x * (IR)); \
      sKX[(cb_ + 5) * 72 + 4 * rg + (R)] = f2bf((BR).y * (IR)); \
      sKX[(cb_ + 6) * 72 + 4 * rg + (R)] = f2bf((BR).z * (IR)); \
      sKX[(cb_ + 7) * 72 + 4 * rg + (R)] = f2bf((BR).w * (IR)); \
    } while (0)
    WRX(0, A0, B0, 1.f / dg.x);
    WRX(1, A1, B1, 1.f / dg.y);
    WRX(2, A2, B2, 1.f / dg.z);
    WRX(3, A3, B3, 1.f / dg.w);
#undef WRX
  }
  __syncthreads();
  {
    int rbase = w * 16;
    bf16x8 aA0 = *(const bf16x8*)&sAb[(rbase + (lane & 15)) * 72 + (lane >> 4) * 8];
    bf16x8 aA1 = *(const bf16x8*)&sAb[(rbase + (lane & 15)) * 72 + 32 + (lane >> 4) * 8];
    bf16x8 aR0 = *(const bf16x8*)&sRW[(rbase + (lane & 15)) * 72 + (lane >> 4) * 8];
    bf16x8 aR1 = *(const bf16x8*)&sRW[(rbase + (lane & 15)) * 72 + 32 + (lane >> 4) * 8];
    f32x4 yv[4];
    #pragma unroll
    for (int ct = 0; ct < 4; ++ct) {
      bf16x8 bX0 = *(const bf16x8*)&sKX[(ct * 16 + (lane & 15)) * 72 + (lane >> 4) * 8];
      bf16x8 bX1 = *(const bf16x8*)&sKX[(ct * 16 + (lane & 15)) * 72 + 32 + (lane >> 4) * 8];
      bf16x8 bS0 = *(const bf16x8*)&sSTt[(ct * 16 + (lane & 15)) * 72 + (lane >> 4) * 8];
      bf16x8 bS1 = *(const bf16x8*)&sSTt[(ct * 16 + (lane & 15)) * 72 + 32 + (lane >> 4) * 8];
      f32x4 acc = {0.f, 0.f, 0.f, 0.f};
      acc = __builtin_amdgcn_mfma_f32_16x16x32_bf16(aA0, bX0, acc, 0, 0, 0);
      acc = __builtin_amdgcn_mfma_f32_16x16x32_bf16(aA1, bX1, acc, 0, 0, 0);
      acc = __builtin_amdgcn_mfma_f32_16x16x32_bf16(aR0, bS0, acc, 0, 0, 0);
      acc = __builtin_amdgcn_mfma_f32_16x16x32_bf16(aR1, bS1, acc, 0, 0, 0);
      yv[ct] = acc;
    }
    #pragma unroll
    for (int q = 0; q < 4; ++q) {
      float s1 = yv[0][q] + yv[1][q] + yv[2][q] + yv[3][q];
      float s2 = yv[0][q] * yv[0][q] + yv[1][q] * yv[1][q] +
                 yv[2][q] * yv[2][q] + yv[3][q] * yv[3][q];
      #pragma unroll
      for (int o = 1; o < 16; o <<= 1) {
        s1 += __shfl_xor(s1, o, 64);
        s2 += __shfl_xor(s2, o, 64);
      }
      float mu = s1 * (1.f / 64.f);
      float var = s2 * (1.f / 64.f) - mu * mu;
      float rs = rsqrtf(var + 6.4e-4f);
      int t = rbase + (lane >> 4) * 4 + q;
      #pragma unroll
      for (int ct = 0; ct < 4; ++ct) {
        int cc = ct * 16 + (lane & 15);
        size_t g = base + (size_t)t * Cc + cc;
        float yn = (yv[ct][q] - mu) * rs;
        float o = (yn * gamma[h * 64 + cc] + beta[h * 64 + cc]) * bf2f(gbuf[g]);
        ong[g] = f2bf(o);
      }
    }
  }
}

// ---------------- state recurrence only (bf16 kv/statebuf, f32 registers) ----------------
__global__ __launch_bounds__(128) void k_scanstate(
    const float* __restrict__ wkv0, const ushort_t* __restrict__ kvbf,
    const float* __restrict__ esum, ushort_t* __restrict__ statebuf,
    float* __restrict__ stout) {
  int bh = blockIdx.x >> 3;
  int rg = blockIdx.x & 7;
  int b = bh >> 4, h = bh & 15;
  int tid = threadIdx.x;
  int r = rg * 8 + (tid >> 4);
  int c0 = (tid & 15) * 4;
  float4 st = *(const float4*)(wkv0 + ((size_t)bh * 64 + r) * 64 + c0);
  size_t kvb = (size_t)(b * Tc) * Cc + (size_t)h * 64 + (size_t)r * Cc + c0;
  constexpr int PF = 4;
  uint2 kvn[PF];
  float4 evn[PF];
  #pragma unroll
  for (int j = 0; j < PF; ++j) {
    kvn[j] = *(const uint2*)(kvbf + kvb + (size_t)j * 64 * Cc);
    evn[j] = *(const float4*)(esum + ((size_t)bh * 32 + j) * 64 + c0);
  }
  #pragma unroll
  for (int ci = 0; ci < NCHUNK; ++ci) {
    *(uint2*)(statebuf + ((size_t)bh * 32 + ci) * 4096 + (size_t)r * 64 + c0) = f4pk(st);
    float4 kv = bf4up(kvn[ci & 3]);
    float4 ev = evn[ci & 3];
    if (ci + PF < NCHUNK) {
      kvn[ci & 3] = *(const uint2*)(kvbf + kvb + (size_t)(ci + PF) * 64 * Cc);
      evn[ci & 3] = *(const float4*)(esum + ((size_t)bh * 32 + ci + PF) * 64 + c0);
    }
    st.x = st.x * ev.x + kv.x;
    st.y = st.y * ev.y + kv.y;
    st.z = st.z * ev.z + kv.z;
    st.w = st.w * ev.w + kv.w;
  }
  *(float4*)(stout + ((size_t)bh * 64 + r) * 64 + c0) = st;
}

// ---------------- launcher ----------------
extern "C" void kernel_launch(void* const* d_in, const int* in_sizes, int n_in,
                              void* d_out, int out_size, void* d_ws, size_t ws_size,
                              hipStream_t stream) {
  (void)in_sizes; (void)n_in; (void)out_size;
  const float* x     = (const float*)d_in[0];
  const float* sst   = (const float*)d_in[1];
  const float* wkv0  = (const float*)d_in[2];
  const float* tmx   = (const float*)d_in[3];
  const float* tmw   = (const float*)d_in[4];
  const float* tmk   = (const float*)d_in[5];
  const float* tmv   = (const float*)d_in[6];
  const float* tmr   = (const float*)d_in[7];
  const float* tmg   = (const float*)d_in[8];
  const float* w1    = (const float*)d_in[9];
  const float* w2    = (const float*)d_in[10];
  const float* tdec  = (const float*)d_in[11];
  const float* dw1   = (const float*)d_in[12];
  const float* dw2   = (const float*)d_in[13];
  const float* faaaa = (const float*)d_in[14];
  const float* ltemp = (const float*)d_in[15];
  const float* Wr    = (const float*)d_in[16];
  const float* Wk    = (const float*)d_in[17];
  const float* Wv    = (const float*)d_in[18];
  const float* Wg    = (const float*)d_in[19];
  const float* Wo    = (const float*)d_in[20];
  const float* lng   = (const float*)d_in[21];
  const float* lnb   = (const float*)d_in[22];
  float* out = (float*)d_out;

  const size_t MB = 1ull << 20;
  const size_t NEED = 242 * MB;
  if (ws_size < NEED) return;

  char* p = (char*)d_ws;
  ushort_t* kbb  = (ushort_t*)(p + 0 * MB);    // bf16 k (GEMM out)
  ushort_t* xwb  = (ushort_t*)(p + 16 * MB);   // xw bf16 -> rbb
  ushort_t* rbb  = (ushort_t*)(p + 16 * MB);   // bf16 r (GEMM out), overlays xwb
  ushort_t* kvbf = (ushort_t*)(p + 32 * MB);   // KV bf16 (16 MiB)
  ushort_t* statebuf = (ushort_t*)(p + 96 * MB); // bf16 (16 MiB)
  ushort_t* vbuf = (ushort_t*)(p + 128 * MB);  // v (bf16)
  ushort_t* gbuf = (ushort_t*)(p + 144 * MB);  // silu(g) (bf16)
  ushort_t* xkb  = (ushort_t*)(p + 160 * MB);  // -> Abf
  ushort_t* Abf  = (ushort_t*)(p + 160 * MB);
  ushort_t* xvb  = (ushort_t*)(p + 176 * MB);  // -> rwbf
  ushort_t* rwbf = (ushort_t*)(p + 176 * MB);
  ushort_t* xrb  = (ushort_t*)(p + 192 * MB);
  ushort_t* xgb  = (ushort_t*)(p + 208 * MB);  // xg -> knorm -> ong
  ushort_t* t160b = (ushort_t*)(p + 224 * MB);
  float*    esum = (float*)(p + 224 * MB);     // overlays t160b (dead by then)
  ushort_t* w2t  = (ushort_t*)(p + 227 * MB);  // 0.32 MiB
  ushort_t* w1t  = (ushort_t*)(p + 228 * MB);  // 0.32 MiB
  ushort_t* dw1t = (ushort_t*)(p + 229 * MB);  // 0.13 MiB
  ushort_t* t64bf = (ushort_t*)(p + 230 * MB); // bf16 tanh(xw@dw1), 1 MiB
  ushort_t* Wrb  = (ushort_t*)(p + 232 * MB);
  ushort_t* Wkb  = (ushort_t*)(p + 234 * MB);
  ushort_t* Wvb  = (ushort_t*)(p + 236 * MB);
  ushort_t* Wgb  = (ushort_t*)(p + 238 * MB);
  ushort_t* Wob  = (ushort_t*)(p + 240 * MB);

  const int thr = 256;
  k_f2bf5<<<dim3((Cc * Cc / 4 + 255) / 256, 1, 5), thr, 0, stream>>>(
      Wr, Wk, Wv, Wg, Wo, Wrb, Wkb, Wvb, Wgb, Wob);
  k_prep<<<(397312 + 255) / 256, thr, 0, stream>>>(w2, w1, dw1, x,
                                                   w2t, w1t, dw1t, out + (size_t)BT * Cc);

  k_shift_tanh<<<BT / 64, thr, 0, stream>>>(x, sst, tmx, w1t, t160b);
  k_mix5m<<<dim3(BT / 64, Cc / 64), thr, 0, stream>>>(x, sst, t160b, w2t,
                                                      tmw, tmk, tmv, tmr, tmg,
                                                      xwb, xkb, xvb, xrb, xgb);
  k_tanh_mfma<64, 1><<<BT / 64, thr, 0, stream>>>(xwb, dw1t, t64bf);

  k_gemm4<<<dim3(BT / 128, Cc / 128, 4), thr, 0, stream>>>(
      xrb, xkb, xvb, xgb, Wrb, Wkb, Wvb, Wgb, rbb, kbb, vbuf, gbuf);

  k_preA<<<2048, thr, 0, stream>>>(rbb, kbb, vbuf, t64bf, dw2, tdec, faaaa,
                                   rwbf, kvbf, xgb /*knorm*/, Abf, esum);
  k_scanstate<<<512, 128, 0, stream>>>(wkv0, kvbf, esum, statebuf,
                                       out + (size_t)BT * Cc + (size_t)Bc * Cc);
  k_preB<<<2048, thr, 0, stream>>>(xgb /*knorm*/, vbuf, Abf, rwbf, statebuf, ltemp,
                                   gbuf, lng, lnb, xgb /*ong*/);

  k_gemm_bm64<<<dim3(BT / 64, Cc / 128), thr, 0, stream>>>(xgb, Wob, out);
}

// Round 9
// 390.742 us; speedup vs baseline: 1.0883x; 1.0190x over previous
//
#include <hip/hip_runtime.h>
#include <cstdint>
#include <cstddef>

typedef unsigned short ushort_t;
#define DEVI __device__ __forceinline__

constexpr int Bc = 4, Tc = 2048, Cc = 1024, Hc = 16;
constexpr int BT = Bc * Tc;           // 8192
constexpr int NCHUNK = Tc / 64;       // 32

using f32x4  = __attribute__((ext_vector_type(4))) float;
using bf16x8 = __attribute__((ext_vector_type(8))) __bf16;

DEVI ushort_t f2bf(float f) {
  union { float f; unsigned u; } v; v.f = f;
  unsigned r = v.u + 0x7fffu + ((v.u >> 16) & 1u);
  return (ushort_t)(r >> 16);
}
DEVI float bf2f(ushort_t u) {
  union { unsigned u; float f; } v; v.u = ((unsigned)u) << 16; return v.f;
}
DEVI float clip30(float x) { return fminf(fmaxf(x, -30.f), 30.f); }
DEVI float clip20(float x) { return fminf(fmaxf(x, -20.f), 20.f); }

DEVI float4 bf4up(uint2 r) {
  float4 v;
  v.x = bf2f((ushort_t)(r.x & 0xffff)); v.y = bf2f((ushort_t)(r.x >> 16));
  v.z = bf2f((ushort_t)(r.y & 0xffff)); v.w = bf2f((ushort_t)(r.y >> 16));
  return v;
}
DEVI uint2 f4pk(float4 v) {
  uint2 r;
  r.x = (unsigned)f2bf(v.x) | ((unsigned)f2bf(v.y) << 16);
  r.y = (unsigned)f2bf(v.z) | ((unsigned)f2bf(v.w) << 16);
  return r;
}

DEVI void gload_lds16(const ushort_t* g, ushort_t* l) {
  __builtin_amdgcn_global_load_lds(
      (const __attribute__((address_space(1))) void*)g,
      (__attribute__((address_space(3))) void*)l, 16, 0, 0);
}

#define GETEL(V4, E) ((E) == 0 ? (V4).x : (E) == 1 ? (V4).y : (E) == 2 ? (V4).z : (V4).w)
#define SETEL(V4, E, VAL) do { if ((E) == 0) (V4).x = (VAL); else if ((E) == 1) (V4).y = (VAL); \
                               else if ((E) == 2) (V4).z = (VAL); else (V4).w = (VAL); } while (0)

// one launch: 5 weight matrices f32 -> bf16 (z selects), float4 -> ushort4 vectorized
__global__ void k_f2bf5(const float* __restrict__ i0, const float* __restrict__ i1,
                        const float* __restrict__ i2, const float* __restrict__ i3,
                        const float* __restrict__ i4,
                        ushort_t* __restrict__ o0, ushort_t* __restrict__ o1,
                        ushort_t* __restrict__ o2, ushort_t* __restrict__ o3,
                        ushort_t* __restrict__ o4) {
  int z = blockIdx.z;
  const float* in = (z == 0) ? i0 : (z == 1) ? i1 : (z == 2) ? i2 : (z == 3) ? i3 : i4;
  ushort_t* out   = (z == 0) ? o0 : (z == 1) ? o1 : (z == 2) ? o2 : (z == 3) ? o3 : o4;
  int i = blockIdx.x * 256 + threadIdx.x;
  if (i < Cc * Cc / 4) {
    float4 v = *(const float4*)(in + (size_t)i * 4);
    ushort4 o;
    o.x = f2bf(v.x); o.y = f2bf(v.y); o.z = f2bf(v.z); o.w = f2bf(v.w);
    *(ushort4*)(out + (size_t)i * 4) = o;
  }
}

// merged prep: w2t (160K) | w1t (160K) | dw1t (64K) | xlast (4K) — one launch replaces 4
__global__ void k_prep(const float* __restrict__ w2, const float* __restrict__ w1,
                       const float* __restrict__ dw1, const float* __restrict__ x,
                       ushort_t* __restrict__ w2t, ushort_t* __restrict__ w1t,
                       ushort_t* __restrict__ dw1t, float* __restrict__ xlast) {
  int i = blockIdx.x * 256 + threadIdx.x;
  if (i < 163840) {                       // w2t[c][fd] = bf16(w2[fd][c])
    int c = i / 160, fd = i % 160;
    w2t[i] = f2bf(w2[(size_t)fd * 1024 + c]);
  } else if (i < 327680) {                // w1t[n][r] = bf16(w1[r][n]), w1 is 1024x160
    int j = i - 163840; int n = j >> 10, r = j & 1023;
    w1t[j] = f2bf(w1[(size_t)r * 160 + n]);
  } else if (i < 393216) {                // dw1t[n][r] = bf16(dw1[r][n]), dw1 is 1024x64
    int j = i - 327680; int n = j >> 10, r = j & 1023;
    dw1t[j] = f2bf(dw1[(size_t)r * 64 + n]);
  } else if (i < 397312) {                // xlast
    int j = i - 393216; int b = j >> 10, c = j & 1023;
    xlast[j] = x[((size_t)b * Tc + Tc - 1) * Cc + c];
  }
}

// ---------------- fused token-shift + skinny MFMA GEMM + tanh (NCOLS=160, bf16 out) ----------------
__global__ __launch_bounds__(256) void k_shift_tanh(
    const float* __restrict__ x, const float* __restrict__ sst,
    const float* __restrict__ tmx, const ushort_t* __restrict__ Wt,
    ushort_t* __restrict__ outv) {
  constexpr int NCOLS = 160, NF = NCOLS / 16;
  int tid = threadIdx.x;
  int wave = tid >> 6, lane = tid & 63;
  int row0 = (blockIdx.x * 4 + wave) * 16;
  int lr = lane & 15, lk = (lane >> 4) * 8;
  int rg = row0 + lr;
  int tt = rg & (Tc - 1);
  const float* xrow = x + (size_t)rg * Cc;
  const float* prow = (tt == 0) ? (sst + (size_t)(rg >> 11) * Cc) : (xrow - Cc);
  f32x4 acc[NF];
  #pragma unroll
  for (int n = 0; n < NF; ++n) acc[n] = (f32x4){0.f, 0.f, 0.f, 0.f};
  for (int k0 = 0; k0 < 1024; k0 += 32) {
    int c0 = k0 + lk;
    float4 xa = *(const float4*)(xrow + c0), xb = *(const float4*)(xrow + c0 + 4);
    float4 pa = *(const float4*)(prow + c0), pb = *(const float4*)(prow + c0 + 4);
    float4 ta = *(const float4*)(tmx + c0), tb = *(const float4*)(tmx + c0 + 4);
    union { bf16x8 v; uint2 u[2]; } cv;
    cv.u[0] = f4pk(make_float4(xa.x + (pa.x - xa.x) * ta.x, xa.y + (pa.y - xa.y) * ta.y,
                               xa.z + (pa.z - xa.z) * ta.z, xa.w + (pa.w - xa.w) * ta.w));
    cv.u[1] = f4pk(make_float4(xb.x + (pb.x - xb.x) * tb.x, xb.y + (pb.y - xb.y) * tb.y,
                               xb.z + (pb.z - xb.z) * tb.z, xb.w + (pb.w - xb.w) * tb.w));
    #pragma unroll
    for (int n = 0; n < NF; ++n) {
      bf16x8 b = *(const bf16x8*)&Wt[(size_t)(n * 16 + lr) * 1024 + k0 + lk];
      acc[n] = __builtin_amdgcn_mfma_f32_16x16x32_bf16(cv.v, b, acc[n], 0, 0, 0);
    }
  }
  #pragma unroll
  for (int n = 0; n < NF; ++n) {
    #pragma unroll
    for (int q = 0; q < 4; ++q) {
      int row = row0 + (lane >> 4) * 4 + q;
      size_t oi = (size_t)row * NCOLS + n * 16 + lr;
      outv[oi] = f2bf(tanhf(acc[n][q]));
    }
  }
}

// ---------------- skinny MFMA GEMM + tanh ----------------
template<int NCOLS, int OBF>
__global__ __launch_bounds__(256) void k_tanh_mfma(const ushort_t* __restrict__ A,
                                                   const ushort_t* __restrict__ Wt,
                                                   void* __restrict__ outv) {
  constexpr int NF = NCOLS / 16;
  int tid = threadIdx.x;
  int wave = tid >> 6, lane = tid & 63;
  int row0 = (blockIdx.x * 4 + wave) * 16;
  int lr = lane & 15, lk = (lane >> 4) * 8;
  f32x4 acc[NF];
  #pragma unroll
  for (int n = 0; n < NF; ++n) acc[n] = (f32x4){0.f, 0.f, 0.f, 0.f};
  for (int k0 = 0; k0 < 1024; k0 += 32) {
    bf16x8 a = *(const bf16x8*)&A[(size_t)(row0 + lr) * 1024 + k0 + lk];
    #pragma unroll
    for (int n = 0; n < NF; ++n) {
      bf16x8 b = *(const bf16x8*)&Wt[(size_t)(n * 16 + lr) * 1024 + k0 + lk];
      acc[n] = __builtin_amdgcn_mfma_f32_16x16x32_bf16(a, b, acc[n], 0, 0, 0);
    }
  }
  #pragma unroll
  for (int n = 0; n < NF; ++n) {
    #pragma unroll
    for (int q = 0; q < 4; ++q) {
      int row = row0 + (lane >> 4) * 4 + q;
      size_t oi = (size_t)row * NCOLS + n * 16 + lr;
      float v = tanhf(acc[n][q]);
      if (OBF == 1) ((ushort_t*)outv)[oi] = f2bf(v);
      else          ((float*)outv)[oi] = v;
    }
  }
}

// ---------------- mixer via MFMA; epilogue routed through LDS for coalesced int4 stores ----------------
__global__ __launch_bounds__(256) void k_mix5m(
    const float* __restrict__ x, const float* __restrict__ sst,
    const ushort_t* __restrict__ t160b, const ushort_t* __restrict__ w2t,
    const float* __restrict__ maaw, const float* __restrict__ maak,
    const float* __restrict__ maav, const float* __restrict__ maar,
    const float* __restrict__ maag,
    ushort_t* __restrict__ xw, ushort_t* __restrict__ xk, ushort_t* __restrict__ xv,
    ushort_t* __restrict__ xr, ushort_t* __restrict__ xg) {
  __shared__ __align__(16) ushort_t smem[23040];   // 46080 B: As/Bs (21504 us) | 5x64x72 tiles
  ushort_t* As = smem;
  ushort_t* Bs = smem + 64 * 168;
  ushort_t* sT = smem;                              // reused after MFMA phase
  int tid = threadIdx.x;
  int lane = tid & 63;
  int bRow = blockIdx.x * 64, bCol = blockIdx.y * 64;
  #pragma unroll
  for (int i = 0; i < 5; ++i) {
    int e = tid + i * 256;
    int r = e / 20, cc = (e % 20) * 8;
    *(int4*)&As[r * 168 + cc] = *(const int4*)&t160b[(size_t)(bRow + r) * 160 + cc];
    *(int4*)&Bs[r * 168 + cc] = *(const int4*)&w2t[(size_t)(bCol + r) * 160 + cc];
  }
  __syncthreads();
  int wm = tid >> 7, wn = (tid >> 6) & 1;
  f32x4 acc[5][2][2];
  #pragma unroll
  for (int f = 0; f < 5; ++f)
    #pragma unroll
    for (int m = 0; m < 2; ++m)
      #pragma unroll
      for (int n = 0; n < 2; ++n) acc[f][m][n] = (f32x4){0.f, 0.f, 0.f, 0.f};
  #pragma unroll
  for (int f = 0; f < 5; ++f) {
    bf16x8 af[2], bfv[2];
    #pragma unroll
    for (int m = 0; m < 2; ++m)
      af[m] = *(const bf16x8*)&As[(wm * 32 + m * 16 + (lane & 15)) * 168 + f * 32 + (lane >> 4) * 8];
    #pragma unroll
    for (int n = 0; n < 2; ++n)
      bfv[n] = *(const bf16x8*)&Bs[(wn * 32 + n * 16 + (lane & 15)) * 168 + f * 32 + (lane >> 4) * 8];
    #pragma unroll
    for (int m = 0; m < 2; ++m)
      #pragma unroll
      for (int n = 0; n < 2; ++n)
        acc[f][m][n] = __builtin_amdgcn_mfma_f32_16x16x32_bf16(af[m], bfv[n], acc[f][m][n], 0, 0, 0);
  }
  __syncthreads();   // As/Bs dead -> sT reuse safe
  #pragma unroll
  for (int n = 0; n < 2; ++n) {
    int colL = wn * 32 + n * 16 + (lane & 15);
    int col = bCol + colL;
    float mw_c = maaw[col], mk_c = maak[col], mv_c = maav[col];
    float mr_c = maar[col], mg_c = maag[col];
    #pragma unroll
    for (int m = 0; m < 2; ++m) {
      int rowL0 = wm * 32 + m * 16 + (lane >> 4) * 4;
      #pragma unroll
      for (int q = 0; q < 4; ++q) {
        int rL = rowL0 + q;
        int rg = bRow + rL;
        int tt = rg & (Tc - 1);
        size_t g = (size_t)rg * Cc + col;
        float xv0 = x[g];
        float xprev = (tt == 0) ? sst[(size_t)(rg >> 11) * Cc + col] : x[g - Cc];
        float dv = xprev - xv0;
        sT[0 * 4608 + rL * 72 + colL] = f2bf(xv0 + dv * (mw_c + acc[0][m][n][q]));
        sT[1 * 4608 + rL * 72 + colL] = f2bf(xv0 + dv * (mk_c + acc[1][m][n][q]));
        sT[2 * 4608 + rL * 72 + colL] = f2bf(xv0 + dv * (mv_c + acc[2][m][n][q]));
        sT[3 * 4608 + rL * 72 + colL] = f2bf(xv0 + dv * (mr_c + acc[3][m][n][q]));
        sT[4 * 4608 + rL * 72 + colL] = f2bf(xv0 + dv * (mg_c + acc[4][m][n][q]));
      }
    }
  }
  __syncthreads();
  // coalesced flush: per field 512 int4 chunks (64 rows x 8), 2 per thread
  #pragma unroll
  for (int f = 0; f < 5; ++f) {
    ushort_t* dst = (f == 0) ? xw : (f == 1) ? xk : (f == 2) ? xv : (f == 3) ? xr : xg;
    #pragma unroll
    for (int j = 0; j < 2; ++j) {
      int e = tid + j * 256;
      int r = e >> 3, ch = (e & 7) * 8;
      *(int4*)&dst[(size_t)(bRow + r) * 1024 + bCol + ch] =
          *(const int4*)&sT[f * 4608 + r * 72 + ch];
    }
  }
}

// ---------------- big bf16 MFMA GEMM body: BK=64, swizzled LDS, global_load_lds ----------------
// [R4: 32x32x16 variant = 8.4M bank conflicts; R7: 256² 8-phase = 0 conflicts but 124µs at
//  1 blk/CU — this 16x16x32 / 128² / 2-barrier form at ~109µs, 0 conflicts is the keeper.]
template<int EPI, int OBF>
DEVI void gemm_body(const ushort_t* __restrict__ A, const ushort_t* __restrict__ Wt,
                    void* __restrict__ outv, ushort_t* As, ushort_t* Bs,
                    int bRow, int bCol) {
  int tid = threadIdx.x;
  int wave = tid >> 6, lane = tid & 63;
  int wm = wave >> 1, wn = wave & 1;
  int lr = lane >> 2;
  int lkb = (((lane & 3) ^ ((lane >> 3) & 3))) * 8;   // swizzled source chunk
  int pch = ((lane >> 4) ^ ((lane >> 1) & 3)) * 8;    // physical chunk for fragment reads
  f32x4 zero4 = {0.f, 0.f, 0.f, 0.f};
  f32x4 acc[4][4];
  #pragma unroll
  for (int m = 0; m < 4; ++m)
    #pragma unroll
    for (int n = 0; n < 4; ++n) acc[m][n] = zero4;

#define STAGEK(OFS, K0) do { \
    _Pragma("unroll") \
    for (int i = 0; i < 2; ++i) { \
      int row = (wave + 4 * i) * 16 + lr; \
      gload_lds16(A + (size_t)(bRow + row) * 1024 + (K0) + lkb, &As[(OFS) + (wave + 4 * i) * 512]); \
      gload_lds16(Wt + (size_t)(bCol + row) * 1024 + (K0) + lkb, &Bs[(OFS) + (wave + 4 * i) * 512]); \
    } } while (0)
#define CMP(OFS) do { \
    bf16x8 af[4], bfv[4]; \
    _Pragma("unroll") \
    for (int m = 0; m < 4; ++m) \
      af[m] = *(const bf16x8*)&As[(OFS) + (wm * 64 + m * 16 + (lane & 15)) * 32 + pch]; \
    _Pragma("unroll") \
    for (int n = 0; n < 4; ++n) \
      bfv[n] = *(const bf16x8*)&Bs[(OFS) + (wn * 64 + n * 16 + (lane & 15)) * 32 + pch]; \
    _Pragma("unroll") \
    for (int m = 0; m < 4; ++m) \
      _Pragma("unroll") \
      for (int n = 0; n < 4; ++n) \
        acc[m][n] = __builtin_amdgcn_mfma_f32_16x16x32_bf16(af[m], bfv[n], acc[m][n], 0, 0, 0); \
  } while (0)

  for (int k0 = 0; k0 < 1024; k0 += 64) {
    STAGEK(0, k0);
    STAGEK(4096, k0 + 32);
    __syncthreads();          // single drain (vmcnt(0)) per 64-K
    CMP(0);
    CMP(4096);
    __syncthreads();
  }
#undef STAGEK
#undef CMP

  #pragma unroll
  for (int m = 0; m < 4; ++m) {
    int row = bRow + wm * 64 + m * 16 + (lane >> 4) * 4;
    #pragma unroll
    for (int n = 0; n < 4; ++n) {
      int col = bCol + wn * 64 + n * 16 + (lane & 15);
      #pragma unroll
      for (int q = 0; q < 4; ++q) {
        float v = acc[m][n][q];
        if (EPI == 1) v = v / (1.f + __expf(-v));
        size_t oi = (size_t)(row + q) * 1024 + col;
        if (OBF == 1) ((ushort_t*)outv)[oi] = f2bf(v);
        else          ((float*)outv)[oi] = v;
      }
    }
  }
}

// fused 4-projection GEMM: z selects r/k/v/g (g gets silu); all bf16 out
__global__ __launch_bounds__(256) void k_gemm4(
    const ushort_t* __restrict__ A0, const ushort_t* __restrict__ A1,
    const ushort_t* __restrict__ A2, const ushort_t* __restrict__ A3,
    const ushort_t* __restrict__ W0, const ushort_t* __restrict__ W1,
    const ushort_t* __restrict__ W2, const ushort_t* __restrict__ W3,
    ushort_t* __restrict__ O0, ushort_t* __restrict__ O1,
    ushort_t* __restrict__ O2, ushort_t* __restrict__ O3) {
  __shared__ __align__(16) ushort_t As[2 * 128 * 32];
  __shared__ __align__(16) ushort_t Bs[2 * 128 * 32];
  int z = blockIdx.z;
  const ushort_t* A  = (z == 0) ? A0 : (z == 1) ? A1 : (z == 2) ? A2 : A3;
  const ushort_t* Wt = (z == 0) ? W0 : (z == 1) ? W1 : (z == 2) ? W2 : W3;
  ushort_t* out      = (z == 0) ? O0 : (z == 1) ? O1 : (z == 2) ? O2 : O3;
  if (z == 3) gemm_body<1, 1>(A, Wt, out, As, Bs, blockIdx.x * 128, blockIdx.y * 128);
  else        gemm_body<0, 1>(A, Wt, out, As, Bs, blockIdx.x * 128, blockIdx.y * 128);
}

// ---------------- Wo GEMM, 64x128 tiles: 1024 blocks -> 4 blocks/CU residency ----------------
__global__ __launch_bounds__(256) void k_gemm_bm64(const ushort_t* __restrict__ A,
                                                   const ushort_t* __restrict__ Wt,
                                                   float* __restrict__ out) {
  __shared__ __align__(16) ushort_t As[2 * 64 * 32];
  __shared__ __align__(16) ushort_t Bs[2 * 128 * 32];
  int tid = threadIdx.x;
  int wave = tid >> 6, lane = tid & 63;
  int lr = lane >> 2;
  int lkb = (((lane & 3) ^ ((lane >> 3) & 3))) * 8;
  int pch = ((lane >> 4) ^ ((lane >> 1) & 3)) * 8;
  int bRow = blockIdx.x * 64, bCol = blockIdx.y * 128;
  f32x4 acc[4][2];
  #pragma unroll
  for (int m = 0; m < 4; ++m)
    #pragma unroll
    for (int n = 0; n < 2; ++n) acc[m][n] = (f32x4){0.f, 0.f, 0.f, 0.f};

#define STAGEK64(OA, OB, K0) do { \
    { int row = wave * 16 + lr; \
      gload_lds16(A + (size_t)(bRow + row) * 1024 + (K0) + lkb, &As[(OA) + wave * 512]); } \
    _Pragma("unroll") \
    for (int i = 0; i < 2; ++i) { \
      int row = (wave + 4 * i) * 16 + lr; \
      gload_lds16(Wt + (size_t)(bCol + row) * 1024 + (K0) + lkb, &Bs[(OB) + (wave + 4 * i) * 512]); \
    } } while (0)
#define CMP64(OA, OB) do { \
    bf16x8 af[4], bfv[2]; \
    _Pragma("unroll") \
    for (int m = 0; m < 4; ++m) \
      af[m] = *(const bf16x8*)&As[(OA) + (m * 16 + (lane & 15)) * 32 + pch]; \
    _Pragma("unroll") \
    for (int n = 0; n < 2; ++n) \
      bfv[n] = *(const bf16x8*)&Bs[(OB) + (wave * 32 + n * 16 + (lane & 15)) * 32 + pch]; \
    _Pragma("unroll") \
    for (int m = 0; m < 4; ++m) \
      _Pragma("unroll") \
      for (int n = 0; n < 2; ++n) \
        acc[m][n] = __builtin_amdgcn_mfma_f32_16x16x32_bf16(af[m], bfv[n], acc[m][n], 0, 0, 0); \
  } while (0)

  for (int k0 = 0; k0 < 1024; k0 += 64) {
    STAGEK64(0, 0, k0);
    STAGEK64(2048, 4096, k0 + 32);
    __syncthreads();
    CMP64(0, 0);
    CMP64(2048, 4096);
    __syncthreads();
  }
#undef STAGEK64
#undef CMP64

  #pragma unroll
  for (int m = 0; m < 4; ++m) {
    int row = bRow + m * 16 + (lane >> 4) * 4;
    #pragma unroll
    for (int n = 0; n < 2; ++n) {
      int col = bCol + wave * 32 + n * 16 + (lane & 15);
      #pragma unroll
      for (int q = 0; q < 4; ++q)
        out[(size_t)(row + q) * 1024 + col] = acc[m][n][q];
    }
  }
}

// ---------------- preA: wlog via MFMA, cumsum/esum, RW, A(MFMA), knorm, KV(MFMA) ----------------
// R9: Abf + kvbf MFMA-epilogue stores staged through the dead wc region, flushed as
// coalesced int4 rows (proven mechanism from k_mix5m, bit-identical values).
__global__ __launch_bounds__(256) void k_preA(
    const ushort_t* __restrict__ rbuf, const ushort_t* __restrict__ kbuf,
    const ushort_t* __restrict__ vbf,
    const ushort_t* __restrict__ t64bf, const float* __restrict__ dw2,
    const float* __restrict__ tdec, const float* __restrict__ faaaa,
    ushort_t* __restrict__ rwbf, ushort_t* __restrict__ kvbf, ushort_t* __restrict__ knbuf,
    ushort_t* __restrict__ Abf, float* __restrict__ esum) {
  __shared__ __align__(16) char ubuf[16640 + 9216 + 9216];
  float* wc = (float*)ubuf;
  ushort_t* sS = (ushort_t*)ubuf;                  // staging tile overlaying wc (dead by use)
  ushort_t* sA = (ushort_t*)(ubuf + 16640);
  ushort_t* sB = (ushort_t*)(ubuf + 16640 + 9216);
  __shared__ float sred[4 * 64];
  __shared__ float sdiag[64];
  __shared__ float snrm[64];
  int bx = blockIdx.x;
  int ci = bx & 31, bh = bx >> 5;
  int b = bh >> 4, h = bh & 15;
  int tid = threadIdx.x;
  int w = tid >> 6, lane = tid & 63;
  int c = lane;
  int row0g = b * Tc + ci * 64;
  size_t base = (size_t)row0g * Cc + (size_t)h * 64;

  #pragma unroll
  for (int j = 0; j < 2; ++j) {
    int e = tid + j * 256; int r = e >> 3, cc = (e & 7) * 8;
    *(int4*)&sA[r * 72 + cc] = *(const int4*)&t64bf[(size_t)(row0g + r) * 64 + cc];
  }
  for (int i = 0; i < 16; ++i) {
    int e = tid + i * 256; int r = e >> 6, cc = e & 63;
    sB[cc * 72 + r] = f2bf(dw2[(size_t)r * Cc + h * 64 + cc]);
  }
  float rv[16], kv[16];
  #pragma unroll
  for (int i = 0; i < 16; ++i) {
    size_t g = base + (size_t)(w * 16 + i) * Cc + c;
    rv[i] = bf2f(rbuf[g]); kv[i] = bf2f(kbuf[g]);
  }
  __syncthreads();
  {
    int rbase = w * 16;
    bf16x8 a0 = *(const bf16x8*)&sA[(rbase + (lane & 15)) * 72 + (lane >> 4) * 8];
    bf16x8 a1 = *(const bf16x8*)&sA[(rbase + (lane & 15)) * 72 + 32 + (lane >> 4) * 8];
    #pragma unroll
    for (int ct = 0; ct < 4; ++ct) {
      bf16x8 b0 = *(const bf16x8*)&sB[(ct * 16 + (lane & 15)) * 72 + (lane >> 4) * 8];
      bf16x8 b1 = *(const bf16x8*)&sB[(ct * 16 + (lane & 15)) * 72 + 32 + (lane >> 4) * 8];
      f32x4 acc = {0.f, 0.f, 0.f, 0.f};
      acc = __builtin_amdgcn_mfma_f32_16x16x32_bf16(a0, b0, acc, 0, 0, 0);
      acc = __builtin_amdgcn_mfma_f32_16x16x32_bf16(a1, b1, acc, 0, 0, 0);
      int s = ct * 16 + (lane & 15);
      #pragma unroll
      for (int q = 0; q < 4; ++q) {
        int t = rbase + (lane >> 4) * 4 + q;
        wc[t * 65 + s] = acc[q];
      }
    }
  }
  __syncthreads();
  float wv[16];
  {
    float td = tdec[h * 64 + c];
    #pragma unroll
    for (int i = 0; i < 16; ++i)
      wv[i] = -__expf(td + wc[(w * 16 + i) * 65 + c]);
  }
  {
    float s = 0.f;
    #pragma unroll
    for (int i = 0; i < 16; ++i) s += wv[i];
    sred[w * 64 + c] = s;
  }
  __syncthreads();
  {
    float run = 0.f;
    for (int ww = 0; ww < w; ++ww) run += sred[ww * 64 + c];
    #pragma unroll
    for (int i = 0; i < 16; ++i) {
      run += wv[i]; wv[i] = run;
      wc[(w * 16 + i) * 65 + c] = run;
    }
    if (w == 3) esum[((size_t)bh * 32 + ci) * 64 + c] = __expf(run);
  }
  {
    float u_c = faaaa[h * 64 + c];
    #pragma unroll
    for (int i = 0; i < 16; ++i) {
      float p = rv[i] * kv[i] * u_c;
      float n2 = kv[i] * kv[i];
      #pragma unroll
      for (int o = 32; o; o >>= 1) { p += __shfl_xor(p, o, 64); n2 += __shfl_xor(n2, o, 64); }
      if (lane == 0) {
        sdiag[w * 16 + i] = p;
        snrm[w * 16 + i] = 1.f / fmaxf(sqrtf(n2), 1e-12f);
      }
    }
  }
  __syncthreads();
  float off32 = wc[31 * 65 + c];
  float wc63 = wc[63 * 65 + c];
  #pragma unroll
  for (int i = 0; i < 16; ++i) {
    int t = w * 16 + i;
    size_t g = base + (size_t)t * Cc + c;
    float wsh = (i == 0) ? ((w == 0) ? 0.f : wc[(t - 1) * 65 + c]) : wv[i - 1];
    rwbf[g] = f2bf(rv[i] * __expf(clip30(wsh)));
    sA[t * 72 + c] = f2bf(rv[i] * __expf(clip30(wsh - off32)));
    sB[t * 72 + c] = f2bf(kv[i] * __expf(clip30(off32 - wv[i])));
    knbuf[g] = f2bf(kv[i] * snrm[t]);
  }
  __syncthreads();   // wc fully dead after this point (off32/wc63/wsh all in regs)
  {
    int rbase = w * 16;
    bf16x8 a0 = *(const bf16x8*)&sA[(rbase + (lane & 15)) * 72 + (lane >> 4) * 8];
    bf16x8 a1 = *(const bf16x8*)&sA[(rbase + (lane & 15)) * 72 + 32 + (lane >> 4) * 8];
    #pragma unroll
    for (int ct = 0; ct < 4; ++ct) {
      bf16x8 b0 = *(const bf16x8*)&sB[(ct * 16 + (lane & 15)) * 72 + (lane >> 4) * 8];
      bf16x8 b1 = *(const bf16x8*)&sB[(ct * 16 + (lane & 15)) * 72 + 32 + (lane >> 4) * 8];
      f32x4 acc = {0.f, 0.f, 0.f, 0.f};
      acc = __builtin_amdgcn_mfma_f32_16x16x32_bf16(a0, b0, acc, 0, 0, 0);
      acc = __builtin_amdgcn_mfma_f32_16x16x32_bf16(a1, b1, acc, 0, 0, 0);
      int s = ct * 16 + (lane & 15);
      #pragma unroll
      for (int q = 0; q < 4; ++q) {
        int t = rbase + (lane >> 4) * 4 + q;
        float val = (t > s) ? acc[q] : ((t == s) ? sdiag[t] : 0.f);
        sS[t * 72 + s] = f2bf(val);             // stage (32B-seg -> LDS, 2-way free)
      }
    }
  }
  __syncthreads();
  // flush Abf coalesced (128B rows) + build KV operand tiles (wv/kv in regs)
  #pragma unroll
  for (int j = 0; j < 2; ++j) {
    int e = tid + j * 256;
    int r = e >> 3, ch = (e & 7) * 8;
    *(int4*)&Abf[(size_t)bx * 4096 + r * 64 + ch] = *(const int4*)&sS[r * 72 + ch];
  }
  #pragma unroll
  for (int i = 0; i < 16; ++i) {
    int t = w * 16 + i;
    sA[c * 72 + t] = f2bf(kv[i] * __expf(clip30(wc63 - wv[i])));
    sB[c * 72 + t] = vbf[base + (size_t)t * Cc + c];
  }
  __syncthreads();   // Abf flush reads of sS done -> sS reusable for kvbf staging
  {
    int rbase = w * 16;
    bf16x8 a0 = *(const bf16x8*)&sA[(rbase + (lane & 15)) * 72 + (lane >> 4) * 8];
    bf16x8 a1 = *(const bf16x8*)&sA[(rbase + (lane & 15)) * 72 + 32 + (lane >> 4) * 8];
    #pragma unroll
    for (int ct = 0; ct < 4; ++ct) {
      bf16x8 b0 = *(const bf16x8*)&sB[(ct * 16 + (lane & 15)) * 72 + (lane >> 4) * 8];
      bf16x8 b1 = *(const bf16x8*)&sB[(ct * 16 + (lane & 15)) * 72 + 32 + (lane >> 4) * 8];
      f32x4 acc = {0.f, 0.f, 0.f, 0.f};
      acc = __builtin_amdgcn_mfma_f32_16x16x32_bf16(a0, b0, acc, 0, 0, 0);
      acc = __builtin_amdgcn_mfma_f32_16x16x32_bf16(a1, b1, acc, 0, 0, 0);
      int j = ct * 16 + (lane & 15);
      #pragma unroll
      for (int q = 0; q < 4; ++q) {
        int ii = rbase + (lane >> 4) * 4 + q;
        sS[ii * 72 + j] = f2bf(acc[q]);         // stage kvbf
      }
    }
  }
  __syncthreads();
  #pragma unroll
  for (int j = 0; j < 2; ++j) {
    int e = tid + j * 256;
    int r = e >> 3, ch = (e & 7) * 8;
    *(int4*)&kvbf[base + (size_t)r * Cc + ch] = *(const int4*)&sS[r * 72 + ch];
  }
}

// ---------------- preB: P(MFMA), static-register GJ solve, y = A@X + RW@state, fused GroupNorm*g ----------------
// R9: ong epilogue staged into sAb (waves only read own row-quarter of sAb -> race-free),
// flushed as coalesced int4 rows.
__global__ __launch_bounds__(256) void k_preB(
    const ushort_t* __restrict__ knbuf, const ushort_t* __restrict__ vbf,
    const ushort_t* __restrict__ Abf, const ushort_t* __restrict__ rwbf,
    const ushort_t* __restrict__ statebuf, const float* __restrict__ ltemp,
    const ushort_t* __restrict__ gbuf, const float* __restrict__ gamma,
    const float* __restrict__ beta, ushort_t* __restrict__ ong) {
  __shared__ __align__(16) ushort_t sKX[64 * 72];
  __shared__ __align__(16) ushort_t sAb[64 * 72];
  __shared__ __align__(16) char ubuf[64 * 72 * 2 * 2];
  __shared__ __align__(16) float pivbuf[2][192];
  __shared__ float colbuf[2][64];
  __shared__ float diagbuf[64];
  float* sP = (float*)ubuf;
  ushort_t* sRW = (ushort_t*)ubuf;
  ushort_t* sSTt = (ushort_t*)(ubuf + 64 * 72 * 2);

  int bx = blockIdx.x;
  int ci = bx & 31, bh = bx >> 5;
  int b = bh >> 4, h = bh & 15;
  int tid = threadIdx.x;
  int w = tid >> 6, lane = tid & 63;
  int rg = tid >> 4, cg = tid & 15;
  size_t base = ((size_t)(b * Tc + ci * 64)) * Cc + (size_t)h * 64;

  #pragma unroll
  for (int j = 0; j < 2; ++j) {
    int e = tid + j * 256;
    int r = e >> 3, cc = (e & 7) * 8;
    *(int4*)&sKX[r * 72 + cc] = *(const int4*)&knbuf[base + (size_t)r * Cc + cc];
    *(int4*)&sAb[r * 72 + cc] = *(const int4*)&Abf[(size_t)bx * 4096 + (size_t)r * 64 + cc];
  }
  float4 A0, A1, A2, A3, B0, B1, B2, B3;
  if (cg >= 8) {
#define LDV(R, AR, BR) do { \
      int4 raw = *(const int4*)(vbf + base + (size_t)(4 * rg + (R)) * Cc + (cg - 8) * 8); \
      (AR).x = bf2f((ushort_t)(raw.x & 0xffff)); (AR).y = bf2f((ushort_t)((unsigned)raw.x >> 16)); \
      (AR).z = bf2f((ushort_t)(raw.y & 0xffff)); (AR).w = bf2f((ushort_t)((unsigned)raw.y >> 16)); \
      (BR).x = bf2f((ushort_t)(raw.z & 0xffff)); (BR).y = bf2f((ushort_t)((unsigned)raw.z >> 16)); \
      (BR).z = bf2f((ushort_t)(raw.w & 0xffff)); (BR).w = bf2f((ushort_t)((unsigned)raw.w >> 16)); \
    } while (0)
    LDV(0, A0, B0); LDV(1, A1, B1); LDV(2, A2, B2); LDV(3, A3, B3);
#undef LDV
  }
  __syncthreads();
  float temp = log1pf(__expf(ltemp[h]));
  {
    int rbase = w * 16;
    bf16x8 a0 = *(const bf16x8*)&sKX[(rbase + (lane & 15)) * 72 + (lane >> 4) * 8];
    bf16x8 a1 = *(const bf16x8*)&sKX[(rbase + (lane & 15)) * 72 + 32 + (lane >> 4) * 8];
    #pragma unroll
    for (int ct = 0; ct < 4; ++ct) {
      bf16x8 b0 = *(const bf16x8*)&sKX[(ct * 16 + (lane & 15)) * 72 + (lane >> 4) * 8];
      bf16x8 b1 = *(const bf16x8*)&sKX[(ct * 16 + (lane & 15)) * 72 + 32 + (lane >> 4) * 8];
      f32x4 acc = {0.f, 0.f, 0.f, 0.f};
      acc = __builtin_amdgcn_mfma_f32_16x16x32_bf16(a0, b0, acc, 0, 0, 0);
      acc = __builtin_amdgcn_mfma_f32_16x16x32_bf16(a1, b1, acc, 0, 0, 0);
      int s = ct * 16 + (lane & 15);
      #pragma unroll
      for (int q = 0; q < 4; ++q) {
        int t = rbase + (lane >> 4) * 4 + q;
        sP[t * 68 + s] = ((t == s) ? 1.f : 0.f) + __expf(clip20(temp * acc[q]));
      }
    }
  }
  __syncthreads();
  if (cg < 8) {
    A0 = *(float4*)&sP[(4 * rg + 0) * 68 + cg * 8]; B0 = *(float4*)&sP[(4 * rg + 0) * 68 + cg * 8 + 4];
    A1 = *(float4*)&sP[(4 * rg + 1) * 68 + cg * 8]; B1 = *(float4*)&sP[(4 * rg + 1) * 68 + cg * 8 + 4];
    A2 = *(float4*)&sP[(4 * rg + 2) * 68 + cg * 8]; B2 = *(float4*)&sP[(4 * rg + 2) * 68 + cg * 8 + 4];
    A3 = *(float4*)&sP[(4 * rg + 3) * 68 + cg * 8]; B3 = *(float4*)&sP[(4 * rg + 3) * 68 + cg * 8 + 4];
  }
  __syncthreads();
  #pragma unroll
  for (int j = 0; j < 2; ++j) {
    int e = tid + j * 256;
    int r = e >> 3, cc = (e & 7) * 8;
    *(int4*)&sRW[r * 72 + cc] = *(const int4*)&rwbf[base + (size_t)r * Cc + cc];
  }
  {
    const ushort_t* sb = statebuf + ((size_t)bh * 32 + ci) * 4096;
    #pragma unroll
    for (int i = 0; i < 16; ++i) {
      int e = tid + i * 256;
      int r = e >> 6, c = e & 63;
      sSTt[c * 72 + r] = sb[e];
    }
  }
#define UPD(MA, MB, F) do { \
    (MA).x -= (F) * p0_.x; (MA).y -= (F) * p0_.y; (MA).z -= (F) * p0_.z; (MA).w -= (F) * p0_.w; \
    (MB).x -= (F) * p1_.x; (MB).y -= (F) * p1_.y; (MB).z -= (F) * p1_.z; (MB).w -= (F) * p1_.w; \
  } while (0)
#define GJSTEP(JL, PRA, PRB, H0, H1, H2, H3) do { \
    int j_ = jh * 8 + (JL); \
    if (rg == (j_ >> 2)) { \
      *(float4*)&pivbuf[(JL) & 1][cg * 12]     = (PRA); \
      *(float4*)&pivbuf[(JL) & 1][cg * 12 + 4] = (PRB); \
    } \
    if (cg == jh) { \
      float4 cv_; \
      cv_.x = GETEL(H0, (JL) & 3); \
      cv_.y = GETEL(H1, (JL) & 3); \
      cv_.z = GETEL(H2, (JL) & 3); \
      cv_.w = GETEL(H3, (JL) & 3); \
      *(float4*)&colbuf[(JL) & 1][rg * 4] = cv_; \
    } \
    __syncthreads(); \
    float pd_ = pivbuf[(JL) & 1][(j_ >> 3) * 12 + (j_ & 7)]; \
    float4 fv_ = *(float4*)&colbuf[(JL) & 1][rg * 4]; \
    float4 p0_ = *(float4*)&pivbuf[(JL) & 1][cg * 12]; \
    float4 p1_ = *(float4*)&pivbuf[(JL) & 1][cg * 12 + 4]; \
    if (rg == (j_ >> 2)) SETEL(fv_, (JL) & 3, 0.f); \
    float inv_ = 1.f / pd_; \
    float f0_ = fv_.x * inv_, f1_ = fv_.y * inv_, f2_ = fv_.z * inv_, f3_ = fv_.w * inv_; \
    UPD(A0, B0, f0_); UPD(A1, B1, f1_); UPD(A2, B2, f2_); UPD(A3, B3, f3_); \
  } while (0)
  for (int jh = 0; jh < 8; ++jh) {
    GJSTEP(0, A0, B0, A0, A1, A2, A3);
    GJSTEP(1, A1, B1, A0, A1, A2, A3);
    GJSTEP(2, A2, B2, A0, A1, A2, A3);
    GJSTEP(3, A3, B3, A0, A1, A2, A3);
    GJSTEP(4, A0, B0, B0, B1, B2, B3);
    GJSTEP(5, A1, B1, B0, B1, B2, B3);
    GJSTEP(6, A2, B2, B0, B1, B2, B3);
    GJSTEP(7, A3, B3, B0, B1, B2, B3);
  }
#undef GJSTEP
#undef UPD
  if (cg == (rg >> 1)) {
    float4 h0 = (rg & 1) ? B0 : A0;
    float4 h1 = (rg & 1) ? B1 : A1;
    float4 h2 = (rg & 1) ? B2 : A2;
    float4 h3 = (rg & 1) ? B3 : A3;
    *(float4*)&diagbuf[rg * 4] = make_float4(h0.x, h1.y, h2.z, h3.w);
  }
  __syncthreads();
  if (cg >= 8) {
    float4 dg = *(float4*)&diagbuf[rg * 4];
#define WRX(R, AR, BR, IR) do { \
      int cb_ = (cg - 8) * 8; \
      sKX[(cb_ + 0) * 72 + 4 * rg + (R)] = f2bf((AR).x * (IR)); \
      sKX[(cb_ + 1) * 72 + 4 * rg + (R)] = f2bf((AR).y * (IR)); \
      sKX[(cb_ + 2) * 72 + 4 * rg + (R)] = f2bf((AR).z * (IR)); \
      sKX[(cb_ + 3) * 72 + 4 * rg + (R)] = f2bf((AR).w * (IR)); \
      sKX[(cb_ + 4) * 72 + 4 * rg + (R)] = f2bf((BR).x * (IR)); \
      sKX[(cb_ + 5) * 72 + 4 * rg + (R)] = f2bf((BR).y * (IR)); \
      sKX[(cb_ + 6) * 72 + 4 * rg + (R)] = f2bf((BR).z * (IR)); \
      sKX[(cb_ + 7) * 72 + 4 * rg + (R)] = f2bf((BR).w * (IR)); \
    } while (0)
    WRX(0, A0, B0, 1.f / dg.x);
    WRX(1, A1, B1, 1.f / dg.y);
    WRX(2, A2, B2, 1.f / dg.z);
    WRX(3, A3, B3, 1.f / dg.w);
#undef WRX
  }
  __syncthreads();
  {
    int rbase = w * 16;
    bf16x8 aA0 = *(const bf16x8*)&sAb[(rbase + (lane & 15)) * 72 + (lane >> 4) * 8];
    bf16x8 aA1 = *(const bf16x8*)&sAb[(rbase + (lane & 15)) * 72 + 32 + (lane >> 4) * 8];
    bf16x8 aR0 = *(const bf16x8*)&sRW[(rbase + (lane & 15)) * 72 + (lane >> 4) * 8];
    bf16x8 aR1 = *(const bf16x8*)&sRW[(rbase + (lane & 15)) * 72 + 32 + (lane >> 4) * 8];
    f32x4 yv[4];
    #pragma unroll
    for (int ct = 0; ct < 4; ++ct) {
      bf16x8 bX0 = *(const bf16x8*)&sKX[(ct * 16 + (lane & 15)) * 72 + (lane >> 4) * 8];
      bf16x8 bX1 = *(const bf16x8*)&sKX[(ct * 16 + (lane & 15)) * 72 + 32 + (lane >> 4) * 8];
      bf16x8 bS0 = *(const bf16x8*)&sSTt[(ct * 16 + (lane & 15)) * 72 + (lane >> 4) * 8];
      bf16x8 bS1 = *(const bf16x8*)&sSTt[(ct * 16 + (lane & 15)) * 72 + 32 + (lane >> 4) * 8];
      f32x4 acc = {0.f, 0.f, 0.f, 0.f};
      acc = __builtin_amdgcn_mfma_f32_16x16x32_bf16(aA0, bX0, acc, 0, 0, 0);
      acc = __builtin_amdgcn_mfma_f32_16x16x32_bf16(aA1, bX1, acc, 0, 0, 0);
      acc = __builtin_amdgcn_mfma_f32_16x16x32_bf16(aR0, bS0, acc, 0, 0, 0);
      acc = __builtin_amdgcn_mfma_f32_16x16x32_bf16(aR1, bS1, acc, 0, 0, 0);
      yv[ct] = acc;
    }
    #pragma unroll
    for (int q = 0; q < 4; ++q) {
      float s1 = yv[0][q] + yv[1][q] + yv[2][q] + yv[3][q];
      float s2 = yv[0][q] * yv[0][q] + yv[1][q] * yv[1][q] +
                 yv[2][q] * yv[2][q] + yv[3][q] * yv[3][q];
      #pragma unroll
      for (int o = 1; o < 16; o <<= 1) {
        s1 += __shfl_xor(s1, o, 64);
        s2 += __shfl_xor(s2, o, 64);
      }
      float mu = s1 * (1.f / 64.f);
      float var = s2 * (1.f / 64.f) - mu * mu;
      float rs = rsqrtf(var + 6.4e-4f);
      int t = rbase + (lane >> 4) * 4 + q;
      #pragma unroll
      for (int ct = 0; ct < 4; ++ct) {
        int cc = ct * 16 + (lane & 15);
        size_t g = base + (size_t)t * Cc + cc;
        float yn = (yv[ct][q] - mu) * rs;
        float o = (yn * gamma[h * 64 + cc] + beta[h * 64 + cc]) * bf2f(gbuf[g]);
        sAb[t * 72 + cc] = f2bf(o);            // stage ong (own row-quarter of sAb)
      }
    }
  }
  __syncthreads();
  #pragma unroll
  for (int j = 0; j < 2; ++j) {
    int e = tid + j * 256;
    int r = e >> 3, ch = (e & 7) * 8;
    *(int4*)&ong[base + (size_t)r * Cc + ch] = *(const int4*)&sAb[r * 72 + ch];
  }
}

// ---------------- state recurrence only (bf16 kv/statebuf, f32 registers) ----------------
__global__ __launch_bounds__(128) void k_scanstate(
    const float* __restrict__ wkv0, const ushort_t* __restrict__ kvbf,
    const float* __restrict__ esum, ushort_t* __restrict__ statebuf,
    float* __restrict__ stout) {
  int bh = blockIdx.x >> 3;
  int rg = blockIdx.x & 7;
  int b = bh >> 4, h = bh & 15;
  int tid = threadIdx.x;
  int r = rg * 8 + (tid >> 4);
  int c0 = (tid & 15) * 4;
  float4 st = *(const float4*)(wkv0 + ((size_t)bh * 64 + r) * 64 + c0);
  size_t kvb = (size_t)(b * Tc) * Cc + (size_t)h * 64 + (size_t)r * Cc + c0;
  constexpr int PF = 4;
  uint2 kvn[PF];
  float4 evn[PF];
  #pragma unroll
  for (int j = 0; j < PF; ++j) {
    kvn[j] = *(const uint2*)(kvbf + kvb + (size_t)j * 64 * Cc);
    evn[j] = *(const float4*)(esum + ((size_t)bh * 32 + j) * 64 + c0);
  }
  #pragma unroll
  for (int ci = 0; ci < NCHUNK; ++ci) {
    *(uint2*)(statebuf + ((size_t)bh * 32 + ci) * 4096 + (size_t)r * 64 + c0) = f4pk(st);
    float4 kv = bf4up(kvn[ci & 3]);
    float4 ev = evn[ci & 3];
    if (ci + PF < NCHUNK) {
      kvn[ci & 3] = *(const uint2*)(kvbf + kvb + (size_t)(ci + PF) * 64 * Cc);
      evn[ci & 3] = *(const float4*)(esum + ((size_t)bh * 32 + ci + PF) * 64 + c0);
    }
    st.x = st.x * ev.x + kv.x;
    st.y = st.y * ev.y + kv.y;
    st.z = st.z * ev.z + kv.z;
    st.w = st.w * ev.w + kv.w;
  }
  *(float4*)(stout + ((size_t)bh * 64 + r) * 64 + c0) = st;
}

// ---------------- launcher ----------------
extern "C" void kernel_launch(void* const* d_in, const int* in_sizes, int n_in,
                              void* d_out, int out_size, void* d_ws, size_t ws_size,
                              hipStream_t stream) {
  (void)in_sizes; (void)n_in; (void)out_size;
  const float* x     = (const float*)d_in[0];
  const float* sst   = (const float*)d_in[1];
  const float* wkv0  = (const float*)d_in[2];
  const float* tmx   = (const float*)d_in[3];
  const float* tmw   = (const float*)d_in[4];
  const float* tmk   = (const float*)d_in[5];
  const float* tmv   = (const float*)d_in[6];
  const float* tmr   = (const float*)d_in[7];
  const float* tmg   = (const float*)d_in[8];
  const float* w1    = (const float*)d_in[9];
  const float* w2    = (const float*)d_in[10];
  const float* tdec  = (const float*)d_in[11];
  const float* dw1   = (const float*)d_in[12];
  const float* dw2   = (const float*)d_in[13];
  const float* faaaa = (const float*)d_in[14];
  const float* ltemp = (const float*)d_in[15];
  const float* Wr    = (const float*)d_in[16];
  const float* Wk    = (const float*)d_in[17];
  const float* Wv    = (const float*)d_in[18];
  const float* Wg    = (const float*)d_in[19];
  const float* Wo    = (const float*)d_in[20];
  const float* lng   = (const float*)d_in[21];
  const float* lnb   = (const float*)d_in[22];
  float* out = (float*)d_out;

  const size_t MB = 1ull << 20;
  const size_t NEED = 242 * MB;
  if (ws_size < NEED) return;

  char* p = (char*)d_ws;
  ushort_t* kbb  = (ushort_t*)(p + 0 * MB);    // bf16 k (GEMM out)
  ushort_t* xwb  = (ushort_t*)(p + 16 * MB);   // xw bf16 -> rbb
  ushort_t* rbb  = (ushort_t*)(p + 16 * MB);   // bf16 r (GEMM out), overlays xwb
  ushort_t* kvbf = (ushort_t*)(p + 32 * MB);   // KV bf16 (16 MiB)
  ushort_t* statebuf = (ushort_t*)(p + 96 * MB); // bf16 (16 MiB)
  ushort_t* vbuf = (ushort_t*)(p + 128 * MB);  // v (bf16)
  ushort_t* gbuf = (ushort_t*)(p + 144 * MB);  // silu(g) (bf16)
  ushort_t* xkb  = (ushort_t*)(p + 160 * MB);  // -> Abf
  ushort_t* Abf  = (ushort_t*)(p + 160 * MB);
  ushort_t* xvb  = (ushort_t*)(p + 176 * MB);  // -> rwbf
  ushort_t* rwbf = (ushort_t*)(p + 176 * MB);
  ushort_t* xrb  = (ushort_t*)(p + 192 * MB);
  ushort_t* xgb  = (ushort_t*)(p + 208 * MB);  // xg -> knorm -> ong
  ushort_t* t160b = (ushort_t*)(p + 224 * MB);
  float*    esum = (float*)(p + 224 * MB);     // overlays t160b (dead by then)
  ushort_t* w2t  = (ushort_t*)(p + 227 * MB);  // 0.32 MiB
  ushort_t* w1t  = (ushort_t*)(p + 228 * MB);  // 0.32 MiB
  ushort_t* dw1t = (ushort_t*)(p + 229 * MB);  // 0.13 MiB
  ushort_t* t64bf = (ushort_t*)(p + 230 * MB); // bf16 tanh(xw@dw1), 1 MiB
  ushort_t* Wrb  = (ushort_t*)(p + 232 * MB);
  ushort_t* Wkb  = (ushort_t*)(p + 234 * MB);
  ushort_t* Wvb  = (ushort_t*)(p + 236 * MB);
  ushort_t* Wgb  = (ushort_t*)(p + 238 * MB);
  ushort_t* Wob  = (ushort_t*)(p + 240 * MB);

  const int thr = 256;
  k_f2bf5<<<dim3((Cc * Cc / 4 + 255) / 256, 1, 5), thr, 0, stream>>>(
      Wr, Wk, Wv, Wg, Wo, Wrb, Wkb, Wvb, Wgb, Wob);
  k_prep<<<(397312 + 255) / 256, thr, 0, stream>>>(w2, w1, dw1, x,
                                                   w2t, w1t, dw1t, out + (size_t)BT * Cc);

  k_shift_tanh<<<BT / 64, thr, 0, stream>>>(x, sst, tmx, w1t, t160b);
  k_mix5m<<<dim3(BT / 64, Cc / 64), thr, 0, stream>>>(x, sst, t160b, w2t,
                                                      tmw, tmk, tmv, tmr, tmg,
                                                      xwb, xkb, xvb, xrb, xgb);
  k_tanh_mfma<64, 1><<<BT / 64, thr, 0, stream>>>(xwb, dw1t, t64bf);

  k_gemm4<<<dim3(BT / 128, Cc / 128, 4), thr, 0, stream>>>(
      xrb, xkb, xvb, xgb, Wrb, Wkb, Wvb, Wgb, rbb, kbb, vbuf, gbuf);

  k_preA<<<2048, thr, 0, stream>>>(rbb, kbb, vbuf, t64bf, dw2, tdec, faaaa,
                                   rwbf, kvbf, xgb /*knorm*/, Abf, esum);
  k_scanstate<<<512, 128, 0, stream>>>(wkv0, kvbf, esum, statebuf,
                                       out + (size_t)BT * Cc + (size_t)Bc * Cc);
  k_preB<<<2048, thr, 0, stream>>>(xgb /*knorm*/, vbuf, Abf, rwbf, statebuf, ltemp,
                                   gbuf, lng, lnb, xgb /*ong*/);

  k_gemm_bm64<<<dim3(BT / 64, Cc / 128), thr, 0, stream>>>(xgb, Wob, out);
}

// Round 10
// 384.451 us; speedup vs baseline: 1.1061x; 1.0164x over previous
//
#include <hip/hip_runtime.h>
#include <cstdint>
#include <cstddef>

typedef unsigned short ushort_t;
#define DEVI __device__ __forceinline__

constexpr int Bc = 4, Tc = 2048, Cc = 1024, Hc = 16;
constexpr int BT = Bc * Tc;           // 8192
constexpr int NCHUNK = Tc / 64;       // 32

using f32x4  = __attribute__((ext_vector_type(4))) float;
using bf16x8 = __attribute__((ext_vector_type(8))) __bf16;

DEVI ushort_t f2bf(float f) {
  union { float f; unsigned u; } v; v.f = f;
  unsigned r = v.u + 0x7fffu + ((v.u >> 16) & 1u);
  return (ushort_t)(r >> 16);
}
DEVI float bf2f(ushort_t u) {
  union { unsigned u; float f; } v; v.u = ((unsigned)u) << 16; return v.f;
}
DEVI float clip30(float x) { return fminf(fmaxf(x, -30.f), 30.f); }
DEVI float clip20(float x) { return fminf(fmaxf(x, -20.f), 20.f); }

DEVI float4 bf4up(uint2 r) {
  float4 v;
  v.x = bf2f((ushort_t)(r.x & 0xffff)); v.y = bf2f((ushort_t)(r.x >> 16));
  v.z = bf2f((ushort_t)(r.y & 0xffff)); v.w = bf2f((ushort_t)(r.y >> 16));
  return v;
}
DEVI uint2 f4pk(float4 v) {
  uint2 r;
  r.x = (unsigned)f2bf(v.x) | ((unsigned)f2bf(v.y) << 16);
  r.y = (unsigned)f2bf(v.z) | ((unsigned)f2bf(v.w) << 16);
  return r;
}

DEVI void gload_lds16(const ushort_t* g, ushort_t* l) {
  __builtin_amdgcn_global_load_lds(
      (const __attribute__((address_space(1))) void*)g,
      (__attribute__((address_space(3))) void*)l, 16, 0, 0);
}

#define GETEL(V4, E) ((E) == 0 ? (V4).x : (E) == 1 ? (V4).y : (E) == 2 ? (V4).z : (V4).w)
#define SETEL(V4, E, VAL) do { if ((E) == 0) (V4).x = (VAL); else if ((E) == 1) (V4).y = (VAL); \
                               else if ((E) == 2) (V4).z = (VAL); else (V4).w = (VAL); } while (0)

// merged: 5 weight matrices f32->bf16 (z=0..4) | prep (z=5: w2t/w1t/dw1t/xlast)
__global__ void k_f2bf5p(const float* __restrict__ i0, const float* __restrict__ i1,
                         const float* __restrict__ i2, const float* __restrict__ i3,
                         const float* __restrict__ i4,
                         const float* __restrict__ w2, const float* __restrict__ w1,
                         const float* __restrict__ dw1, const float* __restrict__ x,
                         ushort_t* __restrict__ o0, ushort_t* __restrict__ o1,
                         ushort_t* __restrict__ o2, ushort_t* __restrict__ o3,
                         ushort_t* __restrict__ o4,
                         ushort_t* __restrict__ w2t, ushort_t* __restrict__ w1t,
                         ushort_t* __restrict__ dw1t, float* __restrict__ xlast) {
  int z = blockIdx.z;
  int i = blockIdx.x * 256 + threadIdx.x;
  if (z == 5) {
    if (i < 163840) {                       // w2t[c][fd] = bf16(w2[fd][c])
      int c = i / 160, fd = i % 160;
      w2t[i] = f2bf(w2[(size_t)fd * 1024 + c]);
    } else if (i < 327680) {                // w1t[n][r] = bf16(w1[r][n]), w1 is 1024x160
      int j = i - 163840; int n = j >> 10, r = j & 1023;
      w1t[j] = f2bf(w1[(size_t)r * 160 + n]);
    } else if (i < 393216) {                // dw1t[n][r] = bf16(dw1[r][n]), dw1 is 1024x64
      int j = i - 327680; int n = j >> 10, r = j & 1023;
      dw1t[j] = f2bf(dw1[(size_t)r * 64 + n]);
    } else if (i < 397312) {                // xlast
      int j = i - 393216; int b = j >> 10, c = j & 1023;
      xlast[j] = x[((size_t)b * Tc + Tc - 1) * Cc + c];
    }
    return;
  }
  const float* in = (z == 0) ? i0 : (z == 1) ? i1 : (z == 2) ? i2 : (z == 3) ? i3 : i4;
  ushort_t* out   = (z == 0) ? o0 : (z == 1) ? o1 : (z == 2) ? o2 : (z == 3) ? o3 : o4;
  if (i < Cc * Cc / 4) {
    float4 v = *(const float4*)(in + (size_t)i * 4);
    ushort4 o;
    o.x = f2bf(v.x); o.y = f2bf(v.y); o.z = f2bf(v.z); o.w = f2bf(v.w);
    *(ushort4*)(out + (size_t)i * 4) = o;
  }
}

// ---------------- fused token-shift + skinny MFMA GEMM + tanh (NCOLS=160, bf16 out) ----------------
__global__ __launch_bounds__(256) void k_shift_tanh(
    const float* __restrict__ x, const float* __restrict__ sst,
    const float* __restrict__ tmx, const ushort_t* __restrict__ Wt,
    ushort_t* __restrict__ outv) {
  constexpr int NCOLS = 160, NF = NCOLS / 16;
  int tid = threadIdx.x;
  int wave = tid >> 6, lane = tid & 63;
  int row0 = (blockIdx.x * 4 + wave) * 16;
  int lr = lane & 15, lk = (lane >> 4) * 8;
  int rg = row0 + lr;
  int tt = rg & (Tc - 1);
  const float* xrow = x + (size_t)rg * Cc;
  const float* prow = (tt == 0) ? (sst + (size_t)(rg >> 11) * Cc) : (xrow - Cc);
  f32x4 acc[NF];
  #pragma unroll
  for (int n = 0; n < NF; ++n) acc[n] = (f32x4){0.f, 0.f, 0.f, 0.f};
  for (int k0 = 0; k0 < 1024; k0 += 32) {
    int c0 = k0 + lk;
    float4 xa = *(const float4*)(xrow + c0), xb = *(const float4*)(xrow + c0 + 4);
    float4 pa = *(const float4*)(prow + c0), pb = *(const float4*)(prow + c0 + 4);
    float4 ta = *(const float4*)(tmx + c0), tb = *(const float4*)(tmx + c0 + 4);
    union { bf16x8 v; uint2 u[2]; } cv;
    cv.u[0] = f4pk(make_float4(xa.x + (pa.x - xa.x) * ta.x, xa.y + (pa.y - xa.y) * ta.y,
                               xa.z + (pa.z - xa.z) * ta.z, xa.w + (pa.w - xa.w) * ta.w));
    cv.u[1] = f4pk(make_float4(xb.x + (pb.x - xb.x) * tb.x, xb.y + (pb.y - xb.y) * tb.y,
                               xb.z + (pb.z - xb.z) * tb.z, xb.w + (pb.w - xb.w) * tb.w));
    #pragma unroll
    for (int n = 0; n < NF; ++n) {
      bf16x8 b = *(const bf16x8*)&Wt[(size_t)(n * 16 + lr) * 1024 + k0 + lk];
      acc[n] = __builtin_amdgcn_mfma_f32_16x16x32_bf16(cv.v, b, acc[n], 0, 0, 0);
    }
  }
  #pragma unroll
  for (int n = 0; n < NF; ++n) {
    #pragma unroll
    for (int q = 0; q < 4; ++q) {
      int row = row0 + (lane >> 4) * 4 + q;
      size_t oi = (size_t)row * NCOLS + n * 16 + lr;
      outv[oi] = f2bf(tanhf(acc[n][q]));
    }
  }
}

// ---------------- skinny MFMA GEMM + tanh body (NCOLS=64, bf16 out) — runs as z=4 of k_gemm5 ----------------
DEVI void tanh64_body(const ushort_t* __restrict__ A, const ushort_t* __restrict__ Wt,
                      ushort_t* __restrict__ outv, int bid) {
  constexpr int NF = 4;
  int tid = threadIdx.x;
  int wave = tid >> 6, lane = tid & 63;
  int row0 = (bid * 4 + wave) * 16;
  int lr = lane & 15, lk = (lane >> 4) * 8;
  f32x4 acc[NF];
  #pragma unroll
  for (int n = 0; n < NF; ++n) acc[n] = (f32x4){0.f, 0.f, 0.f, 0.f};
  for (int k0 = 0; k0 < 1024; k0 += 32) {
    bf16x8 a = *(const bf16x8*)&A[(size_t)(row0 + lr) * 1024 + k0 + lk];
    #pragma unroll
    for (int n = 0; n < NF; ++n) {
      bf16x8 b = *(const bf16x8*)&Wt[(size_t)(n * 16 + lr) * 1024 + k0 + lk];
      acc[n] = __builtin_amdgcn_mfma_f32_16x16x32_bf16(a, b, acc[n], 0, 0, 0);
    }
  }
  #pragma unroll
  for (int n = 0; n < NF; ++n) {
    #pragma unroll
    for (int q = 0; q < 4; ++q) {
      int row = row0 + (lane >> 4) * 4 + q;
      outv[(size_t)row * 64 + n * 16 + lr] = f2bf(tanhf(acc[n][q]));
    }
  }
}

// ---------------- mixer via MFMA; epilogue routed through LDS for coalesced int4 stores ----------------
__global__ __launch_bounds__(256) void k_mix5m(
    const float* __restrict__ x, const float* __restrict__ sst,
    const ushort_t* __restrict__ t160b, const ushort_t* __restrict__ w2t,
    const float* __restrict__ maaw, const float* __restrict__ maak,
    const float* __restrict__ maav, const float* __restrict__ maar,
    const float* __restrict__ maag,
    ushort_t* __restrict__ xw, ushort_t* __restrict__ xk, ushort_t* __restrict__ xv,
    ushort_t* __restrict__ xr, ushort_t* __restrict__ xg) {
  __shared__ __align__(16) ushort_t smem[23040];   // 46080 B: As/Bs (21504 us) | 5x64x72 tiles
  ushort_t* As = smem;
  ushort_t* Bs = smem + 64 * 168;
  ushort_t* sT = smem;                              // reused after MFMA phase
  int tid = threadIdx.x;
  int lane = tid & 63;
  int bRow = blockIdx.x * 64, bCol = blockIdx.y * 64;
  #pragma unroll
  for (int i = 0; i < 5; ++i) {
    int e = tid + i * 256;
    int r = e / 20, cc = (e % 20) * 8;
    *(int4*)&As[r * 168 + cc] = *(const int4*)&t160b[(size_t)(bRow + r) * 160 + cc];
    *(int4*)&Bs[r * 168 + cc] = *(const int4*)&w2t[(size_t)(bCol + r) * 160 + cc];
  }
  __syncthreads();
  int wm = tid >> 7, wn = (tid >> 6) & 1;
  f32x4 acc[5][2][2];
  #pragma unroll
  for (int f = 0; f < 5; ++f)
    #pragma unroll
    for (int m = 0; m < 2; ++m)
      #pragma unroll
      for (int n = 0; n < 2; ++n) acc[f][m][n] = (f32x4){0.f, 0.f, 0.f, 0.f};
  #pragma unroll
  for (int f = 0; f < 5; ++f) {
    bf16x8 af[2], bfv[2];
    #pragma unroll
    for (int m = 0; m < 2; ++m)
      af[m] = *(const bf16x8*)&As[(wm * 32 + m * 16 + (lane & 15)) * 168 + f * 32 + (lane >> 4) * 8];
    #pragma unroll
    for (int n = 0; n < 2; ++n)
      bfv[n] = *(const bf16x8*)&Bs[(wn * 32 + n * 16 + (lane & 15)) * 168 + f * 32 + (lane >> 4) * 8];
    #pragma unroll
    for (int m = 0; m < 2; ++m)
      #pragma unroll
      for (int n = 0; n < 2; ++n)
        acc[f][m][n] = __builtin_amdgcn_mfma_f32_16x16x32_bf16(af[m], bfv[n], acc[f][m][n], 0, 0, 0);
  }
  __syncthreads();   // As/Bs dead -> sT reuse safe
  #pragma unroll
  for (int n = 0; n < 2; ++n) {
    int colL = wn * 32 + n * 16 + (lane & 15);
    int col = bCol + colL;
    float mw_c = maaw[col], mk_c = maak[col], mv_c = maav[col];
    float mr_c = maar[col], mg_c = maag[col];
    #pragma unroll
    for (int m = 0; m < 2; ++m) {
      int rowL0 = wm * 32 + m * 16 + (lane >> 4) * 4;
      #pragma unroll
      for (int q = 0; q < 4; ++q) {
        int rL = rowL0 + q;
        int rg = bRow + rL;
        int tt = rg & (Tc - 1);
        size_t g = (size_t)rg * Cc + col;
        float xv0 = x[g];
        float xprev = (tt == 0) ? sst[(size_t)(rg >> 11) * Cc + col] : x[g - Cc];
        float dv = xprev - xv0;
        sT[0 * 4608 + rL * 72 + colL] = f2bf(xv0 + dv * (mw_c + acc[0][m][n][q]));
        sT[1 * 4608 + rL * 72 + colL] = f2bf(xv0 + dv * (mk_c + acc[1][m][n][q]));
        sT[2 * 4608 + rL * 72 + colL] = f2bf(xv0 + dv * (mv_c + acc[2][m][n][q]));
        sT[3 * 4608 + rL * 72 + colL] = f2bf(xv0 + dv * (mr_c + acc[3][m][n][q]));
        sT[4 * 4608 + rL * 72 + colL] = f2bf(xv0 + dv * (mg_c + acc[4][m][n][q]));
      }
    }
  }
  __syncthreads();
  // coalesced flush: per field 512 int4 chunks (64 rows x 8), 2 per thread
  #pragma unroll
  for (int f = 0; f < 5; ++f) {
    ushort_t* dst = (f == 0) ? xw : (f == 1) ? xk : (f == 2) ? xv : (f == 3) ? xr : xg;
    #pragma unroll
    for (int j = 0; j < 2; ++j) {
      int e = tid + j * 256;
      int r = e >> 3, ch = (e & 7) * 8;
      *(int4*)&dst[(size_t)(bRow + r) * 1024 + bCol + ch] =
          *(const int4*)&sT[f * 4608 + r * 72 + ch];
    }
  }
}

// ---------------- big bf16 MFMA GEMM body: BK=64, swizzled LDS, global_load_lds ----------------
// [R4: 32x32x16 variant = 8.4M bank conflicts; R7: 256² 8-phase = 0 conflicts but 124µs at
//  1 blk/CU — this 16x16x32 / 128² / 2-barrier form at ~109µs, 0 conflicts is the keeper.]
template<int EPI, int OBF>
DEVI void gemm_body(const ushort_t* __restrict__ A, const ushort_t* __restrict__ Wt,
                    void* __restrict__ outv, ushort_t* As, ushort_t* Bs,
                    int bRow, int bCol) {
  int tid = threadIdx.x;
  int wave = tid >> 6, lane = tid & 63;
  int wm = wave >> 1, wn = wave & 1;
  int lr = lane >> 2;
  int lkb = (((lane & 3) ^ ((lane >> 3) & 3))) * 8;   // swizzled source chunk
  int pch = ((lane >> 4) ^ ((lane >> 1) & 3)) * 8;    // physical chunk for fragment reads
  f32x4 zero4 = {0.f, 0.f, 0.f, 0.f};
  f32x4 acc[4][4];
  #pragma unroll
  for (int m = 0; m < 4; ++m)
    #pragma unroll
    for (int n = 0; n < 4; ++n) acc[m][n] = zero4;

#define STAGEK(OFS, K0) do { \
    _Pragma("unroll") \
    for (int i = 0; i < 2; ++i) { \
      int row = (wave + 4 * i) * 16 + lr; \
      gload_lds16(A + (size_t)(bRow + row) * 1024 + (K0) + lkb, &As[(OFS) + (wave + 4 * i) * 512]); \
      gload_lds16(Wt + (size_t)(bCol + row) * 1024 + (K0) + lkb, &Bs[(OFS) + (wave + 4 * i) * 512]); \
    } } while (0)
#define CMP(OFS) do { \
    bf16x8 af[4], bfv[4]; \
    _Pragma("unroll") \
    for (int m = 0; m < 4; ++m) \
      af[m] = *(const bf16x8*)&As[(OFS) + (wm * 64 + m * 16 + (lane & 15)) * 32 + pch]; \
    _Pragma("unroll") \
    for (int n = 0; n < 4; ++n) \
      bfv[n] = *(const bf16x8*)&Bs[(OFS) + (wn * 64 + n * 16 + (lane & 15)) * 32 + pch]; \
    _Pragma("unroll") \
    for (int m = 0; m < 4; ++m) \
      _Pragma("unroll") \
      for (int n = 0; n < 4; ++n) \
        acc[m][n] = __builtin_amdgcn_mfma_f32_16x16x32_bf16(af[m], bfv[n], acc[m][n], 0, 0, 0); \
  } while (0)

  for (int k0 = 0; k0 < 1024; k0 += 64) {
    STAGEK(0, k0);
    STAGEK(4096, k0 + 32);
    __syncthreads();          // single drain (vmcnt(0)) per 64-K
    CMP(0);
    CMP(4096);
    __syncthreads();
  }
#undef STAGEK
#undef CMP

  #pragma unroll
  for (int m = 0; m < 4; ++m) {
    int row = bRow + wm * 64 + m * 16 + (lane >> 4) * 4;
    #pragma unroll
    for (int n = 0; n < 4; ++n) {
      int col = bCol + wn * 64 + n * 16 + (lane & 15);
      #pragma unroll
      for (int q = 0; q < 4; ++q) {
        float v = acc[m][n][q];
        if (EPI == 1) v = v / (1.f + __expf(-v));
        size_t oi = (size_t)(row + q) * 1024 + col;
        if (OBF == 1) ((ushort_t*)outv)[oi] = f2bf(v);
        else          ((float*)outv)[oi] = v;
      }
    }
  }
}

// fused 4-projection GEMM (z=0..3: r/k/v/g, g gets silu) + z=4: skinny tanh GEMM (t64bf)
// z=4 is dependency-free of z=0..3 (reads xwb, writes t64bf; rbb no longer overlays xwb),
// so it fills occupancy slack instead of a serial launch.
__global__ __launch_bounds__(256) void k_gemm5(
    const ushort_t* __restrict__ A0, const ushort_t* __restrict__ A1,
    const ushort_t* __restrict__ A2, const ushort_t* __restrict__ A3,
    const ushort_t* __restrict__ W0, const ushort_t* __restrict__ W1,
    const ushort_t* __restrict__ W2, const ushort_t* __restrict__ W3,
    ushort_t* __restrict__ O0, ushort_t* __restrict__ O1,
    ushort_t* __restrict__ O2, ushort_t* __restrict__ O3,
    const ushort_t* __restrict__ xwb, const ushort_t* __restrict__ dw1t,
    ushort_t* __restrict__ t64bf) {
  int z = blockIdx.z;
  if (z == 4) {
    int bid = blockIdx.y * 64 + blockIdx.x;
    if (bid < BT / 64) tanh64_body(xwb, dw1t, t64bf, bid);
    return;
  }
  __shared__ __align__(16) ushort_t As[2 * 128 * 32];
  __shared__ __align__(16) ushort_t Bs[2 * 128 * 32];
  const ushort_t* A  = (z == 0) ? A0 : (z == 1) ? A1 : (z == 2) ? A2 : A3;
  const ushort_t* Wt = (z == 0) ? W0 : (z == 1) ? W1 : (z == 2) ? W2 : W3;
  ushort_t* out      = (z == 0) ? O0 : (z == 1) ? O1 : (z == 2) ? O2 : O3;
  if (z == 3) gemm_body<1, 1>(A, Wt, out, As, Bs, blockIdx.x * 128, blockIdx.y * 128);
  else        gemm_body<0, 1>(A, Wt, out, As, Bs, blockIdx.x * 128, blockIdx.y * 128);
}

// ---------------- Wo GEMM, 64x128 tiles; f32 epilogue staged through LDS -> float4 rows ----------------
__global__ __launch_bounds__(256) void k_gemm_bm64(const ushort_t* __restrict__ A,
                                                   const ushort_t* __restrict__ Wt,
                                                   float* __restrict__ out) {
  __shared__ __align__(16) char ub[64 * 132 * 4];   // 33792 B >= As(8K)+Bs(16K)
  ushort_t* As = (ushort_t*)ub;
  ushort_t* Bs = (ushort_t*)(ub + 8192);
  float* sT = (float*)ub;                            // reused after K-loop
  int tid = threadIdx.x;
  int wave = tid >> 6, lane = tid & 63;
  int lr = lane >> 2;
  int lkb = (((lane & 3) ^ ((lane >> 3) & 3))) * 8;
  int pch = ((lane >> 4) ^ ((lane >> 1) & 3)) * 8;
  int bRow = blockIdx.x * 64, bCol = blockIdx.y * 128;
  f32x4 acc[4][2];
  #pragma unroll
  for (int m = 0; m < 4; ++m)
    #pragma unroll
    for (int n = 0; n < 2; ++n) acc[m][n] = (f32x4){0.f, 0.f, 0.f, 0.f};

#define STAGEK64(OA, OB, K0) do { \
    { int row = wave * 16 + lr; \
      gload_lds16(A + (size_t)(bRow + row) * 1024 + (K0) + lkb, &As[(OA) + wave * 512]); } \
    _Pragma("unroll") \
    for (int i = 0; i < 2; ++i) { \
      int row = (wave + 4 * i) * 16 + lr; \
      gload_lds16(Wt + (size_t)(bCol + row) * 1024 + (K0) + lkb, &Bs[(OB) + (wave + 4 * i) * 512]); \
    } } while (0)
#define CMP64(OA, OB) do { \
    bf16x8 af[4], bfv[2]; \
    _Pragma("unroll") \
    for (int m = 0; m < 4; ++m) \
      af[m] = *(const bf16x8*)&As[(OA) + (m * 16 + (lane & 15)) * 32 + pch]; \
    _Pragma("unroll") \
    for (int n = 0; n < 2; ++n) \
      bfv[n] = *(const bf16x8*)&Bs[(OB) + (wave * 32 + n * 16 + (lane & 15)) * 32 + pch]; \
    _Pragma("unroll") \
    for (int m = 0; m < 4; ++m) \
      _Pragma("unroll") \
      for (int n = 0; n < 2; ++n) \
        acc[m][n] = __builtin_amdgcn_mfma_f32_16x16x32_bf16(af[m], bfv[n], acc[m][n], 0, 0, 0); \
  } while (0)

  for (int k0 = 0; k0 < 1024; k0 += 64) {
    STAGEK64(0, 0, k0);
    STAGEK64(2048, 4096, k0 + 32);
    __syncthreads();
    CMP64(0, 0);
    CMP64(2048, 4096);
    __syncthreads();          // final iter: As/Bs reads done -> sT reuse safe
  }
#undef STAGEK64
#undef CMP64

  #pragma unroll
  for (int m = 0; m < 4; ++m) {
    int rL = m * 16 + (lane >> 4) * 4;
    #pragma unroll
    for (int n = 0; n < 2; ++n) {
      int cL = wave * 32 + n * 16 + (lane & 15);
      #pragma unroll
      for (int q = 0; q < 4; ++q)
        sT[(rL + q) * 132 + cL] = acc[m][n][q];
    }
  }
  __syncthreads();
  #pragma unroll
  for (int j = 0; j < 8; ++j) {
    int e = tid + j * 256;
    int r = e >> 5, c4 = (e & 31) * 4;
    *(float4*)&out[(size_t)(bRow + r) * 1024 + bCol + c4] = *(const float4*)&sT[r * 132 + c4];
  }
}

// ---------------- preA: wlog via MFMA, cumsum/esum, RW, A(MFMA), knorm, KV(MFMA) ----------------
// Abf + kvbf MFMA-epilogue stores staged through the dead wc region, flushed as
// coalesced int4 rows (proven mechanism, bit-identical values).
__global__ __launch_bounds__(256) void k_preA(
    const ushort_t* __restrict__ rbuf, const ushort_t* __restrict__ kbuf,
    const ushort_t* __restrict__ vbf,
    const ushort_t* __restrict__ t64bf, const float* __restrict__ dw2,
    const float* __restrict__ tdec, const float* __restrict__ faaaa,
    ushort_t* __restrict__ rwbf, ushort_t* __restrict__ kvbf, ushort_t* __restrict__ knbuf,
    ushort_t* __restrict__ Abf, float* __restrict__ esum) {
  __shared__ __align__(16) char ubuf[16640 + 9216 + 9216];
  float* wc = (float*)ubuf;
  ushort_t* sS = (ushort_t*)ubuf;                  // staging tile overlaying wc (dead by use)
  ushort_t* sA = (ushort_t*)(ubuf + 16640);
  ushort_t* sB = (ushort_t*)(ubuf + 16640 + 9216);
  __shared__ float sred[4 * 64];
  __shared__ float sdiag[64];
  __shared__ float snrm[64];
  int bx = blockIdx.x;
  int ci = bx & 31, bh = bx >> 5;
  int b = bh >> 4, h = bh & 15;
  int tid = threadIdx.x;
  int w = tid >> 6, lane = tid & 63;
  int c = lane;
  int row0g = b * Tc + ci * 64;
  size_t base = (size_t)row0g * Cc + (size_t)h * 64;

  #pragma unroll
  for (int j = 0; j < 2; ++j) {
    int e = tid + j * 256; int r = e >> 3, cc = (e & 7) * 8;
    *(int4*)&sA[r * 72 + cc] = *(const int4*)&t64bf[(size_t)(row0g + r) * 64 + cc];
  }
  for (int i = 0; i < 16; ++i) {
    int e = tid + i * 256; int r = e >> 6, cc = e & 63;
    sB[cc * 72 + r] = f2bf(dw2[(size_t)r * Cc + h * 64 + cc]);
  }
  float rv[16], kv[16];
  #pragma unroll
  for (int i = 0; i < 16; ++i) {
    size_t g = base + (size_t)(w * 16 + i) * Cc + c;
    rv[i] = bf2f(rbuf[g]); kv[i] = bf2f(kbuf[g]);
  }
  __syncthreads();
  {
    int rbase = w * 16;
    bf16x8 a0 = *(const bf16x8*)&sA[(rbase + (lane & 15)) * 72 + (lane >> 4) * 8];
    bf16x8 a1 = *(const bf16x8*)&sA[(rbase + (lane & 15)) * 72 + 32 + (lane >> 4) * 8];
    #pragma unroll
    for (int ct = 0; ct < 4; ++ct) {
      bf16x8 b0 = *(const bf16x8*)&sB[(ct * 16 + (lane & 15)) * 72 + (lane >> 4) * 8];
      bf16x8 b1 = *(const bf16x8*)&sB[(ct * 16 + (lane & 15)) * 72 + 32 + (lane >> 4) * 8];
      f32x4 acc = {0.f, 0.f, 0.f, 0.f};
      acc = __builtin_amdgcn_mfma_f32_16x16x32_bf16(a0, b0, acc, 0, 0, 0);
      acc = __builtin_amdgcn_mfma_f32_16x16x32_bf16(a1, b1, acc, 0, 0, 0);
      int s = ct * 16 + (lane & 15);
      #pragma unroll
      for (int q = 0; q < 4; ++q) {
        int t = rbase + (lane >> 4) * 4 + q;
        wc[t * 65 + s] = acc[q];
      }
    }
  }
  __syncthreads();
  float wv[16];
  {
    float td = tdec[h * 64 + c];
    #pragma unroll
    for (int i = 0; i < 16; ++i)
      wv[i] = -__expf(td + wc[(w * 16 + i) * 65 + c]);
  }
  {
    float s = 0.f;
    #pragma unroll
    for (int i = 0; i < 16; ++i) s += wv[i];
    sred[w * 64 + c] = s;
  }
  __syncthreads();
  {
    float run = 0.f;
    for (int ww = 0; ww < w; ++ww) run += sred[ww * 64 + c];
    #pragma unroll
    for (int i = 0; i < 16; ++i) {
      run += wv[i]; wv[i] = run;
      wc[(w * 16 + i) * 65 + c] = run;
    }
    if (w == 3) esum[((size_t)bh * 32 + ci) * 64 + c] = __expf(run);
  }
  {
    float u_c = faaaa[h * 64 + c];
    #pragma unroll
    for (int i = 0; i < 16; ++i) {
      float p = rv[i] * kv[i] * u_c;
      float n2 = kv[i] * kv[i];
      #pragma unroll
      for (int o = 32; o; o >>= 1) { p += __shfl_xor(p, o, 64); n2 += __shfl_xor(n2, o, 64); }
      if (lane == 0) {
        sdiag[w * 16 + i] = p;
        snrm[w * 16 + i] = 1.f / fmaxf(sqrtf(n2), 1e-12f);
      }
    }
  }
  __syncthreads();
  float off32 = wc[31 * 65 + c];
  float wc63 = wc[63 * 65 + c];
  #pragma unroll
  for (int i = 0; i < 16; ++i) {
    int t = w * 16 + i;
    size_t g = base + (size_t)t * Cc + c;
    float wsh = (i == 0) ? ((w == 0) ? 0.f : wc[(t - 1) * 65 + c]) : wv[i - 1];
    rwbf[g] = f2bf(rv[i] * __expf(clip30(wsh)));
    sA[t * 72 + c] = f2bf(rv[i] * __expf(clip30(wsh - off32)));
    sB[t * 72 + c] = f2bf(kv[i] * __expf(clip30(off32 - wv[i])));
    knbuf[g] = f2bf(kv[i] * snrm[t]);
  }
  __syncthreads();   // wc fully dead after this point (off32/wc63/wsh all in regs)
  {
    int rbase = w * 16;
    bf16x8 a0 = *(const bf16x8*)&sA[(rbase + (lane & 15)) * 72 + (lane >> 4) * 8];
    bf16x8 a1 = *(const bf16x8*)&sA[(rbase + (lane & 15)) * 72 + 32 + (lane >> 4) * 8];
    #pragma unroll
    for (int ct = 0; ct < 4; ++ct) {
      bf16x8 b0 = *(const bf16x8*)&sB[(ct * 16 + (lane & 15)) * 72 + (lane >> 4) * 8];
      bf16x8 b1 = *(const bf16x8*)&sB[(ct * 16 + (lane & 15)) * 72 + 32 + (lane >> 4) * 8];
      f32x4 acc = {0.f, 0.f, 0.f, 0.f};
      acc = __builtin_amdgcn_mfma_f32_16x16x32_bf16(a0, b0, acc, 0, 0, 0);
      acc = __builtin_amdgcn_mfma_f32_16x16x32_bf16(a1, b1, acc, 0, 0, 0);
      int s = ct * 16 + (lane & 15);
      #pragma unroll
      for (int q = 0; q < 4; ++q) {
        int t = rbase + (lane >> 4) * 4 + q;
        float val = (t > s) ? acc[q] : ((t == s) ? sdiag[t] : 0.f);
        sS[t * 72 + s] = f2bf(val);             // stage (32B-seg -> LDS, 2-way free)
      }
    }
  }
  __syncthreads();
  // flush Abf coalesced (128B rows) + build KV operand tiles (wv/kv in regs)
  #pragma unroll
  for (int j = 0; j < 2; ++j) {
    int e = tid + j * 256;
    int r = e >> 3, ch = (e & 7) * 8;
    *(int4*)&Abf[(size_t)bx * 4096 + r * 64 + ch] = *(const int4*)&sS[r * 72 + ch];
  }
  #pragma unroll
  for (int i = 0; i < 16; ++i) {
    int t = w * 16 + i;
    sA[c * 72 + t] = f2bf(kv[i] * __expf(clip30(wc63 - wv[i])));
    sB[c * 72 + t] = vbf[base + (size_t)t * Cc + c];
  }
  __syncthreads();   // Abf flush reads of sS done -> sS reusable for kvbf staging
  {
    int rbase = w * 16;
    bf16x8 a0 = *(const bf16x8*)&sA[(rbase + (lane & 15)) * 72 + (lane >> 4) * 8];
    bf16x8 a1 = *(const bf16x8*)&sA[(rbase + (lane & 15)) * 72 + 32 + (lane >> 4) * 8];
    #pragma unroll
    for (int ct = 0; ct < 4; ++ct) {
      bf16x8 b0 = *(const bf16x8*)&sB[(ct * 16 + (lane & 15)) * 72 + (lane >> 4) * 8];
      bf16x8 b1 = *(const bf16x8*)&sB[(ct * 16 + (lane & 15)) * 72 + 32 + (lane >> 4) * 8];
      f32x4 acc = {0.f, 0.f, 0.f, 0.f};
      acc = __builtin_amdgcn_mfma_f32_16x16x32_bf16(a0, b0, acc, 0, 0, 0);
      acc = __builtin_amdgcn_mfma_f32_16x16x32_bf16(a1, b1, acc, 0, 0, 0);
      int j = ct * 16 + (lane & 15);
      #pragma unroll
      for (int q = 0; q < 4; ++q) {
        int ii = rbase + (lane >> 4) * 4 + q;
        sS[ii * 72 + j] = f2bf(acc[q]);         // stage kvbf
      }
    }
  }
  __syncthreads();
  #pragma unroll
  for (int j = 0; j < 2; ++j) {
    int e = tid + j * 256;
    int r = e >> 3, ch = (e & 7) * 8;
    *(int4*)&kvbf[base + (size_t)r * Cc + ch] = *(const int4*)&sS[r * 72 + ch];
  }
}

// ---------------- preB: P(MFMA), static-register GJ solve, y = A@X + RW@state, fused GroupNorm*g ----------------
// ong epilogue staged into sAb (waves only read own row-quarter of sAb -> race-free),
// flushed as coalesced int4 rows.
__global__ __launch_bounds__(256) void k_preB(
    const ushort_t* __restrict__ knbuf, const ushort_t* __restrict__ vbf,
    const ushort_t* __restrict__ Abf, const ushort_t* __restrict__ rwbf,
    const ushort_t* __restrict__ statebuf, const float* __restrict__ ltemp,
    const ushort_t* __restrict__ gbuf, const float* __restrict__ gamma,
    const float* __restrict__ beta, ushort_t* __restrict__ ong) {
  __shared__ __align__(16) ushort_t sKX[64 * 72];
  __shared__ __align__(16) ushort_t sAb[64 * 72];
  __shared__ __align__(16) char ubuf[64 * 72 * 2 * 2];
  __shared__ __align__(16) float pivbuf[2][192];
  __shared__ float colbuf[2][64];
  __shared__ float diagbuf[64];
  float* sP = (float*)ubuf;
  ushort_t* sRW = (ushort_t*)ubuf;
  ushort_t* sSTt = (ushort_t*)(ubuf + 64 * 72 * 2);

  int bx = blockIdx.x;
  int ci = bx & 31, bh = bx >> 5;
  int b = bh >> 4, h = bh & 15;
  int tid = threadIdx.x;
  int w = tid >> 6, lane = tid & 63;
  int rg = tid >> 4, cg = tid & 15;
  size_t base = ((size_t)(b * Tc + ci * 64)) * Cc + (size_t)h * 64;

  #pragma unroll
  for (int j = 0; j < 2; ++j) {
    int e = tid + j * 256;
    int r = e >> 3, cc = (e & 7) * 8;
    *(int4*)&sKX[r * 72 + cc] = *(const int4*)&knbuf[base + (size_t)r * Cc + cc];
    *(int4*)&sAb[r * 72 + cc] = *(const int4*)&Abf[(size_t)bx * 4096 + (size_t)r * 64 + cc];
  }
  float4 A0, A1, A2, A3, B0, B1, B2, B3;
  if (cg >= 8) {
#define LDV(R, AR, BR) do { \
      int4 raw = *(const int4*)(vbf + base + (size_t)(4 * rg + (R)) * Cc + (cg - 8) * 8); \
      (AR).x = bf2f((ushort_t)(raw.x & 0xffff)); (AR).y = bf2f((ushort_t)((unsigned)raw.x >> 16)); \
      (AR).z = bf2f((ushort_t)(raw.y & 0xffff)); (AR).w = bf2f((ushort_t)((unsigned)raw.y >> 16)); \
      (BR).x = bf2f((ushort_t)(raw.z & 0xffff)); (BR).y = bf2f((ushort_t)((unsigned)raw.z >> 16)); \
      (BR).z = bf2f((ushort_t)(raw.w & 0xffff)); (BR).w = bf2f((ushort_t)((unsigned)raw.w >> 16)); \
    } while (0)
    LDV(0, A0, B0); LDV(1, A1, B1); LDV(2, A2, B2); LDV(3, A3, B3);
#undef LDV
  }
  __syncthreads();
  float temp = log1pf(__expf(ltemp[h]));
  {
    int rbase = w * 16;
    bf16x8 a0 = *(const bf16x8*)&sKX[(rbase + (lane & 15)) * 72 + (lane >> 4) * 8];
    bf16x8 a1 = *(const bf16x8*)&sKX[(rbase + (lane & 15)) * 72 + 32 + (lane >> 4) * 8];
    #pragma unroll
    for (int ct = 0; ct < 4; ++ct) {
      bf16x8 b0 = *(const bf16x8*)&sKX[(ct * 16 + (lane & 15)) * 72 + (lane >> 4) * 8];
      bf16x8 b1 = *(const bf16x8*)&sKX[(ct * 16 + (lane & 15)) * 72 + 32 + (lane >> 4) * 8];
      f32x4 acc = {0.f, 0.f, 0.f, 0.f};
      acc = __builtin_amdgcn_mfma_f32_16x16x32_bf16(a0, b0, acc, 0, 0, 0);
      acc = __builtin_amdgcn_mfma_f32_16x16x32_bf16(a1, b1, acc, 0, 0, 0);
      int s = ct * 16 + (lane & 15);
      #pragma unroll
      for (int q = 0; q < 4; ++q) {
        int t = rbase + (lane >> 4) * 4 + q;
        sP[t * 68 + s] = ((t == s) ? 1.f : 0.f) + __expf(clip20(temp * acc[q]));
      }
    }
  }
  __syncthreads();
  if (cg < 8) {
    A0 = *(float4*)&sP[(4 * rg + 0) * 68 + cg * 8]; B0 = *(float4*)&sP[(4 * rg + 0) * 68 + cg * 8 + 4];
    A1 = *(float4*)&sP[(4 * rg + 1) * 68 + cg * 8]; B1 = *(float4*)&sP[(4 * rg + 1) * 68 + cg * 8 + 4];
    A2 = *(float4*)&sP[(4 * rg + 2) * 68 + cg * 8]; B2 = *(float4*)&sP[(4 * rg + 2) * 68 + cg * 8 + 4];
    A3 = *(float4*)&sP[(4 * rg + 3) * 68 + cg * 8]; B3 = *(float4*)&sP[(4 * rg + 3) * 68 + cg * 8 + 4];
  }
  __syncthreads();
  #pragma unroll
  for (int j = 0; j < 2; ++j) {
    int e = tid + j * 256;
    int r = e >> 3, cc = (e & 7) * 8;
    *(int4*)&sRW[r * 72 + cc] = *(const int4*)&rwbf[base + (size_t)r * Cc + cc];
  }
  {
    const ushort_t* sb = statebuf + ((size_t)bh * 32 + ci) * 4096;
    #pragma unroll
    for (int i = 0; i < 16; ++i) {
      int e = tid + i * 256;
      int r = e >> 6, c = e & 63;
      sSTt[c * 72 + r] = sb[e];
    }
  }
#define UPD(MA, MB, F) do { \
    (MA).x -= (F) * p0_.x; (MA).y -= (F) * p0_.y; (MA).z -= (F) * p0_.z; (MA).w -= (F) * p0_.w; \
    (MB).x -= (F) * p1_.x; (MB).y -= (F) * p1_.y; (MB).z -= (F) * p1_.z; (MB).w -= (F) * p1_.w; \
  } while (0)
#define GJSTEP(JL, PRA, PRB, H0, H1, H2, H3) do { \
    int j_ = jh * 8 + (JL); \
    if (rg == (j_ >> 2)) { \
      *(float4*)&pivbuf[(JL) & 1][cg * 12]     = (PRA); \
      *(float4*)&pivbuf[(JL) & 1][cg * 12 + 4] = (PRB); \
    } \
    if (cg == jh) { \
      float4 cv_; \
      cv_.x = GETEL(H0, (JL) & 3); \
      cv_.y = GETEL(H1, (JL) & 3); \
      cv_.z = GETEL(H2, (JL) & 3); \
      cv_.w = GETEL(H3, (JL) & 3); \
      *(float4*)&colbuf[(JL) & 1][rg * 4] = cv_; \
    } \
    __syncthreads(); \
    float pd_ = pivbuf[(JL) & 1][(j_ >> 3) * 12 + (j_ & 7)]; \
    float4 fv_ = *(float4*)&colbuf[(JL) & 1][rg * 4]; \
    float4 p0_ = *(float4*)&pivbuf[(JL) & 1][cg * 12]; \
    float4 p1_ = *(float4*)&pivbuf[(JL) & 1][cg * 12 + 4]; \
    if (rg == (j_ >> 2)) SETEL(fv_, (JL) & 3, 0.f); \
    float inv_ = 1.f / pd_; \
    float f0_ = fv_.x * inv_, f1_ = fv_.y * inv_, f2_ = fv_.z * inv_, f3_ = fv_.w * inv_; \
    UPD(A0, B0, f0_); UPD(A1, B1, f1_); UPD(A2, B2, f2_); UPD(A3, B3, f3_); \
  } while (0)
  for (int jh = 0; jh < 8; ++jh) {
    GJSTEP(0, A0, B0, A0, A1, A2, A3);
    GJSTEP(1, A1, B1, A0, A1, A2, A3);
    GJSTEP(2, A2, B2, A0, A1, A2, A3);
    GJSTEP(3, A3, B3, A0, A1, A2, A3);
    GJSTEP(4, A0, B0, B0, B1, B2, B3);
    GJSTEP(5, A1, B1, B0, B1, B2, B3);
    GJSTEP(6, A2, B2, B0, B1, B2, B3);
    GJSTEP(7, A3, B3, B0, B1, B2, B3);
  }
#undef GJSTEP
#undef UPD
  if (cg == (rg >> 1)) {
    float4 h0 = (rg & 1) ? B0 : A0;
    float4 h1 = (rg & 1) ? B1 : A1;
    float4 h2 = (rg & 1) ? B2 : A2;
    float4 h3 = (rg & 1) ? B3 : A3;
    *(float4*)&diagbuf[rg * 4] = make_float4(h0.x, h1.y, h2.z, h3.w);
  }
  __syncthreads();
  if (cg >= 8) {
    float4 dg = *(float4*)&diagbuf[rg * 4];
#define WRX(R, AR, BR, IR) do { \
      int cb_ = (cg - 8) * 8; \
      sKX[(cb_ + 0) * 72 + 4 * rg + (R)] = f2bf((AR).x * (IR)); \
      sKX[(cb_ + 1) * 72 + 4 * rg + (R)] = f2bf((AR).y * (IR)); \
      sKX[(cb_ + 2) * 72 + 4 * rg + (R)] = f2bf((AR).z * (IR)); \
      sKX[(cb_ + 3) * 72 + 4 * rg + (R)] = f2bf((AR).w * (IR)); \
      sKX[(cb_ + 4) * 72 + 4 * rg + (R)] = f2bf((BR).x * (IR)); \
      sKX[(cb_ + 5) * 72 + 4 * rg + (R)] = f2bf((BR).y * (IR)); \
      sKX[(cb_ + 6) * 72 + 4 * rg + (R)] = f2bf((BR).z * (IR)); \
      sKX[(cb_ + 7) * 72 + 4 * rg + (R)] = f2bf((BR).w * (IR)); \
    } while (0)
    WRX(0, A0, B0, 1.f / dg.x);
    WRX(1, A1, B1, 1.f / dg.y);
    WRX(2, A2, B2, 1.f / dg.z);
    WRX(3, A3, B3, 1.f / dg.w);
#undef WRX
  }
  __syncthreads();
  {
    int rbase = w * 16;
    bf16x8 aA0 = *(const bf16x8*)&sAb[(rbase + (lane & 15)) * 72 + (lane >> 4) * 8];
    bf16x8 aA1 = *(const bf16x8*)&sAb[(rbase + (lane & 15)) * 72 + 32 + (lane >> 4) * 8];
    bf16x8 aR0 = *(const bf16x8*)&sRW[(rbase + (lane & 15)) * 72 + (lane >> 4) * 8];
    bf16x8 aR1 = *(const bf16x8*)&sRW[(rbase + (lane & 15)) * 72 + 32 + (lane >> 4) * 8];
    f32x4 yv[4];
    #pragma unroll
    for (int ct = 0; ct < 4; ++ct) {
      bf16x8 bX0 = *(const bf16x8*)&sKX[(ct * 16 + (lane & 15)) * 72 + (lane >> 4) * 8];
      bf16x8 bX1 = *(const bf16x8*)&sKX[(ct * 16 + (lane & 15)) * 72 + 32 + (lane >> 4) * 8];
      bf16x8 bS0 = *(const bf16x8*)&sSTt[(ct * 16 + (lane & 15)) * 72 + (lane >> 4) * 8];
      bf16x8 bS1 = *(const bf16x8*)&sSTt[(ct * 16 + (lane & 15)) * 72 + 32 + (lane >> 4) * 8];
      f32x4 acc = {0.f, 0.f, 0.f, 0.f};
      acc = __builtin_amdgcn_mfma_f32_16x16x32_bf16(aA0, bX0, acc, 0, 0, 0);
      acc = __builtin_amdgcn_mfma_f32_16x16x32_bf16(aA1, bX1, acc, 0, 0, 0);
      acc = __builtin_amdgcn_mfma_f32_16x16x32_bf16(aR0, bS0, acc, 0, 0, 0);
      acc = __builtin_amdgcn_mfma_f32_16x16x32_bf16(aR1, bS1, acc, 0, 0, 0);
      yv[ct] = acc;
    }
    #pragma unroll
    for (int q = 0; q < 4; ++q) {
      float s1 = yv[0][q] + yv[1][q] + yv[2][q] + yv[3][q];
      float s2 = yv[0][q] * yv[0][q] + yv[1][q] * yv[1][q] +
                 yv[2][q] * yv[2][q] + yv[3][q] * yv[3][q];
      #pragma unroll
      for (int o = 1; o < 16; o <<= 1) {
        s1 += __shfl_xor(s1, o, 64);
        s2 += __shfl_xor(s2, o, 64);
      }
      float mu = s1 * (1.f / 64.f);
      float var = s2 * (1.f / 64.f) - mu * mu;
      float rs = rsqrtf(var + 6.4e-4f);
      int t = rbase + (lane >> 4) * 4 + q;
      #pragma unroll
      for (int ct = 0; ct < 4; ++ct) {
        int cc = ct * 16 + (lane & 15);
        size_t g = base + (size_t)t * Cc + cc;
        float yn = (yv[ct][q] - mu) * rs;
        float o = (yn * gamma[h * 64 + cc] + beta[h * 64 + cc]) * bf2f(gbuf[g]);
        sAb[t * 72 + cc] = f2bf(o);            // stage ong (own row-quarter of sAb)
      }
    }
  }
  __syncthreads();
  #pragma unroll
  for (int j = 0; j < 2; ++j) {
    int e = tid + j * 256;
    int r = e >> 3, ch = (e & 7) * 8;
    *(int4*)&ong[base + (size_t)r * Cc + ch] = *(const int4*)&sAb[r * 72 + ch];
  }
}

// ---------------- state recurrence only (bf16 kv/statebuf, f32 registers) ----------------
__global__ __launch_bounds__(128) void k_scanstate(
    const float* __restrict__ wkv0, const ushort_t* __restrict__ kvbf,
    const float* __restrict__ esum, ushort_t* __restrict__ statebuf,
    float* __restrict__ stout) {
  int bh = blockIdx.x >> 3;
  int rg = blockIdx.x & 7;
  int b = bh >> 4, h = bh & 15;
  int tid = threadIdx.x;
  int r = rg * 8 + (tid >> 4);
  int c0 = (tid & 15) * 4;
  float4 st = *(const float4*)(wkv0 + ((size_t)bh * 64 + r) * 64 + c0);
  size_t kvb = (size_t)(b * Tc) * Cc + (size_t)h * 64 + (size_t)r * Cc + c0;
  constexpr int PF = 4;
  uint2 kvn[PF];
  float4 evn[PF];
  #pragma unroll
  for (int j = 0; j < PF; ++j) {
    kvn[j] = *(const uint2*)(kvbf + kvb + (size_t)j * 64 * Cc);
    evn[j] = *(const float4*)(esum + ((size_t)bh * 32 + j) * 64 + c0);
  }
  #pragma unroll
  for (int ci = 0; ci < NCHUNK; ++ci) {
    *(uint2*)(statebuf + ((size_t)bh * 32 + ci) * 4096 + (size_t)r * 64 + c0) = f4pk(st);
    float4 kv = bf4up(kvn[ci & 3]);
    float4 ev = evn[ci & 3];
    if (ci + PF < NCHUNK) {
      kvn[ci & 3] = *(const uint2*)(kvbf + kvb + (size_t)(ci + PF) * 64 * Cc);
      evn[ci & 3] = *(const float4*)(esum + ((size_t)bh * 32 + ci + PF) * 64 + c0);
    }
    st.x = st.x * ev.x + kv.x;
    st.y = st.y * ev.y + kv.y;
    st.z = st.z * ev.z + kv.z;
    st.w = st.w * ev.w + kv.w;
  }
  *(float4*)(stout + ((size_t)bh * 64 + r) * 64 + c0) = st;
}

// ---------------- launcher ----------------
extern "C" void kernel_launch(void* const* d_in, const int* in_sizes, int n_in,
                              void* d_out, int out_size, void* d_ws, size_t ws_size,
                              hipStream_t stream) {
  (void)in_sizes; (void)n_in; (void)out_size;
  const float* x     = (const float*)d_in[0];
  const float* sst   = (const float*)d_in[1];
  const float* wkv0  = (const float*)d_in[2];
  const float* tmx   = (const float*)d_in[3];
  const float* tmw   = (const float*)d_in[4];
  const float* tmk   = (const float*)d_in[5];
  const float* tmv   = (const float*)d_in[6];
  const float* tmr   = (const float*)d_in[7];
  const float* tmg   = (const float*)d_in[8];
  const float* w1    = (const float*)d_in[9];
  const float* w2    = (const float*)d_in[10];
  const float* tdec  = (const float*)d_in[11];
  const float* dw1   = (const float*)d_in[12];
  const float* dw2   = (const float*)d_in[13];
  const float* faaaa = (const float*)d_in[14];
  const float* ltemp = (const float*)d_in[15];
  const float* Wr    = (const float*)d_in[16];
  const float* Wk    = (const float*)d_in[17];
  const float* Wv    = (const float*)d_in[18];
  const float* Wg    = (const float*)d_in[19];
  const float* Wo    = (const float*)d_in[20];
  const float* lng   = (const float*)d_in[21];
  const float* lnb   = (const float*)d_in[22];
  float* out = (float*)d_out;

  const size_t MB = 1ull << 20;
  const size_t NEED = 242 * MB;
  if (ws_size < NEED) return;

  char* p = (char*)d_ws;
  ushort_t* kbb  = (ushort_t*)(p + 0 * MB);    // bf16 k (GEMM out)
  ushort_t* xwb  = (ushort_t*)(p + 16 * MB);   // xw bf16 (stays live through k_gemm5 z=4)
  ushort_t* rbb  = (ushort_t*)(p + 48 * MB);   // bf16 r (GEMM out) — no longer overlays xwb
  ushort_t* kvbf = (ushort_t*)(p + 32 * MB);   // KV bf16 (16 MiB)
  ushort_t* statebuf = (ushort_t*)(p + 96 * MB); // bf16 (16 MiB)
  ushort_t* vbuf = (ushort_t*)(p + 128 * MB);  // v (bf16)
  ushort_t* gbuf = (ushort_t*)(p + 144 * MB);  // silu(g) (bf16)
  ushort_t* xkb  = (ushort_t*)(p + 160 * MB);  // -> Abf
  ushort_t* Abf  = (ushort_t*)(p + 160 * MB);
  ushort_t* xvb  = (ushort_t*)(p + 176 * MB);  // -> rwbf
  ushort_t* rwbf = (ushort_t*)(p + 176 * MB);
  ushort_t* xrb  = (ushort_t*)(p + 192 * MB);
  ushort_t* xgb  = (ushort_t*)(p + 208 * MB);  // xg -> knorm -> ong
  ushort_t* t160b = (ushort_t*)(p + 224 * MB);
  float*    esum = (float*)(p + 224 * MB);     // overlays t160b (dead by then)
  ushort_t* w2t  = (ushort_t*)(p + 227 * MB);  // 0.32 MiB
  ushort_t* w1t  = (ushort_t*)(p + 228 * MB);  // 0.32 MiB
  ushort_t* dw1t = (ushort_t*)(p + 229 * MB);  // 0.13 MiB
  ushort_t* t64bf = (ushort_t*)(p + 230 * MB); // bf16 tanh(xw@dw1), 1 MiB
  ushort_t* Wrb  = (ushort_t*)(p + 232 * MB);
  ushort_t* Wkb  = (ushort_t*)(p + 234 * MB);
  ushort_t* Wvb  = (ushort_t*)(p + 236 * MB);
  ushort_t* Wgb  = (ushort_t*)(p + 238 * MB);
  ushort_t* Wob  = (ushort_t*)(p + 240 * MB);

  const int thr = 256;
  k_f2bf5p<<<dim3(1552, 1, 6), thr, 0, stream>>>(
      Wr, Wk, Wv, Wg, Wo, w2, w1, dw1, x,
      Wrb, Wkb, Wvb, Wgb, Wob, w2t, w1t, dw1t, out + (size_t)BT * Cc);

  k_shift_tanh<<<BT / 64, thr, 0, stream>>>(x, sst, tmx, w1t, t160b);
  k_mix5m<<<dim3(BT / 64, Cc / 64), thr, 0, stream>>>(x, sst, t160b, w2t,
                                                      tmw, tmk, tmv, tmr, tmg,
                                                      xwb, xkb, xvb, xrb, xgb);

  k_gemm5<<<dim3(BT / 128, Cc / 128, 5), thr, 0, stream>>>(
      xrb, xkb, xvb, xgb, Wrb, Wkb, Wvb, Wgb, rbb, kbb, vbuf, gbuf,
      xwb, dw1t, t64bf);

  k_preA<<<2048, thr, 0, stream>>>(rbb, kbb, vbuf, t64bf, dw2, tdec, faaaa,
                                   rwbf, kvbf, xgb /*knorm*/, Abf, esum);
  k_scanstate<<<512, 128, 0, stream>>>(wkv0, kvbf, esum, statebuf,
                                       out + (size_t)BT * Cc + (size_t)Bc * Cc);
  k_preB<<<2048, thr, 0, stream>>>(xgb /*knorm*/, vbuf, Abf, rwbf, statebuf, ltemp,
                                   gbuf, lng, lnb, xgb /*ong*/);

  k_gemm_bm64<<<dim3(BT / 64, Cc / 128), thr, 0, stream>>>(xgb, Wob, out);
}